// Round 8
// baseline (683.716 us; speedup 1.0000x reference)
//
#include <hip/hip_runtime.h>
#include <hip/hip_bf16.h>
#include <math.h>

#define S_LEN 2048
#define HID   1024
#define NHEAD 16
#define KVH   4
#define HD    64
#define FF    1024
#define NE    8
#define NL    2

// ---- workspace layout (float offsets) ----
#define OFF_H    0
#define OFF_XN   (OFF_H + S_LEN*HID)
#define OFF_Q    (OFF_XN + S_LEN*HID)
#define OFF_K    (OFF_Q + S_LEN*HID)
#define OFF_V    (OFF_K + S_LEN*KVH*HD)
#define OFF_COS  (OFF_V + S_LEN*KVH*HD)
#define OFF_SIN  (OFF_COS + S_LEN*32)
#define OFF_WT   (OFF_SIN + S_LEN*32)
#define OFF_INT  (OFF_WT + NE*S_LEN)
#define OFF_XH   (OFF_INT + NE*S_LEN + 16)
#define OFF_AOH  (OFF_XH + S_LEN*HID/2)
#define OFF_ABH  (OFF_AOH + S_LEN*HID/2)
#define OFF_PO   (OFF_ABH + NE*S_LEN*FF/2)
#define OFF_PM   (OFF_PO + 80*NHEAD*64*64)
#define OFF_PL   (OFF_PM + 80*NHEAD*64)
#define OFF_WCVT (OFF_PL + 80*NHEAD*64)
// WCVT region (shorts): qkvo 2.5M + w1 8M + w3 8M + w2 8M = 26.5M shorts = 53MB

typedef __attribute__((ext_vector_type(8))) _Float16 f16x8;
typedef __attribute__((ext_vector_type(8))) short  s16x8;
typedef __attribute__((ext_vector_type(4))) float  f32x4;

__device__ __forceinline__ short f2h(float f) {
    union { _Float16 h; short s; } u;
    u.h = (_Float16)f;
    return u.s;
}

__device__ __forceinline__ s16x8 cvt8(float4 a, float4 b) {
    s16x8 w;
    w[0]=f2h(a.x); w[1]=f2h(a.y); w[2]=f2h(a.z); w[3]=f2h(a.w);
    w[4]=f2h(b.x); w[5]=f2h(b.y); w[6]=f2h(b.z); w[7]=f2h(b.w);
    return w;
}

// ---------------- fp32 -> fp16 convert ----------------
__global__ __launch_bounds__(256) void cvt16_kernel(const float* __restrict__ src,
                                                    short* __restrict__ dst, int n8) {
    int gid = blockIdx.x * 256 + threadIdx.x;
    if (gid >= n8) return;
    const float4* s = (const float4*)src + (size_t)gid * 2;
    *(s16x8*)(dst + (size_t)gid * 8) = cvt8(s[0], s[1]);
}

// ---------------- RoPE tables ----------------
__global__ void rope_tables_kernel(float* __restrict__ cosb, float* __restrict__ sinb) {
    int gid = blockIdx.x * 256 + threadIdx.x;
    int t = gid >> 5, i = gid & 31;
    float invf = powf(1.0e6f, -(float)i / 32.0f);
    float ang = (float)t * invf;
    cosb[gid] = cosf(ang);
    sinb[gid] = sinf(ang);
}

// ---------------- RMSNorm -> fp32 + fp16 ----------------
__global__ __launch_bounds__(256) void rmsnorm_h16_kernel(const float* __restrict__ x,
                                                          const float* __restrict__ w,
                                                          float* __restrict__ out,
                                                          short* __restrict__ oh) {
    int row = blockIdx.x;
    const float4* xr = (const float4*)(x + (size_t)row * HID);
    float4 xv = xr[threadIdx.x];
    float ss = xv.x*xv.x + xv.y*xv.y + xv.z*xv.z + xv.w*xv.w;
    for (int off = 32; off; off >>= 1) ss += __shfl_xor(ss, off);
    __shared__ float sred[4];
    if ((threadIdx.x & 63) == 0) sred[threadIdx.x >> 6] = ss;
    __syncthreads();
    float tot = sred[0] + sred[1] + sred[2] + sred[3];
    float scale = rsqrtf(tot * (1.0f / (float)HID) + 1e-5f);
    float4 wv = ((const float4*)w)[threadIdx.x];
    float4 o;
    o.x = xv.x * scale * wv.x; o.y = xv.y * scale * wv.y;
    o.z = xv.z * scale * wv.z; o.w = xv.w * scale * wv.w;
    ((float4*)(out + (size_t)row * HID))[threadIdx.x] = o;
    union { short s[4]; float2 f2; } hh;
    hh.s[0]=f2h(o.x); hh.s[1]=f2h(o.y); hh.s[2]=f2h(o.z); hh.s[3]=f2h(o.w);
    ((float2*)(oh + (size_t)row * HID))[threadIdx.x] = hh.f2;
}

// plain rmsnorm for final output
__global__ __launch_bounds__(256) void rmsnorm_kernel(const float* __restrict__ x,
                                                      const float* __restrict__ w,
                                                      float* __restrict__ out) {
    int row = blockIdx.x;
    const float4* xr = (const float4*)(x + (size_t)row * HID);
    float4 xv = xr[threadIdx.x];
    float ss = xv.x*xv.x + xv.y*xv.y + xv.z*xv.z + xv.w*xv.w;
    for (int off = 32; off; off >>= 1) ss += __shfl_xor(ss, off);
    __shared__ float sred[4];
    if ((threadIdx.x & 63) == 0) sred[threadIdx.x >> 6] = ss;
    __syncthreads();
    float tot = sred[0] + sred[1] + sred[2] + sred[3];
    float scale = rsqrtf(tot * (1.0f / (float)HID) + 1e-5f);
    float4 wv = ((const float4*)w)[threadIdx.x];
    float4 o;
    o.x = xv.x * scale * wv.x; o.y = xv.y * scale * wv.y;
    o.z = xv.z * scale * wv.z; o.w = xv.w * scale * wv.w;
    ((float4*)(out + (size_t)row * HID))[threadIdx.x] = o;
}

// ---------------- RoPE apply ----------------
__global__ void rope_apply_kernel(float* __restrict__ p, const float* __restrict__ cosb,
                                  const float* __restrict__ sinb, int nh, int total) {
    int gid = blockIdx.x * 256 + threadIdx.x;
    if (gid >= total) return;
    int per = nh * 32;
    int t = gid / per, r = gid % per;
    int hh = r >> 5, i = r & 31;
    float c = cosb[t*32 + i], s = sinb[t*32 + i];
    float* base = p + (size_t)t * (nh * HD) + hh * HD + i;
    float a = base[0], b = base[32];
    base[0]  = a * c - b * s;
    base[32] = b * c + a * s;
}

// ---------------- single-pass fp16 128x128 GEMM core ----------------
__device__ __forceinline__ void gemm128_core(
        const short* pA0, const short* pA1, const short* pB0, const short* pB1,
        int Kd, int tid, short* As, short* Bs, f32x4 (&acc)[4][4]) {
    const int lane = tid & 63, lo = lane & 15, hi = lane >> 4;
    const int wid = tid >> 6, wr = wid >> 1, wc = wid & 1;
    const int srow = tid >> 2, scol = (tid & 3) * 8;
    for (int k0 = 0; k0 < Kd; k0 += 32) {
        s16x8 a0 = *(const s16x8*)(pA0 + k0);
        s16x8 a1 = *(const s16x8*)(pA1 + k0);
        s16x8 b0 = *(const s16x8*)(pB0 + k0);
        s16x8 b1 = *(const s16x8*)(pB1 + k0);
        __syncthreads();
        *(s16x8*)&As[srow*40 + scol] = a0;
        *(s16x8*)&As[(64+srow)*40 + scol] = a1;
        *(s16x8*)&Bs[srow*40 + scol] = b0;
        *(s16x8*)&Bs[(64+srow)*40 + scol] = b1;
        __syncthreads();
        f16x8 aF[4], bF[4];
        #pragma unroll
        for (int m = 0; m < 4; ++m) aF[m] = *(const f16x8*)&As[(wr*64 + m*16 + lo)*40 + hi*8];
        #pragma unroll
        for (int n = 0; n < 4; ++n) bF[n] = *(const f16x8*)&Bs[(wc*64 + n*16 + lo)*40 + hi*8];
        #pragma unroll
        for (int m = 0; m < 4; ++m)
            #pragma unroll
            for (int n = 0; n < 4; ++n)
                acc[m][n] = __builtin_amdgcn_mfma_f32_16x16x32_f16(aF[m], bF[n], acc[m][n], 0, 0, 0);
    }
}

// ---------------- generic fp16 GEMM: C = A@B^T (+resid) ----------------
__global__ __launch_bounds__(256) void gemm_h16_kernel(const short* __restrict__ Ag,
        const short* __restrict__ Bg, float* __restrict__ C,
        const float* __restrict__ resid, int N, int Kd) {
    __shared__ __align__(16) short As[128*40], Bs[128*40];
    const int tid = threadIdx.x;
    const int lane = tid & 63, lo = lane & 15, hi = lane >> 4;
    const int wid = tid >> 6, wr = wid >> 1, wc = wid & 1;
    const int m0 = blockIdx.y * 128, n0 = blockIdx.x * 128;
    const int srow = tid >> 2, scol = (tid & 3) * 8;
    f32x4 acc[4][4];
    #pragma unroll
    for (int m = 0; m < 4; ++m)
        #pragma unroll
        for (int n = 0; n < 4; ++n) { acc[m][n][0]=0.f; acc[m][n][1]=0.f; acc[m][n][2]=0.f; acc[m][n][3]=0.f; }
    gemm128_core(Ag + (size_t)(m0+srow)*Kd + scol, Ag + (size_t)(m0+64+srow)*Kd + scol,
                 Bg + (size_t)(n0+srow)*Kd + scol, Bg + (size_t)(n0+64+srow)*Kd + scol,
                 Kd, tid, As, Bs, acc);
    #pragma unroll
    for (int m = 0; m < 4; ++m)
        #pragma unroll
        for (int n = 0; n < 4; ++n)
            #pragma unroll
            for (int r = 0; r < 4; ++r) {
                int row = m0 + wr*64 + m*16 + hi*4 + r;
                int col = n0 + wc*64 + n*16 + lo;
                float val = acc[m][n][r];
                if (resid) val += resid[(size_t)row * N + col];
                C[(size_t)row * N + col] = val;
            }
}

// ---------------- fused QKV GEMM (fp16) ----------------
__global__ __launch_bounds__(256) void qkv_h16_kernel(const short* __restrict__ Xh,
        const short* __restrict__ qw16, const short* __restrict__ kw16,
        const short* __restrict__ vw16,
        float* __restrict__ qo, float* __restrict__ ko, float* __restrict__ vo) {
    __shared__ __align__(16) short As[128*40], Bs[128*40];
    const int bx = blockIdx.x;
    const short* Bp; float* Cp; int Nc, n0;
    if (bx < 8)       { Bp = qw16; Cp = qo; Nc = 1024; n0 = bx * 128; }
    else if (bx < 10) { Bp = kw16; Cp = ko; Nc = 256;  n0 = (bx - 8) * 128; }
    else              { Bp = vw16; Cp = vo; Nc = 256;  n0 = (bx - 10) * 128; }
    const int tid = threadIdx.x;
    const int lane = tid & 63, lo = lane & 15, hi = lane >> 4;
    const int wid = tid >> 6, wr = wid >> 1, wc = wid & 1;
    const int m0 = blockIdx.y * 128;
    const int srow = tid >> 2, scol = (tid & 3) * 8;
    f32x4 acc[4][4];
    #pragma unroll
    for (int m = 0; m < 4; ++m)
        #pragma unroll
        for (int n = 0; n < 4; ++n) { acc[m][n][0]=0.f; acc[m][n][1]=0.f; acc[m][n][2]=0.f; acc[m][n][3]=0.f; }
    gemm128_core(Xh + (size_t)(m0+srow)*HID + scol, Xh + (size_t)(m0+64+srow)*HID + scol,
                 Bp + (size_t)(n0+srow)*HID + scol, Bp + (size_t)(n0+64+srow)*HID + scol,
                 HID, tid, As, Bs, acc);
    #pragma unroll
    for (int m = 0; m < 4; ++m)
        #pragma unroll
        for (int n = 0; n < 4; ++n)
            #pragma unroll
            for (int r = 0; r < 4; ++r) {
                int row = m0 + wr*64 + m*16 + hi*4 + r;
                int col = n0 + wc*64 + n*16 + lo;
                Cp[(size_t)row * Nc + col] = acc[m][n][r];
            }
}

// ---------------- split-K fp16 MFMA flash attention -> partials ----------------
// grid (80, NHEAD): slot -> (q-tile, key-chunk of <=8 tiles). Long chunks first.
__global__ __launch_bounds__(256) void attn_mfma_kernel(const float* __restrict__ q,
                                                        const float* __restrict__ k,
                                                        const float* __restrict__ v,
                                                        float* __restrict__ pO,
                                                        float* __restrict__ pm,
                                                        float* __restrict__ pl) {
    __shared__ __align__(16) short Ks[64][72];
    __shared__ __align__(16) short Vt[64][72];
    __shared__ __align__(16) short Ps[4][16][72];
    const int wid = threadIdx.x >> 6, lane = threadIdx.x & 63;
    const int lo = lane & 15, hi = lane >> 4;
    const int head = blockIdx.y;
    const int s = 79 - blockIdx.x;            // long chunks dispatched first
    int qi, c;
    if (s < 8)       { qi = s;                     c = 0; }
    else if (s < 24) { int t = s - 8;  qi = 8  + (t >> 1); c = t & 1; }
    else if (s < 48) { int t = s - 24; qi = 16 + t / 3;    c = t % 3; }
    else             { int t = s - 48; qi = 24 + (t >> 2); c = t & 3; }
    const int t_beg = c * 8;
    const int t_end = min(t_beg + 8, qi + 1);
    const int q0 = qi * 64;
    const int kvh = head >> 2;

    f16x8 qf[2];
    {
        const float* qr = q + (size_t)(q0 + wid*16 + lo) * HID + head*HD;
        #pragma unroll
        for (int kk = 0; kk < 2; ++kk)
            #pragma unroll
            for (int i = 0; i < 8; ++i)
                qf[kk][i] = (_Float16)qr[kk*32 + hi*8 + i];
    }

    f32x4 acc[4];
    float m[4], l[4];
    #pragma unroll
    for (int r = 0; r < 4; ++r) {
        m[r] = -1e30f; l[r] = 0.f;
        acc[0][r] = 0.f; acc[1][r] = 0.f; acc[2][r] = 0.f; acc[3][r] = 0.f;
    }

    const int skey = threadIdx.x >> 2;
    const int sdg  = (threadIdx.x & 3) * 16;

    // prefetch tile t_beg into registers
    float4 ka0, ka1, ka2, ka3, vv0, vv1, vv2, vv3;
    {
        const float* kr = k + (size_t)(t_beg*64 + skey)*(KVH*HD) + kvh*HD + sdg;
        ka0 = ((const float4*)kr)[0]; ka1 = ((const float4*)kr)[1];
        ka2 = ((const float4*)kr)[2]; ka3 = ((const float4*)kr)[3];
        const float* vr = v + (size_t)(t_beg*64 + skey)*(KVH*HD) + kvh*HD + sdg;
        vv0 = ((const float4*)vr)[0]; vv1 = ((const float4*)vr)[1];
        vv2 = ((const float4*)vr)[2]; vv3 = ((const float4*)vr)[3];
    }

    for (int t = t_beg; t < t_end; ++t) {
        __syncthreads();   // previous tile's LDS reads complete
        *(s16x8*)&Ks[skey][sdg]     = cvt8(ka0, ka1);
        *(s16x8*)&Ks[skey][sdg + 8] = cvt8(ka2, ka3);
        Vt[sdg+ 0][skey]=f2h(vv0.x); Vt[sdg+ 1][skey]=f2h(vv0.y);
        Vt[sdg+ 2][skey]=f2h(vv0.z); Vt[sdg+ 3][skey]=f2h(vv0.w);
        Vt[sdg+ 4][skey]=f2h(vv1.x); Vt[sdg+ 5][skey]=f2h(vv1.y);
        Vt[sdg+ 6][skey]=f2h(vv1.z); Vt[sdg+ 7][skey]=f2h(vv1.w);
        Vt[sdg+ 8][skey]=f2h(vv2.x); Vt[sdg+ 9][skey]=f2h(vv2.y);
        Vt[sdg+10][skey]=f2h(vv2.z); Vt[sdg+11][skey]=f2h(vv2.w);
        Vt[sdg+12][skey]=f2h(vv3.x); Vt[sdg+13][skey]=f2h(vv3.y);
        Vt[sdg+14][skey]=f2h(vv3.z); Vt[sdg+15][skey]=f2h(vv3.w);
        __syncthreads();
        if (t + 1 < t_end) {  // issue next-tile loads; latency hides under compute
            const float* kr = k + (size_t)((t+1)*64 + skey)*(KVH*HD) + kvh*HD + sdg;
            ka0 = ((const float4*)kr)[0]; ka1 = ((const float4*)kr)[1];
            ka2 = ((const float4*)kr)[2]; ka3 = ((const float4*)kr)[3];
            const float* vr = v + (size_t)((t+1)*64 + skey)*(KVH*HD) + kvh*HD + sdg;
            vv0 = ((const float4*)vr)[0]; vv1 = ((const float4*)vr)[1];
            vv2 = ((const float4*)vr)[2]; vv3 = ((const float4*)vr)[3];
        }
        const int k0 = t * 64;
        f32x4 sc[4];
        #pragma unroll
        for (int f = 0; f < 4; ++f) {
            f32x4 sf; sf[0]=0.f; sf[1]=0.f; sf[2]=0.f; sf[3]=0.f;
            f16x8 bk0 = *(const f16x8*)&Ks[f*16 + lo][hi*8];
            sf = __builtin_amdgcn_mfma_f32_16x16x32_f16(qf[0], bk0, sf, 0, 0, 0);
            f16x8 bk1 = *(const f16x8*)&Ks[f*16 + lo][32 + hi*8];
            sf = __builtin_amdgcn_mfma_f32_16x16x32_f16(qf[1], bk1, sf, 0, 0, 0);
            sc[f] = sf;
        }
        #pragma unroll
        for (int f = 0; f < 4; ++f)
            #pragma unroll
            for (int r = 0; r < 4; ++r) sc[f][r] *= 0.125f;
        if (t == qi) {   // diagonal tile: causal mask
            int qrow = q0 + wid*16 + hi*4;
            #pragma unroll
            for (int f = 0; f < 4; ++f)
                #pragma unroll
                for (int r = 0; r < 4; ++r)
                    if (k0 + f*16 + lo > qrow + r) sc[f][r] = -1e30f;
        }
        float scale_[4];
        #pragma unroll
        for (int r = 0; r < 4; ++r) {
            float x = fmaxf(fmaxf(sc[0][r], sc[1][r]), fmaxf(sc[2][r], sc[3][r]));
            x = fmaxf(x, __shfl_xor(x, 1));
            x = fmaxf(x, __shfl_xor(x, 2));
            x = fmaxf(x, __shfl_xor(x, 4));
            x = fmaxf(x, __shfl_xor(x, 8));
            float mn = fmaxf(m[r], x);
            scale_[r] = __expf(m[r] - mn);
            m[r] = mn;
            l[r] *= scale_[r];
            acc[0][r] *= scale_[r]; acc[1][r] *= scale_[r];
            acc[2][r] *= scale_[r]; acc[3][r] *= scale_[r];
        }
        float rs[4] = {0.f, 0.f, 0.f, 0.f};
        #pragma unroll
        for (int f = 0; f < 4; ++f)
            #pragma unroll
            for (int r = 0; r < 4; ++r) {
                float e = __expf(sc[f][r] - m[r]);
                rs[r] += e;
                Ps[wid][hi*4 + r][f*16 + lo] = f2h(e);
            }
        #pragma unroll
        for (int r = 0; r < 4; ++r) {
            float x = rs[r];
            x += __shfl_xor(x, 1); x += __shfl_xor(x, 2);
            x += __shfl_xor(x, 4); x += __shfl_xor(x, 8);
            l[r] += x;
        }
        asm volatile("s_waitcnt lgkmcnt(0)" ::: "memory");
        __builtin_amdgcn_sched_barrier(0);
        f16x8 pa0 = *(const f16x8*)&Ps[wid][lo][hi*8];
        f16x8 pa1 = *(const f16x8*)&Ps[wid][lo][32 + hi*8];
        #pragma unroll
        for (int f = 0; f < 4; ++f) {
            f32x4 o = acc[f];
            f16x8 v0 = *(const f16x8*)&Vt[f*16 + lo][hi*8];
            o = __builtin_amdgcn_mfma_f32_16x16x32_f16(pa0, v0, o, 0, 0, 0);
            f16x8 v1 = *(const f16x8*)&Vt[f*16 + lo][32 + hi*8];
            o = __builtin_amdgcn_mfma_f32_16x16x32_f16(pa1, v1, o, 0, 0, 0);
            acc[f] = o;
        }
    }
    const int pbase = head * 80 + s;
    float* po = pO + (size_t)pbase * 4096;
    #pragma unroll
    for (int r = 0; r < 4; ++r)
        #pragma unroll
        for (int f = 0; f < 4; ++f)
            po[(wid*16 + hi*4 + r) * 64 + f*16 + lo] = acc[f][r];
    if (lo == 0) {
        #pragma unroll
        for (int r = 0; r < 4; ++r) {
            pm[pbase*64 + wid*16 + hi*4 + r] = m[r];
            pl[pbase*64 + wid*16 + hi*4 + r] = l[r];
        }
    }
}

// ---------------- combine partials -> fp16 attention output ----------------
__global__ __launch_bounds__(256) void attn_combine_kernel(const float* __restrict__ pO,
        const float* __restrict__ pm, const float* __restrict__ pl,
        short* __restrict__ aoh) {
    const int qi = blockIdx.x, head = blockIdx.y;
    const int nch = qi / 8 + 1;
    int sbase;
    if (qi < 8)       sbase = qi;
    else if (qi < 16) sbase = 8 + (qi - 8) * 2;
    else if (qi < 24) sbase = 24 + (qi - 16) * 3;
    else              sbase = 48 + (qi - 24) * 4;
    const int row = threadIdx.x >> 2;
    const int d0 = (threadIdx.x & 3) * 16;
    float mv[4], lv[4];
    float mx = -1e30f;
    #pragma unroll
    for (int cd = 0; cd < 4; ++cd) {
        if (cd < nch) {
            int p = head * 80 + sbase + cd;
            mv[cd] = pm[p * 64 + row];
            lv[cd] = pl[p * 64 + row];
            mx = fmaxf(mx, mv[cd]);
        } else { mv[cd] = -1e30f; lv[cd] = 0.f; }
    }
    float w[4];
    float lsum = 0.f;
    #pragma unroll
    for (int cd = 0; cd < 4; ++cd) {
        w[cd] = (cd < nch) ? __expf(mv[cd] - mx) : 0.f;
        lsum += w[cd] * lv[cd];
    }
    float inv = 1.0f / lsum;
    float o[16] = {};
    #pragma unroll
    for (int cd = 0; cd < 4; ++cd) {
        if (cd < nch) {
            const float4* po = (const float4*)(pO + ((size_t)(head * 80 + sbase + cd)) * 4096 + row * 64 + d0);
            float wc = w[cd] * inv;
            #pragma unroll
            for (int j = 0; j < 4; ++j) {
                float4 vv = po[j];
                o[j*4+0] += wc * vv.x; o[j*4+1] += wc * vv.y;
                o[j*4+2] += wc * vv.z; o[j*4+3] += wc * vv.w;
            }
        }
    }
    size_t outb = (size_t)(qi * 64 + row) * HID + head * HD + d0;
    s16x8 w0, w1;
    #pragma unroll
    for (int i = 0; i < 8; ++i) { w0[i] = f2h(o[i]); w1[i] = f2h(o[8+i]); }
    *(s16x8*)(aoh + outb) = w0;
    *(s16x8*)(aoh + outb + 8) = w1;
}

// ---------------- gate + top-2 routing (exact fp32, vectorized) ----------------
// 256 threads = 16 tokens/block x 16 lanes/token; float4 loads; gw L1-resident.
__global__ __launch_bounds__(256) void gate_topk_kernel(const float* __restrict__ xn,
                                                        const float* __restrict__ gw,
                                                        int* __restrict__ cnt,
                                                        int* __restrict__ idx,
                                                        float* __restrict__ wt) {
    const int t = blockIdx.x * 16 + (threadIdx.x >> 4);
    const int g = threadIdx.x & 15;
    const float4* xr = (const float4*)(xn + (size_t)t * HID);
    const float4* gr = (const float4*)gw;
    float acc[NE] = {};
    #pragma unroll
    for (int i = 0; i < 16; ++i) {
        float4 x4 = xr[i*16 + g];
        #pragma unroll
        for (int e = 0; e < NE; ++e) {
            float4 g4 = gr[e*256 + i*16 + g];
            acc[e] += x4.x*g4.x + x4.y*g4.y + x4.z*g4.z + x4.w*g4.w;
        }
    }
    #pragma unroll
    for (int e = 0; e < NE; ++e) {
        acc[e] += __shfl_xor(acc[e], 1);
        acc[e] += __shfl_xor(acc[e], 2);
        acc[e] += __shfl_xor(acc[e], 4);
        acc[e] += __shfl_xor(acc[e], 8);
    }
    if (g == 0) {
        float mx = acc[0];
        #pragma unroll
        for (int e = 1; e < NE; ++e) mx = fmaxf(mx, acc[e]);
        float p[NE];
        #pragma unroll
        for (int e = 0; e < NE; ++e) p[e] = __expf(acc[e] - mx);
        int i0 = 0;
        #pragma unroll
        for (int e = 1; e < NE; ++e) if (p[e] > p[i0]) i0 = e;
        int i1 = -1;
        #pragma unroll
        for (int e = 0; e < NE; ++e) if (e != i0 && (i1 < 0 || p[e] > p[i1])) i1 = e;
        float w0 = p[i0], w1 = p[i1];
        float inv = 1.0f / (w0 + w1);
        int s0 = atomicAdd(&cnt[i0], 1);
        idx[i0 * S_LEN + s0] = t; wt[i0 * S_LEN + s0] = w0 * inv;
        int s1 = atomicAdd(&cnt[i1], 1);
        idx[i1 * S_LEN + s1] = t; wt[i1 * S_LEN + s1] = w1 * inv;
    }
}

// ---------------- MoE mlp1 (fp16): ab16 = fp16( silu(x@w1^T) * (x@w3^T) ) ----------------
__global__ __launch_bounds__(256) void moe_mlp1_h16(const short* __restrict__ Xh,
        const short* __restrict__ W1h, const short* __restrict__ W3h,
        const int* __restrict__ cnt, const int* __restrict__ idx,
        short* __restrict__ abh) {
    int e = blockIdx.z;
    int ne = cnt[e];
    int m0 = blockIdx.y * 128;
    if (m0 >= ne) return;
    int f0 = blockIdx.x * 64;
    __shared__ __align__(16) short As[128*40];
    __shared__ __align__(16) short Gs[64*40], Us[64*40];
    __shared__ int rows[128];
    const int tid = threadIdx.x;
    if (tid < 128) {
        int slot = m0 + tid;
        rows[tid] = (slot < ne) ? idx[e * S_LEN + slot] : 0;
    }
    __syncthreads();
    const int lane = tid & 63, lo = lane & 15, hi = lane >> 4;
    const int wid = tid >> 6, wr = wid >> 1, wc = wid & 1;
    const int srow = tid >> 2, scol = (tid & 3) * 8;
    const short* pX0 = Xh + (size_t)rows[srow] * HID + scol;
    const short* pX1 = Xh + (size_t)rows[64 + srow] * HID + scol;
    const short* p1 = W1h + ((size_t)e * FF + f0 + srow) * HID + scol;
    const short* p3 = W3h + ((size_t)e * FF + f0 + srow) * HID + scol;

    f32x4 ag[4][2], au[4][2];
    #pragma unroll
    for (int m = 0; m < 4; ++m)
        #pragma unroll
        for (int n = 0; n < 2; ++n) {
            ag[m][n][0]=0.f; ag[m][n][1]=0.f; ag[m][n][2]=0.f; ag[m][n][3]=0.f;
            au[m][n][0]=0.f; au[m][n][1]=0.f; au[m][n][2]=0.f; au[m][n][3]=0.f;
        }

    for (int k0 = 0; k0 < HID; k0 += 32) {
        s16x8 a0 = *(const s16x8*)(pX0 + k0);
        s16x8 a1 = *(const s16x8*)(pX1 + k0);
        s16x8 g0 = *(const s16x8*)(p1 + k0);
        s16x8 u0 = *(const s16x8*)(p3 + k0);
        __syncthreads();
        *(s16x8*)&As[srow*40 + scol] = a0;
        *(s16x8*)&As[(64+srow)*40 + scol] = a1;
        *(s16x8*)&Gs[srow*40 + scol] = g0;
        *(s16x8*)&Us[srow*40 + scol] = u0;
        __syncthreads();
        f16x8 aF[4], gF[2], uF[2];
        #pragma unroll
        for (int m = 0; m < 4; ++m) aF[m] = *(const f16x8*)&As[(wr*64 + m*16 + lo)*40 + hi*8];
        #pragma unroll
        for (int n = 0; n < 2; ++n) {
            gF[n] = *(const f16x8*)&Gs[(wc*32 + n*16 + lo)*40 + hi*8];
            uF[n] = *(const f16x8*)&Us[(wc*32 + n*16 + lo)*40 + hi*8];
        }
        #pragma unroll
        for (int m = 0; m < 4; ++m)
            #pragma unroll
            for (int n = 0; n < 2; ++n) {
                ag[m][n] = __builtin_amdgcn_mfma_f32_16x16x32_f16(aF[m], gF[n], ag[m][n], 0, 0, 0);
                au[m][n] = __builtin_amdgcn_mfma_f32_16x16x32_f16(aF[m], uF[n], au[m][n], 0, 0, 0);
            }
    }
    #pragma unroll
    for (int m = 0; m < 4; ++m)
        #pragma unroll
        for (int n = 0; n < 2; ++n)
            #pragma unroll
            for (int r = 0; r < 4; ++r) {
                int slot = m0 + wr*64 + m*16 + hi*4 + r;
                if (slot >= ne) continue;
                float g = ag[m][n][r], u = au[m][n][r];
                float a = g * (1.0f / (1.0f + __expf(-g))) * u;
                abh[((size_t)e * S_LEN + slot) * FF + f0 + wc*32 + n*16 + lo] = f2h(a);
            }
}

// ---------------- MoE mlp2 (fp16): h += wt * (a @ w2^T) ----------------
__global__ __launch_bounds__(256) void moe_mlp2_h16(const short* __restrict__ abh,
        const short* __restrict__ W2h,
        const int* __restrict__ cnt, const int* __restrict__ idx,
        const float* __restrict__ wt, float* __restrict__ hbuf) {
    int e = blockIdx.z;
    int ne = cnt[e];
    int m0 = blockIdx.y * 128;
    if (m0 >= ne) return;
    int n0 = blockIdx.x * 128;
    __shared__ __align__(16) short As[128*40], Bs[128*40];
    const int tid = threadIdx.x;
    const int lane = tid & 63, lo = lane & 15, hi = lane >> 4;
    const int wid = tid >> 6, wr = wid >> 1, wc = wid & 1;
    const int srow = tid >> 2, scol = (tid & 3) * 8;
    f32x4 acc[4][4];
    #pragma unroll
    for (int m = 0; m < 4; ++m)
        #pragma unroll
        for (int n = 0; n < 4; ++n) { acc[m][n][0]=0.f; acc[m][n][1]=0.f; acc[m][n][2]=0.f; acc[m][n][3]=0.f; }
    gemm128_core(abh + ((size_t)e*S_LEN + m0 + srow)*FF + scol,
                 abh + ((size_t)e*S_LEN + m0 + 64 + srow)*FF + scol,
                 W2h + ((size_t)e*HID + n0 + srow)*FF + scol,
                 W2h + ((size_t)e*HID + n0 + 64 + srow)*FF + scol,
                 FF, tid, As, Bs, acc);
    #pragma unroll
    for (int m = 0; m < 4; ++m) {
        #pragma unroll
        for (int r = 0; r < 4; ++r) {
            int slot = m0 + wr*64 + m*16 + hi*4 + r;
            if (slot >= ne) continue;
            int tok = idx[e * S_LEN + slot];
            float wv = wt[e * S_LEN + slot];
            #pragma unroll
            for (int n = 0; n < 4; ++n)
                atomicAdd(&hbuf[(size_t)tok * HID + n0 + wc*64 + n*16 + lo], acc[m][n][r] * wv);
        }
    }
}

extern "C" void kernel_launch(void* const* d_in, const int* in_sizes, int n_in,
                              void* d_out, int out_size, void* d_ws, size_t ws_size,
                              hipStream_t stream) {
    const float* emb = (const float*)d_in[0];
    const float* ln1 = (const float*)d_in[1];
    const float* ln2 = (const float*)d_in[2];
    const float* fln = (const float*)d_in[3];
    const float* qw  = (const float*)d_in[4];
    const float* kw  = (const float*)d_in[5];
    const float* vw  = (const float*)d_in[6];
    const float* ow  = (const float*)d_in[7];
    const float* gw  = (const float*)d_in[8];
    const float* w1  = (const float*)d_in[9];
    const float* w2  = (const float*)d_in[10];
    const float* w3  = (const float*)d_in[11];

    float* ws   = (float*)d_ws;
    float* h    = ws + OFF_H;
    float* xn   = ws + OFF_XN;
    float* q    = ws + OFF_Q;
    float* kb   = ws + OFF_K;
    float* vb   = ws + OFF_V;
    float* cosb = ws + OFF_COS;
    float* sinb = ws + OFF_SIN;
    float* wt   = ws + OFF_WT;
    int*   cnt  = (int*)(ws + OFF_INT);
    int*   idx  = cnt + 8;
    short* xh   = (short*)(ws + OFF_XH);
    short* aoh  = (short*)(ws + OFF_AOH);
    short* abh  = (short*)(ws + OFF_ABH);
    float* pO   = ws + OFF_PO;
    float* pm   = ws + OFF_PM;
    float* pl   = ws + OFF_PL;
    short* WC   = (short*)(ws + OFF_WCVT);

    // converted weights (fp16), non-overlapping
    short* sq = WC;
    short* sk = sq + HID*HID;
    short* sv = sk + KVH*HD*HID;
    short* so = sv + KVH*HD*HID;
    short* s1 = so + HID*HID;
    short* s3 = s1 + (size_t)NE*FF*HID;
    short* s2 = s3 + (size_t)NE*FF*HID;

    hipMemcpyAsync(h, emb, (size_t)S_LEN * HID * sizeof(float), hipMemcpyDeviceToDevice, stream);
    rope_tables_kernel<<<S_LEN * 32 / 256, 256, 0, stream>>>(cosb, sinb);

    const int n8_qo = HID*HID/8, n8_kv = KVH*HD*HID/8, n8_w = NE*FF*HID/8;

    for (int l = 0; l < NL; ++l) {
        cvt16_kernel<<<n8_qo/256, 256, 0, stream>>>(qw + (size_t)l*HID*HID, sq, n8_qo);
        cvt16_kernel<<<n8_kv/256, 256, 0, stream>>>(kw + (size_t)l*KVH*HD*HID, sk, n8_kv);
        cvt16_kernel<<<n8_kv/256, 256, 0, stream>>>(vw + (size_t)l*KVH*HD*HID, sv, n8_kv);
        cvt16_kernel<<<n8_qo/256, 256, 0, stream>>>(ow + (size_t)l*HID*HID, so, n8_qo);

        rmsnorm_h16_kernel<<<S_LEN, 256, 0, stream>>>(h, ln1 + l * HID, xn, xh);
        qkv_h16_kernel<<<dim3(12, 16), 256, 0, stream>>>(xh, sq, sk, sv, q, kb, vb);
        rope_apply_kernel<<<(S_LEN * NHEAD * 32) / 256, 256, 0, stream>>>(q, cosb, sinb, NHEAD, S_LEN * NHEAD * 32);
        rope_apply_kernel<<<(S_LEN * KVH * 32) / 256, 256, 0, stream>>>(kb, cosb, sinb, KVH, S_LEN * KVH * 32);
        attn_mfma_kernel<<<dim3(80, NHEAD), 256, 0, stream>>>(q, kb, vb, pO, pm, pl);
        attn_combine_kernel<<<dim3(32, NHEAD), 256, 0, stream>>>(pO, pm, pl, aoh);
        gemm_h16_kernel<<<dim3(8, 16), 256, 0, stream>>>(aoh, so, h, h, HID, HID);

        rmsnorm_h16_kernel<<<S_LEN, 256, 0, stream>>>(h, ln2 + l * HID, xn, xh);
        hipMemsetAsync(cnt, 0, 8 * sizeof(int), stream);
        gate_topk_kernel<<<S_LEN / 16, 256, 0, stream>>>(xn, gw + (size_t)l * NE * HID, cnt, idx, wt);

        cvt16_kernel<<<n8_w/256, 256, 0, stream>>>(w1 + (size_t)l*NE*FF*HID, s1, n8_w);
        cvt16_kernel<<<n8_w/256, 256, 0, stream>>>(w3 + (size_t)l*NE*FF*HID, s3, n8_w);
        moe_mlp1_h16<<<dim3(16, 16, 8), 256, 0, stream>>>(xh, s1, s3, cnt, idx, abh);

        cvt16_kernel<<<n8_w/256, 256, 0, stream>>>(w2 + (size_t)l*NE*HID*FF, s2, n8_w);
        moe_mlp2_h16<<<dim3(8, 16, 8), 256, 0, stream>>>(abh, s2, cnt, idx, wt, h);
    }
    rmsnorm_kernel<<<S_LEN, 256, 0, stream>>>(h, fln, (float*)d_out);
}

// Round 9
// 635.393 us; speedup vs baseline: 1.0761x; 1.0761x over previous
//
#include <hip/hip_runtime.h>
#include <hip/hip_bf16.h>
#include <math.h>

#define S_LEN 2048
#define HID   1024
#define NHEAD 16
#define KVH   4
#define HD    64
#define FF    1024
#define NE    8
#define NL    2

// ---- workspace layout (float offsets) ----
#define OFF_H    0
#define OFF_Q    (OFF_H + S_LEN*HID)
#define OFF_K    (OFF_Q + S_LEN*HID)
#define OFF_V    (OFF_K + S_LEN*KVH*HD)
#define OFF_COS  (OFF_V + S_LEN*KVH*HD)
#define OFF_SIN  (OFF_COS + S_LEN*32)
#define OFF_WT   (OFF_SIN + S_LEN*32)
#define OFF_INT  (OFF_WT + NE*S_LEN)
#define OFF_XH   (OFF_INT + NE*S_LEN + 16)
#define OFF_AOH  (OFF_XH + S_LEN*HID/2)
#define OFF_ABH  (OFF_AOH + S_LEN*HID/2)
#define OFF_PO   (OFF_ABH + NE*S_LEN*FF/2)
#define OFF_PM   (OFF_PO + 80*NHEAD*64*64)
#define OFF_PL   (OFF_PM + 80*NHEAD*64)
#define OFF_WCVT (OFF_PL + 80*NHEAD*64)
// WCVT region (shorts): qkvo 2.5M + w1 8M + w3 8M + w2 8M = 26.5M shorts = 53MB

typedef __attribute__((ext_vector_type(8))) _Float16 f16x8;
typedef __attribute__((ext_vector_type(8))) short  s16x8;
typedef __attribute__((ext_vector_type(4))) float  f32x4;

__device__ __forceinline__ short f2h(float f) {
    union { _Float16 h; short s; } u;
    u.h = (_Float16)f;
    return u.s;
}

__device__ __forceinline__ s16x8 cvt8(float4 a, float4 b) {
    s16x8 w;
    w[0]=f2h(a.x); w[1]=f2h(a.y); w[2]=f2h(a.z); w[3]=f2h(a.w);
    w[4]=f2h(b.x); w[5]=f2h(b.y); w[6]=f2h(b.z); w[7]=f2h(b.w);
    return w;
}

// ---------------- fp32 -> fp16 convert ----------------
__global__ __launch_bounds__(256) void cvt16_kernel(const float* __restrict__ src,
                                                    short* __restrict__ dst, int n8) {
    int gid = blockIdx.x * 256 + threadIdx.x;
    if (gid >= n8) return;
    const float4* s = (const float4*)src + (size_t)gid * 2;
    *(s16x8*)(dst + (size_t)gid * 8) = cvt8(s[0], s[1]);
}

// ---------------- RoPE tables ----------------
__global__ void rope_tables_kernel(float* __restrict__ cosb, float* __restrict__ sinb) {
    int gid = blockIdx.x * 256 + threadIdx.x;
    int t = gid >> 5, i = gid & 31;
    float invf = powf(1.0e6f, -(float)i / 32.0f);
    float ang = (float)t * invf;
    cosb[gid] = cosf(ang);
    sinb[gid] = sinf(ang);
}

// ---------------- RMSNorm -> fp16 only ----------------
__global__ __launch_bounds__(256) void rmsnorm_h16_kernel(const float* __restrict__ x,
                                                          const float* __restrict__ w,
                                                          short* __restrict__ oh) {
    int row = blockIdx.x;
    const float4* xr = (const float4*)(x + (size_t)row * HID);
    float4 xv = xr[threadIdx.x];
    float ss = xv.x*xv.x + xv.y*xv.y + xv.z*xv.z + xv.w*xv.w;
    for (int off = 32; off; off >>= 1) ss += __shfl_xor(ss, off);
    __shared__ float sred[4];
    if ((threadIdx.x & 63) == 0) sred[threadIdx.x >> 6] = ss;
    __syncthreads();
    float tot = sred[0] + sred[1] + sred[2] + sred[3];
    float scale = rsqrtf(tot * (1.0f / (float)HID) + 1e-5f);
    float4 wv = ((const float4*)w)[threadIdx.x];
    float4 o;
    o.x = xv.x * scale * wv.x; o.y = xv.y * scale * wv.y;
    o.z = xv.z * scale * wv.z; o.w = xv.w * scale * wv.w;
    union { short s[4]; float2 f2; } hh;
    hh.s[0]=f2h(o.x); hh.s[1]=f2h(o.y); hh.s[2]=f2h(o.z); hh.s[3]=f2h(o.w);
    ((float2*)(oh + (size_t)row * HID))[threadIdx.x] = hh.f2;
}

// ---------------- RMSNorm + fused gate top-2 routing ----------------
// one block per token; xn stays in registers; gate logits exact fp32.
__global__ __launch_bounds__(256) void rmsnorm_gate_kernel(const float* __restrict__ x,
                                                           const float* __restrict__ w,
                                                           const float* __restrict__ gw,
                                                           short* __restrict__ oh,
                                                           int* __restrict__ cnt,
                                                           int* __restrict__ idx,
                                                           float* __restrict__ wt) {
    int row = blockIdx.x;
    const float4* xr = (const float4*)(x + (size_t)row * HID);
    float4 xv = xr[threadIdx.x];
    float ss = xv.x*xv.x + xv.y*xv.y + xv.z*xv.z + xv.w*xv.w;
    for (int off = 32; off; off >>= 1) ss += __shfl_xor(ss, off);
    __shared__ float sred[4];
    __shared__ float gred[4][NE];
    if ((threadIdx.x & 63) == 0) sred[threadIdx.x >> 6] = ss;
    __syncthreads();
    float tot = sred[0] + sred[1] + sred[2] + sred[3];
    float scale = rsqrtf(tot * (1.0f / (float)HID) + 1e-5f);
    float4 wv = ((const float4*)w)[threadIdx.x];
    float4 o;
    o.x = xv.x * scale * wv.x; o.y = xv.y * scale * wv.y;
    o.z = xv.z * scale * wv.z; o.w = xv.w * scale * wv.w;
    union { short s[4]; float2 f2; } hh;
    hh.s[0]=f2h(o.x); hh.s[1]=f2h(o.y); hh.s[2]=f2h(o.z); hh.s[3]=f2h(o.w);
    ((float2*)(oh + (size_t)row * HID))[threadIdx.x] = hh.f2;
    // gate logits: each thread dots its 4 columns against all 8 expert rows
    const float4* gr = (const float4*)gw;
    float acc[NE];
    #pragma unroll
    for (int e = 0; e < NE; ++e) {
        float4 g4 = gr[e * 256 + threadIdx.x];
        acc[e] = o.x*g4.x + o.y*g4.y + o.z*g4.z + o.w*g4.w;
    }
    #pragma unroll
    for (int e = 0; e < NE; ++e)
        for (int off = 32; off; off >>= 1) acc[e] += __shfl_xor(acc[e], off);
    if ((threadIdx.x & 63) == 0) {
        #pragma unroll
        for (int e = 0; e < NE; ++e) gred[threadIdx.x >> 6][e] = acc[e];
    }
    __syncthreads();
    if (threadIdx.x == 0) {
        float lg[NE];
        #pragma unroll
        for (int e = 0; e < NE; ++e)
            lg[e] = gred[0][e] + gred[1][e] + gred[2][e] + gred[3][e];
        float mx = lg[0];
        #pragma unroll
        for (int e = 1; e < NE; ++e) mx = fmaxf(mx, lg[e]);
        float p[NE];
        #pragma unroll
        for (int e = 0; e < NE; ++e) p[e] = __expf(lg[e] - mx);
        int i0 = 0;
        #pragma unroll
        for (int e = 1; e < NE; ++e) if (p[e] > p[i0]) i0 = e;
        int i1 = -1;
        #pragma unroll
        for (int e = 0; e < NE; ++e) if (e != i0 && (i1 < 0 || p[e] > p[i1])) i1 = e;
        float w0 = p[i0], w1 = p[i1];
        float inv = 1.0f / (w0 + w1);
        int s0 = atomicAdd(&cnt[i0], 1);
        idx[i0 * S_LEN + s0] = row; wt[i0 * S_LEN + s0] = w0 * inv;
        int s1 = atomicAdd(&cnt[i1], 1);
        idx[i1 * S_LEN + s1] = row; wt[i1 * S_LEN + s1] = w1 * inv;
    }
}

// plain rmsnorm for final output (fp32)
__global__ __launch_bounds__(256) void rmsnorm_kernel(const float* __restrict__ x,
                                                      const float* __restrict__ w,
                                                      float* __restrict__ out) {
    int row = blockIdx.x;
    const float4* xr = (const float4*)(x + (size_t)row * HID);
    float4 xv = xr[threadIdx.x];
    float ss = xv.x*xv.x + xv.y*xv.y + xv.z*xv.z + xv.w*xv.w;
    for (int off = 32; off; off >>= 1) ss += __shfl_xor(ss, off);
    __shared__ float sred[4];
    if ((threadIdx.x & 63) == 0) sred[threadIdx.x >> 6] = ss;
    __syncthreads();
    float tot = sred[0] + sred[1] + sred[2] + sred[3];
    float scale = rsqrtf(tot * (1.0f / (float)HID) + 1e-5f);
    float4 wv = ((const float4*)w)[threadIdx.x];
    float4 o;
    o.x = xv.x * scale * wv.x; o.y = xv.y * scale * wv.y;
    o.z = xv.z * scale * wv.z; o.w = xv.w * scale * wv.w;
    ((float4*)(out + (size_t)row * HID))[threadIdx.x] = o;
}

// ---------------- RoPE apply ----------------
__global__ void rope_apply_kernel(float* __restrict__ p, const float* __restrict__ cosb,
                                  const float* __restrict__ sinb, int nh, int total) {
    int gid = blockIdx.x * 256 + threadIdx.x;
    if (gid >= total) return;
    int per = nh * 32;
    int t = gid / per, r = gid % per;
    int hh = r >> 5, i = r & 31;
    float c = cosb[t*32 + i], s = sinb[t*32 + i];
    float* base = p + (size_t)t * (nh * HD) + hh * HD + i;
    float a = base[0], b = base[32];
    base[0]  = a * c - b * s;
    base[32] = b * c + a * s;
}

// ---------------- single-pass fp16 128x128 GEMM core ----------------
__device__ __forceinline__ void gemm128_core(
        const short* pA0, const short* pA1, const short* pB0, const short* pB1,
        int Kd, int tid, short* As, short* Bs, f32x4 (&acc)[4][4]) {
    const int lane = tid & 63, lo = lane & 15, hi = lane >> 4;
    const int wid = tid >> 6, wr = wid >> 1, wc = wid & 1;
    const int srow = tid >> 2, scol = (tid & 3) * 8;
    for (int k0 = 0; k0 < Kd; k0 += 32) {
        s16x8 a0 = *(const s16x8*)(pA0 + k0);
        s16x8 a1 = *(const s16x8*)(pA1 + k0);
        s16x8 b0 = *(const s16x8*)(pB0 + k0);
        s16x8 b1 = *(const s16x8*)(pB1 + k0);
        __syncthreads();
        *(s16x8*)&As[srow*40 + scol] = a0;
        *(s16x8*)&As[(64+srow)*40 + scol] = a1;
        *(s16x8*)&Bs[srow*40 + scol] = b0;
        *(s16x8*)&Bs[(64+srow)*40 + scol] = b1;
        __syncthreads();
        f16x8 aF[4], bF[4];
        #pragma unroll
        for (int m = 0; m < 4; ++m) aF[m] = *(const f16x8*)&As[(wr*64 + m*16 + lo)*40 + hi*8];
        #pragma unroll
        for (int n = 0; n < 4; ++n) bF[n] = *(const f16x8*)&Bs[(wc*64 + n*16 + lo)*40 + hi*8];
        #pragma unroll
        for (int m = 0; m < 4; ++m)
            #pragma unroll
            for (int n = 0; n < 4; ++n)
                acc[m][n] = __builtin_amdgcn_mfma_f32_16x16x32_f16(aF[m], bF[n], acc[m][n], 0, 0, 0);
    }
}

// ---------------- generic fp16 GEMM: C = A@B^T (+resid) ----------------
__global__ __launch_bounds__(256) void gemm_h16_kernel(const short* __restrict__ Ag,
        const short* __restrict__ Bg, float* __restrict__ C,
        const float* __restrict__ resid, int N, int Kd) {
    __shared__ __align__(16) short As[128*40], Bs[128*40];
    const int tid = threadIdx.x;
    const int lane = tid & 63, lo = lane & 15, hi = lane >> 4;
    const int wid = tid >> 6, wr = wid >> 1, wc = wid & 1;
    const int m0 = blockIdx.y * 128, n0 = blockIdx.x * 128;
    const int srow = tid >> 2, scol = (tid & 3) * 8;
    f32x4 acc[4][4];
    #pragma unroll
    for (int m = 0; m < 4; ++m)
        #pragma unroll
        for (int n = 0; n < 4; ++n) { acc[m][n][0]=0.f; acc[m][n][1]=0.f; acc[m][n][2]=0.f; acc[m][n][3]=0.f; }
    gemm128_core(Ag + (size_t)(m0+srow)*Kd + scol, Ag + (size_t)(m0+64+srow)*Kd + scol,
                 Bg + (size_t)(n0+srow)*Kd + scol, Bg + (size_t)(n0+64+srow)*Kd + scol,
                 Kd, tid, As, Bs, acc);
    #pragma unroll
    for (int m = 0; m < 4; ++m)
        #pragma unroll
        for (int n = 0; n < 4; ++n)
            #pragma unroll
            for (int r = 0; r < 4; ++r) {
                int row = m0 + wr*64 + m*16 + hi*4 + r;
                int col = n0 + wc*64 + n*16 + lo;
                float val = acc[m][n][r];
                if (resid) val += resid[(size_t)row * N + col];
                C[(size_t)row * N + col] = val;
            }
}

// ---------------- fused QKV GEMM (fp16) ----------------
__global__ __launch_bounds__(256) void qkv_h16_kernel(const short* __restrict__ Xh,
        const short* __restrict__ qw16, const short* __restrict__ kw16,
        const short* __restrict__ vw16,
        float* __restrict__ qo, float* __restrict__ ko, float* __restrict__ vo) {
    __shared__ __align__(16) short As[128*40], Bs[128*40];
    const int bx = blockIdx.x;
    const short* Bp; float* Cp; int Nc, n0;
    if (bx < 8)       { Bp = qw16; Cp = qo; Nc = 1024; n0 = bx * 128; }
    else if (bx < 10) { Bp = kw16; Cp = ko; Nc = 256;  n0 = (bx - 8) * 128; }
    else              { Bp = vw16; Cp = vo; Nc = 256;  n0 = (bx - 10) * 128; }
    const int tid = threadIdx.x;
    const int lane = tid & 63, lo = lane & 15, hi = lane >> 4;
    const int wid = tid >> 6, wr = wid >> 1, wc = wid & 1;
    const int m0 = blockIdx.y * 128;
    const int srow = tid >> 2, scol = (tid & 3) * 8;
    f32x4 acc[4][4];
    #pragma unroll
    for (int m = 0; m < 4; ++m)
        #pragma unroll
        for (int n = 0; n < 4; ++n) { acc[m][n][0]=0.f; acc[m][n][1]=0.f; acc[m][n][2]=0.f; acc[m][n][3]=0.f; }
    gemm128_core(Xh + (size_t)(m0+srow)*HID + scol, Xh + (size_t)(m0+64+srow)*HID + scol,
                 Bp + (size_t)(n0+srow)*HID + scol, Bp + (size_t)(n0+64+srow)*HID + scol,
                 HID, tid, As, Bs, acc);
    #pragma unroll
    for (int m = 0; m < 4; ++m)
        #pragma unroll
        for (int n = 0; n < 4; ++n)
            #pragma unroll
            for (int r = 0; r < 4; ++r) {
                int row = m0 + wr*64 + m*16 + hi*4 + r;
                int col = n0 + wc*64 + n*16 + lo;
                Cp[(size_t)row * Nc + col] = acc[m][n][r];
            }
}

// ---------------- split-K fp16 MFMA flash attention -> partials ----------------
// grid (80, NHEAD): slot -> (q-tile, key-chunk of <=8 tiles). Long chunks first.
__global__ __launch_bounds__(256) void attn_mfma_kernel(const float* __restrict__ q,
                                                        const float* __restrict__ k,
                                                        const float* __restrict__ v,
                                                        float* __restrict__ pO,
                                                        float* __restrict__ pm,
                                                        float* __restrict__ pl) {
    __shared__ __align__(16) short Ks[64][72];
    __shared__ __align__(16) short Vt[64][72];
    __shared__ __align__(16) short Ps[4][16][72];
    const int wid = threadIdx.x >> 6, lane = threadIdx.x & 63;
    const int lo = lane & 15, hi = lane >> 4;
    const int head = blockIdx.y;
    const int s = 79 - blockIdx.x;            // long chunks dispatched first
    int qi, c;
    if (s < 8)       { qi = s;                     c = 0; }
    else if (s < 24) { int t = s - 8;  qi = 8  + (t >> 1); c = t & 1; }
    else if (s < 48) { int t = s - 24; qi = 16 + t / 3;    c = t % 3; }
    else             { int t = s - 48; qi = 24 + (t >> 2); c = t & 3; }
    const int t_beg = c * 8;
    const int t_end = min(t_beg + 8, qi + 1);
    const int q0 = qi * 64;
    const int kvh = head >> 2;

    f16x8 qf[2];
    {
        const float* qr = q + (size_t)(q0 + wid*16 + lo) * HID + head*HD;
        #pragma unroll
        for (int kk = 0; kk < 2; ++kk)
            #pragma unroll
            for (int i = 0; i < 8; ++i)
                qf[kk][i] = (_Float16)qr[kk*32 + hi*8 + i];
    }

    f32x4 acc[4];
    float m[4], l[4];
    #pragma unroll
    for (int r = 0; r < 4; ++r) {
        m[r] = -1e30f; l[r] = 0.f;
        acc[0][r] = 0.f; acc[1][r] = 0.f; acc[2][r] = 0.f; acc[3][r] = 0.f;
    }

    const int skey = threadIdx.x >> 2;
    const int sdg  = (threadIdx.x & 3) * 16;

    // prefetch tile t_beg into registers
    float4 ka0, ka1, ka2, ka3, vv0, vv1, vv2, vv3;
    {
        const float* kr = k + (size_t)(t_beg*64 + skey)*(KVH*HD) + kvh*HD + sdg;
        ka0 = ((const float4*)kr)[0]; ka1 = ((const float4*)kr)[1];
        ka2 = ((const float4*)kr)[2]; ka3 = ((const float4*)kr)[3];
        const float* vr = v + (size_t)(t_beg*64 + skey)*(KVH*HD) + kvh*HD + sdg;
        vv0 = ((const float4*)vr)[0]; vv1 = ((const float4*)vr)[1];
        vv2 = ((const float4*)vr)[2]; vv3 = ((const float4*)vr)[3];
    }

    for (int t = t_beg; t < t_end; ++t) {
        __syncthreads();   // previous tile's LDS reads complete
        *(s16x8*)&Ks[skey][sdg]     = cvt8(ka0, ka1);
        *(s16x8*)&Ks[skey][sdg + 8] = cvt8(ka2, ka3);
        Vt[sdg+ 0][skey]=f2h(vv0.x); Vt[sdg+ 1][skey]=f2h(vv0.y);
        Vt[sdg+ 2][skey]=f2h(vv0.z); Vt[sdg+ 3][skey]=f2h(vv0.w);
        Vt[sdg+ 4][skey]=f2h(vv1.x); Vt[sdg+ 5][skey]=f2h(vv1.y);
        Vt[sdg+ 6][skey]=f2h(vv1.z); Vt[sdg+ 7][skey]=f2h(vv1.w);
        Vt[sdg+ 8][skey]=f2h(vv2.x); Vt[sdg+ 9][skey]=f2h(vv2.y);
        Vt[sdg+10][skey]=f2h(vv2.z); Vt[sdg+11][skey]=f2h(vv2.w);
        Vt[sdg+12][skey]=f2h(vv3.x); Vt[sdg+13][skey]=f2h(vv3.y);
        Vt[sdg+14][skey]=f2h(vv3.z); Vt[sdg+15][skey]=f2h(vv3.w);
        __syncthreads();
        if (t + 1 < t_end) {  // issue next-tile loads; latency hides under compute
            const float* kr = k + (size_t)((t+1)*64 + skey)*(KVH*HD) + kvh*HD + sdg;
            ka0 = ((const float4*)kr)[0]; ka1 = ((const float4*)kr)[1];
            ka2 = ((const float4*)kr)[2]; ka3 = ((const float4*)kr)[3];
            const float* vr = v + (size_t)((t+1)*64 + skey)*(KVH*HD) + kvh*HD + sdg;
            vv0 = ((const float4*)vr)[0]; vv1 = ((const float4*)vr)[1];
            vv2 = ((const float4*)vr)[2]; vv3 = ((const float4*)vr)[3];
        }
        const int k0 = t * 64;
        f32x4 sc[4];
        #pragma unroll
        for (int f = 0; f < 4; ++f) {
            f32x4 sf; sf[0]=0.f; sf[1]=0.f; sf[2]=0.f; sf[3]=0.f;
            f16x8 bk0 = *(const f16x8*)&Ks[f*16 + lo][hi*8];
            sf = __builtin_amdgcn_mfma_f32_16x16x32_f16(qf[0], bk0, sf, 0, 0, 0);
            f16x8 bk1 = *(const f16x8*)&Ks[f*16 + lo][32 + hi*8];
            sf = __builtin_amdgcn_mfma_f32_16x16x32_f16(qf[1], bk1, sf, 0, 0, 0);
            sc[f] = sf;
        }
        #pragma unroll
        for (int f = 0; f < 4; ++f)
            #pragma unroll
            for (int r = 0; r < 4; ++r) sc[f][r] *= 0.125f;
        if (t == qi) {   // diagonal tile: causal mask
            int qrow = q0 + wid*16 + hi*4;
            #pragma unroll
            for (int f = 0; f < 4; ++f)
                #pragma unroll
                for (int r = 0; r < 4; ++r)
                    if (k0 + f*16 + lo > qrow + r) sc[f][r] = -1e30f;
        }
        float scale_[4];
        #pragma unroll
        for (int r = 0; r < 4; ++r) {
            float x = fmaxf(fmaxf(sc[0][r], sc[1][r]), fmaxf(sc[2][r], sc[3][r]));
            x = fmaxf(x, __shfl_xor(x, 1));
            x = fmaxf(x, __shfl_xor(x, 2));
            x = fmaxf(x, __shfl_xor(x, 4));
            x = fmaxf(x, __shfl_xor(x, 8));
            float mn = fmaxf(m[r], x);
            scale_[r] = __expf(m[r] - mn);
            m[r] = mn;
            l[r] *= scale_[r];
            acc[0][r] *= scale_[r]; acc[1][r] *= scale_[r];
            acc[2][r] *= scale_[r]; acc[3][r] *= scale_[r];
        }
        float rs[4] = {0.f, 0.f, 0.f, 0.f};
        #pragma unroll
        for (int f = 0; f < 4; ++f)
            #pragma unroll
            for (int r = 0; r < 4; ++r) {
                float e = __expf(sc[f][r] - m[r]);
                rs[r] += e;
                Ps[wid][hi*4 + r][f*16 + lo] = f2h(e);
            }
        #pragma unroll
        for (int r = 0; r < 4; ++r) {
            float x = rs[r];
            x += __shfl_xor(x, 1); x += __shfl_xor(x, 2);
            x += __shfl_xor(x, 4); x += __shfl_xor(x, 8);
            l[r] += x;
        }
        asm volatile("s_waitcnt lgkmcnt(0)" ::: "memory");
        __builtin_amdgcn_sched_barrier(0);
        f16x8 pa0 = *(const f16x8*)&Ps[wid][lo][hi*8];
        f16x8 pa1 = *(const f16x8*)&Ps[wid][lo][32 + hi*8];
        #pragma unroll
        for (int f = 0; f < 4; ++f) {
            f32x4 o = acc[f];
            f16x8 v0 = *(const f16x8*)&Vt[f*16 + lo][hi*8];
            o = __builtin_amdgcn_mfma_f32_16x16x32_f16(pa0, v0, o, 0, 0, 0);
            f16x8 v1 = *(const f16x8*)&Vt[f*16 + lo][32 + hi*8];
            o = __builtin_amdgcn_mfma_f32_16x16x32_f16(pa1, v1, o, 0, 0, 0);
            acc[f] = o;
        }
    }
    const int pbase = head * 80 + s;
    float* po = pO + (size_t)pbase * 4096;
    #pragma unroll
    for (int r = 0; r < 4; ++r)
        #pragma unroll
        for (int f = 0; f < 4; ++f)
            po[(wid*16 + hi*4 + r) * 64 + f*16 + lo] = acc[f][r];
    if (lo == 0) {
        #pragma unroll
        for (int r = 0; r < 4; ++r) {
            pm[pbase*64 + wid*16 + hi*4 + r] = m[r];
            pl[pbase*64 + wid*16 + hi*4 + r] = l[r];
        }
    }
}

// ---------------- combine partials -> fp16 attention output ----------------
__global__ __launch_bounds__(256) void attn_combine_kernel(const float* __restrict__ pO,
        const float* __restrict__ pm, const float* __restrict__ pl,
        short* __restrict__ aoh) {
    const int qi = blockIdx.x, head = blockIdx.y;
    const int nch = qi / 8 + 1;
    int sbase;
    if (qi < 8)       sbase = qi;
    else if (qi < 16) sbase = 8 + (qi - 8) * 2;
    else if (qi < 24) sbase = 24 + (qi - 16) * 3;
    else              sbase = 48 + (qi - 24) * 4;
    const int row = threadIdx.x >> 2;
    const int d0 = (threadIdx.x & 3) * 16;
    float mv[4], lv[4];
    float mx = -1e30f;
    #pragma unroll
    for (int cd = 0; cd < 4; ++cd) {
        if (cd < nch) {
            int p = head * 80 + sbase + cd;
            mv[cd] = pm[p * 64 + row];
            lv[cd] = pl[p * 64 + row];
            mx = fmaxf(mx, mv[cd]);
        } else { mv[cd] = -1e30f; lv[cd] = 0.f; }
    }
    float w[4];
    float lsum = 0.f;
    #pragma unroll
    for (int cd = 0; cd < 4; ++cd) {
        w[cd] = (cd < nch) ? __expf(mv[cd] - mx) : 0.f;
        lsum += w[cd] * lv[cd];
    }
    float inv = 1.0f / lsum;
    float o[16] = {};
    #pragma unroll
    for (int cd = 0; cd < 4; ++cd) {
        if (cd < nch) {
            const float4* po = (const float4*)(pO + ((size_t)(head * 80 + sbase + cd)) * 4096 + row * 64 + d0);
            float wc = w[cd] * inv;
            #pragma unroll
            for (int j = 0; j < 4; ++j) {
                float4 vv = po[j];
                o[j*4+0] += wc * vv.x; o[j*4+1] += wc * vv.y;
                o[j*4+2] += wc * vv.z; o[j*4+3] += wc * vv.w;
            }
        }
    }
    size_t outb = (size_t)(qi * 64 + row) * HID + head * HD + d0;
    s16x8 w0, w1;
    #pragma unroll
    for (int i = 0; i < 8; ++i) { w0[i] = f2h(o[i]); w1[i] = f2h(o[8+i]); }
    *(s16x8*)(aoh + outb) = w0;
    *(s16x8*)(aoh + outb + 8) = w1;
}

// ---------------- MoE mlp1 (fp16): ab16 = fp16( silu(x@w1^T) * (x@w3^T) ) ----------------
__global__ __launch_bounds__(256) void moe_mlp1_h16(const short* __restrict__ Xh,
        const short* __restrict__ W1h, const short* __restrict__ W3h,
        const int* __restrict__ cnt, const int* __restrict__ idx,
        short* __restrict__ abh) {
    int e = blockIdx.z;
    int ne = cnt[e];
    int m0 = blockIdx.y * 128;
    if (m0 >= ne) return;
    int f0 = blockIdx.x * 64;
    __shared__ __align__(16) short As[128*40];
    __shared__ __align__(16) short Gs[64*40], Us[64*40];
    __shared__ int rows[128];
    const int tid = threadIdx.x;
    if (tid < 128) {
        int slot = m0 + tid;
        rows[tid] = (slot < ne) ? idx[e * S_LEN + slot] : 0;
    }
    __syncthreads();
    const int lane = tid & 63, lo = lane & 15, hi = lane >> 4;
    const int wid = tid >> 6, wr = wid >> 1, wc = wid & 1;
    const int srow = tid >> 2, scol = (tid & 3) * 8;
    const short* pX0 = Xh + (size_t)rows[srow] * HID + scol;
    const short* pX1 = Xh + (size_t)rows[64 + srow] * HID + scol;
    const short* p1 = W1h + ((size_t)e * FF + f0 + srow) * HID + scol;
    const short* p3 = W3h + ((size_t)e * FF + f0 + srow) * HID + scol;

    f32x4 ag[4][2], au[4][2];
    #pragma unroll
    for (int m = 0; m < 4; ++m)
        #pragma unroll
        for (int n = 0; n < 2; ++n) {
            ag[m][n][0]=0.f; ag[m][n][1]=0.f; ag[m][n][2]=0.f; ag[m][n][3]=0.f;
            au[m][n][0]=0.f; au[m][n][1]=0.f; au[m][n][2]=0.f; au[m][n][3]=0.f;
        }

    for (int k0 = 0; k0 < HID; k0 += 32) {
        s16x8 a0 = *(const s16x8*)(pX0 + k0);
        s16x8 a1 = *(const s16x8*)(pX1 + k0);
        s16x8 g0 = *(const s16x8*)(p1 + k0);
        s16x8 u0 = *(const s16x8*)(p3 + k0);
        __syncthreads();
        *(s16x8*)&As[srow*40 + scol] = a0;
        *(s16x8*)&As[(64+srow)*40 + scol] = a1;
        *(s16x8*)&Gs[srow*40 + scol] = g0;
        *(s16x8*)&Us[srow*40 + scol] = u0;
        __syncthreads();
        f16x8 aF[4], gF[2], uF[2];
        #pragma unroll
        for (int m = 0; m < 4; ++m) aF[m] = *(const f16x8*)&As[(wr*64 + m*16 + lo)*40 + hi*8];
        #pragma unroll
        for (int n = 0; n < 2; ++n) {
            gF[n] = *(const f16x8*)&Gs[(wc*32 + n*16 + lo)*40 + hi*8];
            uF[n] = *(const f16x8*)&Us[(wc*32 + n*16 + lo)*40 + hi*8];
        }
        #pragma unroll
        for (int m = 0; m < 4; ++m)
            #pragma unroll
            for (int n = 0; n < 2; ++n) {
                ag[m][n] = __builtin_amdgcn_mfma_f32_16x16x32_f16(aF[m], gF[n], ag[m][n], 0, 0, 0);
                au[m][n] = __builtin_amdgcn_mfma_f32_16x16x32_f16(aF[m], uF[n], au[m][n], 0, 0, 0);
            }
    }
    #pragma unroll
    for (int m = 0; m < 4; ++m)
        #pragma unroll
        for (int n = 0; n < 2; ++n)
            #pragma unroll
            for (int r = 0; r < 4; ++r) {
                int slot = m0 + wr*64 + m*16 + hi*4 + r;
                if (slot >= ne) continue;
                float g = ag[m][n][r], u = au[m][n][r];
                float a = g * (1.0f / (1.0f + __expf(-g))) * u;
                abh[((size_t)e * S_LEN + slot) * FF + f0 + wc*32 + n*16 + lo] = f2h(a);
            }
}

// ---------------- MoE mlp2 (fp16): h += wt * (a @ w2^T) ----------------
__global__ __launch_bounds__(256) void moe_mlp2_h16(const short* __restrict__ abh,
        const short* __restrict__ W2h,
        const int* __restrict__ cnt, const int* __restrict__ idx,
        const float* __restrict__ wt, float* __restrict__ hbuf) {
    int e = blockIdx.z;
    int ne = cnt[e];
    int m0 = blockIdx.y * 128;
    if (m0 >= ne) return;
    int n0 = blockIdx.x * 128;
    __shared__ __align__(16) short As[128*40], Bs[128*40];
    const int tid = threadIdx.x;
    const int lane = tid & 63, lo = lane & 15, hi = lane >> 4;
    const int wid = tid >> 6, wr = wid >> 1, wc = wid & 1;
    const int srow = tid >> 2, scol = (tid & 3) * 8;
    f32x4 acc[4][4];
    #pragma unroll
    for (int m = 0; m < 4; ++m)
        #pragma unroll
        for (int n = 0; n < 4; ++n) { acc[m][n][0]=0.f; acc[m][n][1]=0.f; acc[m][n][2]=0.f; acc[m][n][3]=0.f; }
    gemm128_core(abh + ((size_t)e*S_LEN + m0 + srow)*FF + scol,
                 abh + ((size_t)e*S_LEN + m0 + 64 + srow)*FF + scol,
                 W2h + ((size_t)e*HID + n0 + srow)*FF + scol,
                 W2h + ((size_t)e*HID + n0 + 64 + srow)*FF + scol,
                 FF, tid, As, Bs, acc);
    #pragma unroll
    for (int m = 0; m < 4; ++m) {
        #pragma unroll
        for (int r = 0; r < 4; ++r) {
            int slot = m0 + wr*64 + m*16 + hi*4 + r;
            if (slot >= ne) continue;
            int tok = idx[e * S_LEN + slot];
            float wv = wt[e * S_LEN + slot];
            #pragma unroll
            for (int n = 0; n < 4; ++n)
                atomicAdd(&hbuf[(size_t)tok * HID + n0 + wc*64 + n*16 + lo], acc[m][n][r] * wv);
        }
    }
}

extern "C" void kernel_launch(void* const* d_in, const int* in_sizes, int n_in,
                              void* d_out, int out_size, void* d_ws, size_t ws_size,
                              hipStream_t stream) {
    const float* emb = (const float*)d_in[0];
    const float* ln1 = (const float*)d_in[1];
    const float* ln2 = (const float*)d_in[2];
    const float* fln = (const float*)d_in[3];
    const float* qw  = (const float*)d_in[4];
    const float* kw  = (const float*)d_in[5];
    const float* vw  = (const float*)d_in[6];
    const float* ow  = (const float*)d_in[7];
    const float* gw  = (const float*)d_in[8];
    const float* w1  = (const float*)d_in[9];
    const float* w2  = (const float*)d_in[10];
    const float* w3  = (const float*)d_in[11];

    float* ws   = (float*)d_ws;
    float* h    = ws + OFF_H;
    float* q    = ws + OFF_Q;
    float* kb   = ws + OFF_K;
    float* vb   = ws + OFF_V;
    float* cosb = ws + OFF_COS;
    float* sinb = ws + OFF_SIN;
    float* wt   = ws + OFF_WT;
    int*   cnt  = (int*)(ws + OFF_INT);
    int*   idx  = cnt + 8;
    short* xh   = (short*)(ws + OFF_XH);
    short* aoh  = (short*)(ws + OFF_AOH);
    short* abh  = (short*)(ws + OFF_ABH);
    float* pO   = ws + OFF_PO;
    float* pm   = ws + OFF_PM;
    float* pl   = ws + OFF_PL;
    short* WC   = (short*)(ws + OFF_WCVT);

    // converted weights (fp16), non-overlapping
    short* sq = WC;
    short* sk = sq + HID*HID;
    short* sv = sk + KVH*HD*HID;
    short* so = sv + KVH*HD*HID;
    short* s1 = so + HID*HID;
    short* s3 = s1 + (size_t)NE*FF*HID;
    short* s2 = s3 + (size_t)NE*FF*HID;

    hipMemcpyAsync(h, emb, (size_t)S_LEN * HID * sizeof(float), hipMemcpyDeviceToDevice, stream);
    rope_tables_kernel<<<S_LEN * 32 / 256, 256, 0, stream>>>(cosb, sinb);

    const int n8_qo = HID*HID/8, n8_kv = KVH*HD*HID/8, n8_w = NE*FF*HID/8;

    for (int l = 0; l < NL; ++l) {
        cvt16_kernel<<<n8_qo/256, 256, 0, stream>>>(qw + (size_t)l*HID*HID, sq, n8_qo);
        cvt16_kernel<<<n8_kv/256, 256, 0, stream>>>(kw + (size_t)l*KVH*HD*HID, sk, n8_kv);
        cvt16_kernel<<<n8_kv/256, 256, 0, stream>>>(vw + (size_t)l*KVH*HD*HID, sv, n8_kv);
        cvt16_kernel<<<n8_qo/256, 256, 0, stream>>>(ow + (size_t)l*HID*HID, so, n8_qo);

        rmsnorm_h16_kernel<<<S_LEN, 256, 0, stream>>>(h, ln1 + l * HID, xh);
        qkv_h16_kernel<<<dim3(12, 16), 256, 0, stream>>>(xh, sq, sk, sv, q, kb, vb);
        rope_apply_kernel<<<(S_LEN * NHEAD * 32) / 256, 256, 0, stream>>>(q, cosb, sinb, NHEAD, S_LEN * NHEAD * 32);
        rope_apply_kernel<<<(S_LEN * KVH * 32) / 256, 256, 0, stream>>>(kb, cosb, sinb, KVH, S_LEN * KVH * 32);
        attn_mfma_kernel<<<dim3(80, NHEAD), 256, 0, stream>>>(q, kb, vb, pO, pm, pl);
        attn_combine_kernel<<<dim3(32, NHEAD), 256, 0, stream>>>(pO, pm, pl, aoh);
        gemm_h16_kernel<<<dim3(8, 16), 256, 0, stream>>>(aoh, so, h, h, HID, HID);

        hipMemsetAsync(cnt, 0, 8 * sizeof(int), stream);
        rmsnorm_gate_kernel<<<S_LEN, 256, 0, stream>>>(h, ln2 + l * HID, gw + (size_t)l * NE * HID,
                                                       xh, cnt, idx, wt);

        cvt16_kernel<<<n8_w/256, 256, 0, stream>>>(w1 + (size_t)l*NE*FF*HID, s1, n8_w);
        cvt16_kernel<<<n8_w/256, 256, 0, stream>>>(w3 + (size_t)l*NE*FF*HID, s3, n8_w);
        moe_mlp1_h16<<<dim3(16, 16, 8), 256, 0, stream>>>(xh, s1, s3, cnt, idx, abh);

        cvt16_kernel<<<n8_w/256, 256, 0, stream>>>(w2 + (size_t)l*NE*HID*FF, s2, n8_w);
        moe_mlp2_h16<<<dim3(8, 16, 8), 256, 0, stream>>>(abh, s2, cnt, idx, wt, h);
    }
    rmsnorm_kernel<<<S_LEN, 256, 0, stream>>>(h, fln, (float*)d_out);
}

// Round 10
// 618.433 us; speedup vs baseline: 1.1056x; 1.0274x over previous
//
#include <hip/hip_runtime.h>
#include <hip/hip_bf16.h>
#include <math.h>

#define S_LEN 2048
#define HID   1024
#define NHEAD 16
#define KVH   4
#define HD    64
#define FF    1024
#define NE    8
#define NL    2

// ---- workspace layout (float offsets) ----
#define OFF_H    0
#define OFF_Q    (OFF_H + S_LEN*HID)
#define OFF_K    (OFF_Q + S_LEN*HID)
#define OFF_V    (OFF_K + S_LEN*KVH*HD)
#define OFF_COS  (OFF_V + S_LEN*KVH*HD)
#define OFF_SIN  (OFF_COS + S_LEN*32)
#define OFF_WT   (OFF_SIN + S_LEN*32)
#define OFF_INT  (OFF_WT + NE*S_LEN)
#define OFF_XH   (OFF_INT + NE*S_LEN + 16)
#define OFF_AOH  (OFF_XH + S_LEN*HID/2)
#define OFF_ABH  (OFF_AOH + S_LEN*HID/2)
#define OFF_Q16  (OFF_ABH + NE*S_LEN*FF/2)
#define OFF_K16  (OFF_Q16 + S_LEN*HID/2)
#define OFF_VT16 (OFF_K16 + S_LEN*KVH*HD/2)
#define OFF_PO   (OFF_VT16 + S_LEN*KVH*HD/2)
#define OFF_PM   (OFF_PO + 80*NHEAD*64*64)
#define OFF_PL   (OFF_PM + 80*NHEAD*64)
#define OFF_WCVT (OFF_PL + 80*NHEAD*64)
// WCVT region (shorts): qkvo 2.5M + w1 8M + w3 8M + w2 8M = 26.5M shorts = 53MB

typedef __attribute__((ext_vector_type(8))) _Float16 f16x8;
typedef __attribute__((ext_vector_type(8))) short  s16x8;
typedef __attribute__((ext_vector_type(4))) float  f32x4;

__device__ __forceinline__ short f2h(float f) {
    union { _Float16 h; short s; } u;
    u.h = (_Float16)f;
    return u.s;
}

__device__ __forceinline__ s16x8 cvt8(float4 a, float4 b) {
    s16x8 w;
    w[0]=f2h(a.x); w[1]=f2h(a.y); w[2]=f2h(a.z); w[3]=f2h(a.w);
    w[4]=f2h(b.x); w[5]=f2h(b.y); w[6]=f2h(b.z); w[7]=f2h(b.w);
    return w;
}

// ---------------- fp32 -> fp16 convert ----------------
__global__ __launch_bounds__(256) void cvt16_kernel(const float* __restrict__ src,
                                                    short* __restrict__ dst, int n8) {
    int gid = blockIdx.x * 256 + threadIdx.x;
    if (gid >= n8) return;
    const float4* s = (const float4*)src + (size_t)gid * 2;
    *(s16x8*)(dst + (size_t)gid * 8) = cvt8(s[0], s[1]);
}

// ---------------- RoPE tables ----------------
__global__ void rope_tables_kernel(float* __restrict__ cosb, float* __restrict__ sinb) {
    int gid = blockIdx.x * 256 + threadIdx.x;
    int t = gid >> 5, i = gid & 31;
    float invf = powf(1.0e6f, -(float)i / 32.0f);
    float ang = (float)t * invf;
    cosb[gid] = cosf(ang);
    sinb[gid] = sinf(ang);
}

// ---------------- RMSNorm -> fp16 only ----------------
__global__ __launch_bounds__(256) void rmsnorm_h16_kernel(const float* __restrict__ x,
                                                          const float* __restrict__ w,
                                                          short* __restrict__ oh) {
    int row = blockIdx.x;
    const float4* xr = (const float4*)(x + (size_t)row * HID);
    float4 xv = xr[threadIdx.x];
    float ss = xv.x*xv.x + xv.y*xv.y + xv.z*xv.z + xv.w*xv.w;
    for (int off = 32; off; off >>= 1) ss += __shfl_xor(ss, off);
    __shared__ float sred[4];
    if ((threadIdx.x & 63) == 0) sred[threadIdx.x >> 6] = ss;
    __syncthreads();
    float tot = sred[0] + sred[1] + sred[2] + sred[3];
    float scale = rsqrtf(tot * (1.0f / (float)HID) + 1e-5f);
    float4 wv = ((const float4*)w)[threadIdx.x];
    float4 o;
    o.x = xv.x * scale * wv.x; o.y = xv.y * scale * wv.y;
    o.z = xv.z * scale * wv.z; o.w = xv.w * scale * wv.w;
    union { short s[4]; float2 f2; } hh;
    hh.s[0]=f2h(o.x); hh.s[1]=f2h(o.y); hh.s[2]=f2h(o.z); hh.s[3]=f2h(o.w);
    ((float2*)(oh + (size_t)row * HID))[threadIdx.x] = hh.f2;
}

// ---------------- RMSNorm + fused gate top-2 routing ----------------
__global__ __launch_bounds__(256) void rmsnorm_gate_kernel(const float* __restrict__ x,
                                                           const float* __restrict__ w,
                                                           const float* __restrict__ gw,
                                                           short* __restrict__ oh,
                                                           int* __restrict__ cnt,
                                                           int* __restrict__ idx,
                                                           float* __restrict__ wt) {
    int row = blockIdx.x;
    const float4* xr = (const float4*)(x + (size_t)row * HID);
    float4 xv = xr[threadIdx.x];
    float ss = xv.x*xv.x + xv.y*xv.y + xv.z*xv.z + xv.w*xv.w;
    for (int off = 32; off; off >>= 1) ss += __shfl_xor(ss, off);
    __shared__ float sred[4];
    __shared__ float gred[4][NE];
    if ((threadIdx.x & 63) == 0) sred[threadIdx.x >> 6] = ss;
    __syncthreads();
    float tot = sred[0] + sred[1] + sred[2] + sred[3];
    float scale = rsqrtf(tot * (1.0f / (float)HID) + 1e-5f);
    float4 wv = ((const float4*)w)[threadIdx.x];
    float4 o;
    o.x = xv.x * scale * wv.x; o.y = xv.y * scale * wv.y;
    o.z = xv.z * scale * wv.z; o.w = xv.w * scale * wv.w;
    union { short s[4]; float2 f2; } hh;
    hh.s[0]=f2h(o.x); hh.s[1]=f2h(o.y); hh.s[2]=f2h(o.z); hh.s[3]=f2h(o.w);
    ((float2*)(oh + (size_t)row * HID))[threadIdx.x] = hh.f2;
    const float4* gr = (const float4*)gw;
    float acc[NE];
    #pragma unroll
    for (int e = 0; e < NE; ++e) {
        float4 g4 = gr[e * 256 + threadIdx.x];
        acc[e] = o.x*g4.x + o.y*g4.y + o.z*g4.z + o.w*g4.w;
    }
    #pragma unroll
    for (int e = 0; e < NE; ++e)
        for (int off = 32; off; off >>= 1) acc[e] += __shfl_xor(acc[e], off);
    if ((threadIdx.x & 63) == 0) {
        #pragma unroll
        for (int e = 0; e < NE; ++e) gred[threadIdx.x >> 6][e] = acc[e];
    }
    __syncthreads();
    if (threadIdx.x == 0) {
        float lg[NE];
        #pragma unroll
        for (int e = 0; e < NE; ++e)
            lg[e] = gred[0][e] + gred[1][e] + gred[2][e] + gred[3][e];
        float mx = lg[0];
        #pragma unroll
        for (int e = 1; e < NE; ++e) mx = fmaxf(mx, lg[e]);
        float p[NE];
        #pragma unroll
        for (int e = 0; e < NE; ++e) p[e] = __expf(lg[e] - mx);
        int i0 = 0;
        #pragma unroll
        for (int e = 1; e < NE; ++e) if (p[e] > p[i0]) i0 = e;
        int i1 = -1;
        #pragma unroll
        for (int e = 0; e < NE; ++e) if (e != i0 && (i1 < 0 || p[e] > p[i1])) i1 = e;
        float w0 = p[i0], w1 = p[i1];
        float inv = 1.0f / (w0 + w1);
        int s0 = atomicAdd(&cnt[i0], 1);
        idx[i0 * S_LEN + s0] = row; wt[i0 * S_LEN + s0] = w0 * inv;
        int s1 = atomicAdd(&cnt[i1], 1);
        idx[i1 * S_LEN + s1] = row; wt[i1 * S_LEN + s1] = w1 * inv;
    }
}

// plain rmsnorm for final output (fp32)
__global__ __launch_bounds__(256) void rmsnorm_kernel(const float* __restrict__ x,
                                                      const float* __restrict__ w,
                                                      float* __restrict__ out) {
    int row = blockIdx.x;
    const float4* xr = (const float4*)(x + (size_t)row * HID);
    float4 xv = xr[threadIdx.x];
    float ss = xv.x*xv.x + xv.y*xv.y + xv.z*xv.z + xv.w*xv.w;
    for (int off = 32; off; off >>= 1) ss += __shfl_xor(ss, off);
    __shared__ float sred[4];
    if ((threadIdx.x & 63) == 0) sred[threadIdx.x >> 6] = ss;
    __syncthreads();
    float tot = sred[0] + sred[1] + sred[2] + sred[3];
    float scale = rsqrtf(tot * (1.0f / (float)HID) + 1e-5f);
    float4 wv = ((const float4*)w)[threadIdx.x];
    float4 o;
    o.x = xv.x * scale * wv.x; o.y = xv.y * scale * wv.y;
    o.z = xv.z * scale * wv.z; o.w = xv.w * scale * wv.w;
    ((float4*)(out + (size_t)row * HID))[threadIdx.x] = o;
}

// ---------------- RoPE apply + fp16 convert (q or k) ----------------
__global__ void rope_cvt_kernel(const float* __restrict__ p, const float* __restrict__ cosb,
                                const float* __restrict__ sinb, short* __restrict__ o16,
                                int nh, int total) {
    int gid = blockIdx.x * 256 + threadIdx.x;
    if (gid >= total) return;
    int per = nh * 32;
    int t = gid / per, r = gid % per;
    int hh = r >> 5, i = r & 31;
    float c = cosb[t*32 + i], s = sinb[t*32 + i];
    const float* base = p + (size_t)t * (nh * HD) + hh * HD + i;
    float a = base[0], b = base[32];
    short* ob = o16 + (size_t)t * (nh * HD) + hh * HD + i;
    ob[0]  = f2h(a * c - b * s);
    ob[32] = f2h(b * c + a * s);
}

// ---------------- V transpose + fp16: vt16[d][t] = fp16(vb[t][d]) ----------------
// grid (S_LEN/64, KVH*HD/64); LDS-tiled.
__global__ __launch_bounds__(256) void vtrans_kernel(const float* __restrict__ vb,
                                                     short* __restrict__ vt16) {
    __shared__ float tile[64][65];
    const int t0 = blockIdx.x * 64, d0 = blockIdx.y * 64;
    const int tr = threadIdx.x >> 2;
    const int dc = (threadIdx.x & 3) * 16;
    const float4* src = (const float4*)(vb + (size_t)(t0 + tr) * (KVH*HD) + d0 + dc);
    float4 v0 = src[0], v1 = src[1], v2 = src[2], v3 = src[3];
    tile[tr][dc+ 0]=v0.x; tile[tr][dc+ 1]=v0.y; tile[tr][dc+ 2]=v0.z; tile[tr][dc+ 3]=v0.w;
    tile[tr][dc+ 4]=v1.x; tile[tr][dc+ 5]=v1.y; tile[tr][dc+ 6]=v1.z; tile[tr][dc+ 7]=v1.w;
    tile[tr][dc+ 8]=v2.x; tile[tr][dc+ 9]=v2.y; tile[tr][dc+10]=v2.z; tile[tr][dc+11]=v2.w;
    tile[tr][dc+12]=v3.x; tile[tr][dc+13]=v3.y; tile[tr][dc+14]=v3.z; tile[tr][dc+15]=v3.w;
    __syncthreads();
    const int dr = threadIdx.x >> 2;
    const int tc = (threadIdx.x & 3) * 16;
    s16x8 w0, w1;
    #pragma unroll
    for (int i = 0; i < 8; ++i) {
        w0[i] = f2h(tile[tc + i][dr]);
        w1[i] = f2h(tile[tc + 8 + i][dr]);
    }
    short* dst = vt16 + (size_t)(d0 + dr) * S_LEN + t0 + tc;
    *(s16x8*)dst = w0;
    *(s16x8*)(dst + 8) = w1;
}

// ---------------- single-pass fp16 128x128 GEMM core ----------------
__device__ __forceinline__ void gemm128_core(
        const short* pA0, const short* pA1, const short* pB0, const short* pB1,
        int Kd, int tid, short* As, short* Bs, f32x4 (&acc)[4][4]) {
    const int lane = tid & 63, lo = lane & 15, hi = lane >> 4;
    const int wid = tid >> 6, wr = wid >> 1, wc = wid & 1;
    const int srow = tid >> 2, scol = (tid & 3) * 8;
    for (int k0 = 0; k0 < Kd; k0 += 32) {
        s16x8 a0 = *(const s16x8*)(pA0 + k0);
        s16x8 a1 = *(const s16x8*)(pA1 + k0);
        s16x8 b0 = *(const s16x8*)(pB0 + k0);
        s16x8 b1 = *(const s16x8*)(pB1 + k0);
        __syncthreads();
        *(s16x8*)&As[srow*40 + scol] = a0;
        *(s16x8*)&As[(64+srow)*40 + scol] = a1;
        *(s16x8*)&Bs[srow*40 + scol] = b0;
        *(s16x8*)&Bs[(64+srow)*40 + scol] = b1;
        __syncthreads();
        f16x8 aF[4], bF[4];
        #pragma unroll
        for (int m = 0; m < 4; ++m) aF[m] = *(const f16x8*)&As[(wr*64 + m*16 + lo)*40 + hi*8];
        #pragma unroll
        for (int n = 0; n < 4; ++n) bF[n] = *(const f16x8*)&Bs[(wc*64 + n*16 + lo)*40 + hi*8];
        #pragma unroll
        for (int m = 0; m < 4; ++m)
            #pragma unroll
            for (int n = 0; n < 4; ++n)
                acc[m][n] = __builtin_amdgcn_mfma_f32_16x16x32_f16(aF[m], bF[n], acc[m][n], 0, 0, 0);
    }
}

// ---------------- generic fp16 GEMM: C = A@B^T (+resid) ----------------
__global__ __launch_bounds__(256) void gemm_h16_kernel(const short* __restrict__ Ag,
        const short* __restrict__ Bg, float* __restrict__ C,
        const float* __restrict__ resid, int N, int Kd) {
    __shared__ __align__(16) short As[128*40], Bs[128*40];
    const int tid = threadIdx.x;
    const int lane = tid & 63, lo = lane & 15, hi = lane >> 4;
    const int wid = tid >> 6, wr = wid >> 1, wc = wid & 1;
    const int m0 = blockIdx.y * 128, n0 = blockIdx.x * 128;
    const int srow = tid >> 2, scol = (tid & 3) * 8;
    f32x4 acc[4][4];
    #pragma unroll
    for (int m = 0; m < 4; ++m)
        #pragma unroll
        for (int n = 0; n < 4; ++n) { acc[m][n][0]=0.f; acc[m][n][1]=0.f; acc[m][n][2]=0.f; acc[m][n][3]=0.f; }
    gemm128_core(Ag + (size_t)(m0+srow)*Kd + scol, Ag + (size_t)(m0+64+srow)*Kd + scol,
                 Bg + (size_t)(n0+srow)*Kd + scol, Bg + (size_t)(n0+64+srow)*Kd + scol,
                 Kd, tid, As, Bs, acc);
    #pragma unroll
    for (int m = 0; m < 4; ++m)
        #pragma unroll
        for (int n = 0; n < 4; ++n)
            #pragma unroll
            for (int r = 0; r < 4; ++r) {
                int row = m0 + wr*64 + m*16 + hi*4 + r;
                int col = n0 + wc*64 + n*16 + lo;
                float val = acc[m][n][r];
                if (resid) val += resid[(size_t)row * N + col];
                C[(size_t)row * N + col] = val;
            }
}

// ---------------- fused QKV GEMM (fp16) ----------------
__global__ __launch_bounds__(256) void qkv_h16_kernel(const short* __restrict__ Xh,
        const short* __restrict__ qw16, const short* __restrict__ kw16,
        const short* __restrict__ vw16,
        float* __restrict__ qo, float* __restrict__ ko, float* __restrict__ vo) {
    __shared__ __align__(16) short As[128*40], Bs[128*40];
    const int bx = blockIdx.x;
    const short* Bp; float* Cp; int Nc, n0;
    if (bx < 8)       { Bp = qw16; Cp = qo; Nc = 1024; n0 = bx * 128; }
    else if (bx < 10) { Bp = kw16; Cp = ko; Nc = 256;  n0 = (bx - 8) * 128; }
    else              { Bp = vw16; Cp = vo; Nc = 256;  n0 = (bx - 10) * 128; }
    const int tid = threadIdx.x;
    const int lane = tid & 63, lo = lane & 15, hi = lane >> 4;
    const int wid = tid >> 6, wr = wid >> 1, wc = wid & 1;
    const int m0 = blockIdx.y * 128;
    const int srow = tid >> 2, scol = (tid & 3) * 8;
    f32x4 acc[4][4];
    #pragma unroll
    for (int m = 0; m < 4; ++m)
        #pragma unroll
        for (int n = 0; n < 4; ++n) { acc[m][n][0]=0.f; acc[m][n][1]=0.f; acc[m][n][2]=0.f; acc[m][n][3]=0.f; }
    gemm128_core(Xh + (size_t)(m0+srow)*HID + scol, Xh + (size_t)(m0+64+srow)*HID + scol,
                 Bp + (size_t)(n0+srow)*HID + scol, Bp + (size_t)(n0+64+srow)*HID + scol,
                 HID, tid, As, Bs, acc);
    #pragma unroll
    for (int m = 0; m < 4; ++m)
        #pragma unroll
        for (int n = 0; n < 4; ++n)
            #pragma unroll
            for (int r = 0; r < 4; ++r) {
                int row = m0 + wr*64 + m*16 + hi*4 + r;
                int col = n0 + wc*64 + n*16 + lo;
                Cp[(size_t)row * Nc + col] = acc[m][n][r];
            }
}

// ---------------- split-K fp16 MFMA flash attention -> partials ----------------
// grid (80, NHEAD): slot -> (q-tile, key-chunk of <=8 tiles). Long chunks first.
// Inputs pre-converted fp16: q16[t][h*64+d], k16[t][kvh*64+d], vt16[kvh*64+d][t].
__global__ __launch_bounds__(256) void attn_mfma_kernel(const short* __restrict__ q16,
                                                        const short* __restrict__ k16,
                                                        const short* __restrict__ vt16,
                                                        float* __restrict__ pO,
                                                        float* __restrict__ pm,
                                                        float* __restrict__ pl) {
    __shared__ __align__(16) short Ks[64][72];
    __shared__ __align__(16) short Vt[64][72];
    __shared__ __align__(16) short Ps[4][16][72];
    const int wid = threadIdx.x >> 6, lane = threadIdx.x & 63;
    const int lo = lane & 15, hi = lane >> 4;
    const int head = blockIdx.y;
    const int s = 79 - blockIdx.x;            // long chunks dispatched first
    int qi, c;
    if (s < 8)       { qi = s;                     c = 0; }
    else if (s < 24) { int t = s - 8;  qi = 8  + (t >> 1); c = t & 1; }
    else if (s < 48) { int t = s - 24; qi = 16 + t / 3;    c = t % 3; }
    else             { int t = s - 48; qi = 24 + (t >> 2); c = t & 3; }
    const int t_beg = c * 8;
    const int t_end = min(t_beg + 8, qi + 1);
    const int q0 = qi * 64;
    const int kvh = head >> 2;

    f16x8 qf[2];
    {
        const short* qr = q16 + (size_t)(q0 + wid*16 + lo) * HID + head*HD;
        qf[0] = *(const f16x8*)(qr + hi*8);
        qf[1] = *(const f16x8*)(qr + 32 + hi*8);
    }

    f32x4 acc[4];
    float m[4], l[4];
    #pragma unroll
    for (int r = 0; r < 4; ++r) {
        m[r] = -1e30f; l[r] = 0.f;
        acc[0][r] = 0.f; acc[1][r] = 0.f; acc[2][r] = 0.f; acc[3][r] = 0.f;
    }

    const int skey = threadIdx.x >> 2;        // K: token row; V: dim row
    const int sdg  = (threadIdx.x & 3) * 16;  // 16-short chunk

    // prefetch tile t_beg into registers (pure vector loads, already fp16)
    s16x8 ka0, ka1, va0, va1;
    {
        const short* kr = k16 + (size_t)(t_beg*64 + skey)*(KVH*HD) + kvh*HD + sdg;
        ka0 = *(const s16x8*)kr; ka1 = *(const s16x8*)(kr + 8);
        const short* vr = vt16 + (size_t)(kvh*HD + skey)*S_LEN + t_beg*64 + sdg;
        va0 = *(const s16x8*)vr; va1 = *(const s16x8*)(vr + 8);
    }

    for (int t = t_beg; t < t_end; ++t) {
        __syncthreads();   // previous tile's LDS reads complete
        *(s16x8*)&Ks[skey][sdg]     = ka0;
        *(s16x8*)&Ks[skey][sdg + 8] = ka1;
        *(s16x8*)&Vt[skey][sdg]     = va0;
        *(s16x8*)&Vt[skey][sdg + 8] = va1;
        __syncthreads();
        if (t + 1 < t_end) {  // issue next-tile loads; latency hides under compute
            const short* kr = k16 + (size_t)((t+1)*64 + skey)*(KVH*HD) + kvh*HD + sdg;
            ka0 = *(const s16x8*)kr; ka1 = *(const s16x8*)(kr + 8);
            const short* vr = vt16 + (size_t)(kvh*HD + skey)*S_LEN + (t+1)*64 + sdg;
            va0 = *(const s16x8*)vr; va1 = *(const s16x8*)(vr + 8);
        }
        const int k0 = t * 64;
        f32x4 sc[4];
        #pragma unroll
        for (int f = 0; f < 4; ++f) {
            f32x4 sf; sf[0]=0.f; sf[1]=0.f; sf[2]=0.f; sf[3]=0.f;
            f16x8 bk0 = *(const f16x8*)&Ks[f*16 + lo][hi*8];
            sf = __builtin_amdgcn_mfma_f32_16x16x32_f16(qf[0], bk0, sf, 0, 0, 0);
            f16x8 bk1 = *(const f16x8*)&Ks[f*16 + lo][32 + hi*8];
            sf = __builtin_amdgcn_mfma_f32_16x16x32_f16(qf[1], bk1, sf, 0, 0, 0);
            sc[f] = sf;
        }
        #pragma unroll
        for (int f = 0; f < 4; ++f)
            #pragma unroll
            for (int r = 0; r < 4; ++r) sc[f][r] *= 0.125f;
        if (t == qi) {   // diagonal tile: causal mask
            int qrow = q0 + wid*16 + hi*4;
            #pragma unroll
            for (int f = 0; f < 4; ++f)
                #pragma unroll
                for (int r = 0; r < 4; ++r)
                    if (k0 + f*16 + lo > qrow + r) sc[f][r] = -1e30f;
        }
        float scale_[4];
        #pragma unroll
        for (int r = 0; r < 4; ++r) {
            float x = fmaxf(fmaxf(sc[0][r], sc[1][r]), fmaxf(sc[2][r], sc[3][r]));
            x = fmaxf(x, __shfl_xor(x, 1));
            x = fmaxf(x, __shfl_xor(x, 2));
            x = fmaxf(x, __shfl_xor(x, 4));
            x = fmaxf(x, __shfl_xor(x, 8));
            float mn = fmaxf(m[r], x);
            scale_[r] = __expf(m[r] - mn);
            m[r] = mn;
            l[r] *= scale_[r];
            acc[0][r] *= scale_[r]; acc[1][r] *= scale_[r];
            acc[2][r] *= scale_[r]; acc[3][r] *= scale_[r];
        }
        float rs[4] = {0.f, 0.f, 0.f, 0.f};
        #pragma unroll
        for (int f = 0; f < 4; ++f)
            #pragma unroll
            for (int r = 0; r < 4; ++r) {
                float e = __expf(sc[f][r] - m[r]);
                rs[r] += e;
                Ps[wid][hi*4 + r][f*16 + lo] = f2h(e);
            }
        #pragma unroll
        for (int r = 0; r < 4; ++r) {
            float x = rs[r];
            x += __shfl_xor(x, 1); x += __shfl_xor(x, 2);
            x += __shfl_xor(x, 4); x += __shfl_xor(x, 8);
            l[r] += x;
        }
        asm volatile("s_waitcnt lgkmcnt(0)" ::: "memory");
        __builtin_amdgcn_sched_barrier(0);
        f16x8 pa0 = *(const f16x8*)&Ps[wid][lo][hi*8];
        f16x8 pa1 = *(const f16x8*)&Ps[wid][lo][32 + hi*8];
        #pragma unroll
        for (int f = 0; f < 4; ++f) {
            f32x4 o = acc[f];
            f16x8 v0 = *(const f16x8*)&Vt[f*16 + lo][hi*8];
            o = __builtin_amdgcn_mfma_f32_16x16x32_f16(pa0, v0, o, 0, 0, 0);
            f16x8 v1 = *(const f16x8*)&Vt[f*16 + lo][32 + hi*8];
            o = __builtin_amdgcn_mfma_f32_16x16x32_f16(pa1, v1, o, 0, 0, 0);
            acc[f] = o;
        }
    }
    const int pbase = head * 80 + s;
    float* po = pO + (size_t)pbase * 4096;
    #pragma unroll
    for (int r = 0; r < 4; ++r)
        #pragma unroll
        for (int f = 0; f < 4; ++f)
            po[(wid*16 + hi*4 + r) * 64 + f*16 + lo] = acc[f][r];
    if (lo == 0) {
        #pragma unroll
        for (int r = 0; r < 4; ++r) {
            pm[pbase*64 + wid*16 + hi*4 + r] = m[r];
            pl[pbase*64 + wid*16 + hi*4 + r] = l[r];
        }
    }
}

// ---------------- combine partials -> fp16 attention output ----------------
__global__ __launch_bounds__(256) void attn_combine_kernel(const float* __restrict__ pO,
        const float* __restrict__ pm, const float* __restrict__ pl,
        short* __restrict__ aoh) {
    const int qi = blockIdx.x, head = blockIdx.y;
    const int nch = qi / 8 + 1;
    int sbase;
    if (qi < 8)       sbase = qi;
    else if (qi < 16) sbase = 8 + (qi - 8) * 2;
    else if (qi < 24) sbase = 24 + (qi - 16) * 3;
    else              sbase = 48 + (qi - 24) * 4;
    const int row = threadIdx.x >> 2;
    const int d0 = (threadIdx.x & 3) * 16;
    float mv[4], lv[4];
    float mx = -1e30f;
    #pragma unroll
    for (int cd = 0; cd < 4; ++cd) {
        if (cd < nch) {
            int p = head * 80 + sbase + cd;
            mv[cd] = pm[p * 64 + row];
            lv[cd] = pl[p * 64 + row];
            mx = fmaxf(mx, mv[cd]);
        } else { mv[cd] = -1e30f; lv[cd] = 0.f; }
    }
    float w[4];
    float lsum = 0.f;
    #pragma unroll
    for (int cd = 0; cd < 4; ++cd) {
        w[cd] = (cd < nch) ? __expf(mv[cd] - mx) : 0.f;
        lsum += w[cd] * lv[cd];
    }
    float inv = 1.0f / lsum;
    float o[16] = {};
    #pragma unroll
    for (int cd = 0; cd < 4; ++cd) {
        if (cd < nch) {
            const float4* po = (const float4*)(pO + ((size_t)(head * 80 + sbase + cd)) * 4096 + row * 64 + d0);
            float wc = w[cd] * inv;
            #pragma unroll
            for (int j = 0; j < 4; ++j) {
                float4 vv = po[j];
                o[j*4+0] += wc * vv.x; o[j*4+1] += wc * vv.y;
                o[j*4+2] += wc * vv.z; o[j*4+3] += wc * vv.w;
            }
        }
    }
    size_t outb = (size_t)(qi * 64 + row) * HID + head * HD + d0;
    s16x8 w0, w1;
    #pragma unroll
    for (int i = 0; i < 8; ++i) { w0[i] = f2h(o[i]); w1[i] = f2h(o[8+i]); }
    *(s16x8*)(aoh + outb) = w0;
    *(s16x8*)(aoh + outb + 8) = w1;
}

// ---------------- MoE mlp1 (fp16): ab16 = fp16( silu(x@w1^T) * (x@w3^T) ) ----------------
__global__ __launch_bounds__(256) void moe_mlp1_h16(const short* __restrict__ Xh,
        const short* __restrict__ W1h, const short* __restrict__ W3h,
        const int* __restrict__ cnt, const int* __restrict__ idx,
        short* __restrict__ abh) {
    int e = blockIdx.z;
    int ne = cnt[e];
    int m0 = blockIdx.y * 128;
    if (m0 >= ne) return;
    int f0 = blockIdx.x * 64;
    __shared__ __align__(16) short As[128*40];
    __shared__ __align__(16) short Gs[64*40], Us[64*40];
    __shared__ int rows[128];
    const int tid = threadIdx.x;
    if (tid < 128) {
        int slot = m0 + tid;
        rows[tid] = (slot < ne) ? idx[e * S_LEN + slot] : 0;
    }
    __syncthreads();
    const int lane = tid & 63, lo = lane & 15, hi = lane >> 4;
    const int wid = tid >> 6, wr = wid >> 1, wc = wid & 1;
    const int srow = tid >> 2, scol = (tid & 3) * 8;
    const short* pX0 = Xh + (size_t)rows[srow] * HID + scol;
    const short* pX1 = Xh + (size_t)rows[64 + srow] * HID + scol;
    const short* p1 = W1h + ((size_t)e * FF + f0 + srow) * HID + scol;
    const short* p3 = W3h + ((size_t)e * FF + f0 + srow) * HID + scol;

    f32x4 ag[4][2], au[4][2];
    #pragma unroll
    for (int m = 0; m < 4; ++m)
        #pragma unroll
        for (int n = 0; n < 2; ++n) {
            ag[m][n][0]=0.f; ag[m][n][1]=0.f; ag[m][n][2]=0.f; ag[m][n][3]=0.f;
            au[m][n][0]=0.f; au[m][n][1]=0.f; au[m][n][2]=0.f; au[m][n][3]=0.f;
        }

    for (int k0 = 0; k0 < HID; k0 += 32) {
        s16x8 a0 = *(const s16x8*)(pX0 + k0);
        s16x8 a1 = *(const s16x8*)(pX1 + k0);
        s16x8 g0 = *(const s16x8*)(p1 + k0);
        s16x8 u0 = *(const s16x8*)(p3 + k0);
        __syncthreads();
        *(s16x8*)&As[srow*40 + scol] = a0;
        *(s16x8*)&As[(64+srow)*40 + scol] = a1;
        *(s16x8*)&Gs[srow*40 + scol] = g0;
        *(s16x8*)&Us[srow*40 + scol] = u0;
        __syncthreads();
        f16x8 aF[4], gF[2], uF[2];
        #pragma unroll
        for (int m = 0; m < 4; ++m) aF[m] = *(const f16x8*)&As[(wr*64 + m*16 + lo)*40 + hi*8];
        #pragma unroll
        for (int n = 0; n < 2; ++n) {
            gF[n] = *(const f16x8*)&Gs[(wc*32 + n*16 + lo)*40 + hi*8];
            uF[n] = *(const f16x8*)&Us[(wc*32 + n*16 + lo)*40 + hi*8];
        }
        #pragma unroll
        for (int m = 0; m < 4; ++m)
            #pragma unroll
            for (int n = 0; n < 2; ++n) {
                ag[m][n] = __builtin_amdgcn_mfma_f32_16x16x32_f16(aF[m], gF[n], ag[m][n], 0, 0, 0);
                au[m][n] = __builtin_amdgcn_mfma_f32_16x16x32_f16(aF[m], uF[n], au[m][n], 0, 0, 0);
            }
    }
    #pragma unroll
    for (int m = 0; m < 4; ++m)
        #pragma unroll
        for (int n = 0; n < 2; ++n)
            #pragma unroll
            for (int r = 0; r < 4; ++r) {
                int slot = m0 + wr*64 + m*16 + hi*4 + r;
                if (slot >= ne) continue;
                float g = ag[m][n][r], u = au[m][n][r];
                float a = g * (1.0f / (1.0f + __expf(-g))) * u;
                abh[((size_t)e * S_LEN + slot) * FF + f0 + wc*32 + n*16 + lo] = f2h(a);
            }
}

// ---------------- MoE mlp2 (fp16): h += wt * (a @ w2^T) ----------------
__global__ __launch_bounds__(256) void moe_mlp2_h16(const short* __restrict__ abh,
        const short* __restrict__ W2h,
        const int* __restrict__ cnt, const int* __restrict__ idx,
        const float* __restrict__ wt, float* __restrict__ hbuf) {
    int e = blockIdx.z;
    int ne = cnt[e];
    int m0 = blockIdx.y * 128;
    if (m0 >= ne) return;
    int n0 = blockIdx.x * 128;
    __shared__ __align__(16) short As[128*40], Bs[128*40];
    const int tid = threadIdx.x;
    const int lane = tid & 63, lo = lane & 15, hi = lane >> 4;
    const int wid = tid >> 6, wr = wid >> 1, wc = wid & 1;
    const int srow = tid >> 2, scol = (tid & 3) * 8;
    f32x4 acc[4][4];
    #pragma unroll
    for (int m = 0; m < 4; ++m)
        #pragma unroll
        for (int n = 0; n < 4; ++n) { acc[m][n][0]=0.f; acc[m][n][1]=0.f; acc[m][n][2]=0.f; acc[m][n][3]=0.f; }
    gemm128_core(abh + ((size_t)e*S_LEN + m0 + srow)*FF + scol,
                 abh + ((size_t)e*S_LEN + m0 + 64 + srow)*FF + scol,
                 W2h + ((size_t)e*HID + n0 + srow)*FF + scol,
                 W2h + ((size_t)e*HID + n0 + 64 + srow)*FF + scol,
                 FF, tid, As, Bs, acc);
    #pragma unroll
    for (int m = 0; m < 4; ++m) {
        #pragma unroll
        for (int r = 0; r < 4; ++r) {
            int slot = m0 + wr*64 + m*16 + hi*4 + r;
            if (slot >= ne) continue;
            int tok = idx[e * S_LEN + slot];
            float wv = wt[e * S_LEN + slot];
            #pragma unroll
            for (int n = 0; n < 4; ++n)
                atomicAdd(&hbuf[(size_t)tok * HID + n0 + wc*64 + n*16 + lo], acc[m][n][r] * wv);
        }
    }
}

extern "C" void kernel_launch(void* const* d_in, const int* in_sizes, int n_in,
                              void* d_out, int out_size, void* d_ws, size_t ws_size,
                              hipStream_t stream) {
    const float* emb = (const float*)d_in[0];
    const float* ln1 = (const float*)d_in[1];
    const float* ln2 = (const float*)d_in[2];
    const float* fln = (const float*)d_in[3];
    const float* qw  = (const float*)d_in[4];
    const float* kw  = (const float*)d_in[5];
    const float* vw  = (const float*)d_in[6];
    const float* ow  = (const float*)d_in[7];
    const float* gw  = (const float*)d_in[8];
    const float* w1  = (const float*)d_in[9];
    const float* w2  = (const float*)d_in[10];
    const float* w3  = (const float*)d_in[11];

    float* ws   = (float*)d_ws;
    float* h    = ws + OFF_H;
    float* q    = ws + OFF_Q;
    float* kb   = ws + OFF_K;
    float* vb   = ws + OFF_V;
    float* cosb = ws + OFF_COS;
    float* sinb = ws + OFF_SIN;
    float* wt   = ws + OFF_WT;
    int*   cnt  = (int*)(ws + OFF_INT);
    int*   idx  = cnt + 8;
    short* xh   = (short*)(ws + OFF_XH);
    short* aoh  = (short*)(ws + OFF_AOH);
    short* abh  = (short*)(ws + OFF_ABH);
    short* q16  = (short*)(ws + OFF_Q16);
    short* k16  = (short*)(ws + OFF_K16);
    short* vt16 = (short*)(ws + OFF_VT16);
    float* pO   = ws + OFF_PO;
    float* pm   = ws + OFF_PM;
    float* pl   = ws + OFF_PL;
    short* WC   = (short*)(ws + OFF_WCVT);

    // converted weights (fp16), non-overlapping
    short* sq = WC;
    short* sk = sq + HID*HID;
    short* sv = sk + KVH*HD*HID;
    short* so = sv + KVH*HD*HID;
    short* s1 = so + HID*HID;
    short* s3 = s1 + (size_t)NE*FF*HID;
    short* s2 = s3 + (size_t)NE*FF*HID;

    hipMemcpyAsync(h, emb, (size_t)S_LEN * HID * sizeof(float), hipMemcpyDeviceToDevice, stream);
    rope_tables_kernel<<<S_LEN * 32 / 256, 256, 0, stream>>>(cosb, sinb);

    const int n8_qo = HID*HID/8, n8_kv = KVH*HD*HID/8, n8_w = NE*FF*HID/8;

    for (int l = 0; l < NL; ++l) {
        cvt16_kernel<<<n8_qo/256, 256, 0, stream>>>(qw + (size_t)l*HID*HID, sq, n8_qo);
        cvt16_kernel<<<n8_kv/256, 256, 0, stream>>>(kw + (size_t)l*KVH*HD*HID, sk, n8_kv);
        cvt16_kernel<<<n8_kv/256, 256, 0, stream>>>(vw + (size_t)l*KVH*HD*HID, sv, n8_kv);
        cvt16_kernel<<<n8_qo/256, 256, 0, stream>>>(ow + (size_t)l*HID*HID, so, n8_qo);

        rmsnorm_h16_kernel<<<S_LEN, 256, 0, stream>>>(h, ln1 + l * HID, xh);
        qkv_h16_kernel<<<dim3(12, 16), 256, 0, stream>>>(xh, sq, sk, sv, q, kb, vb);
        rope_cvt_kernel<<<(S_LEN * NHEAD * 32) / 256, 256, 0, stream>>>(q, cosb, sinb, q16, NHEAD, S_LEN * NHEAD * 32);
        rope_cvt_kernel<<<(S_LEN * KVH * 32) / 256, 256, 0, stream>>>(kb, cosb, sinb, k16, KVH, S_LEN * KVH * 32);
        vtrans_kernel<<<dim3(S_LEN/64, KVH*HD/64), 256, 0, stream>>>(vb, vt16);
        attn_mfma_kernel<<<dim3(80, NHEAD), 256, 0, stream>>>(q16, k16, vt16, pO, pm, pl);
        attn_combine_kernel<<<dim3(32, NHEAD), 256, 0, stream>>>(pO, pm, pl, aoh);
        gemm_h16_kernel<<<dim3(8, 16), 256, 0, stream>>>(aoh, so, h, h, HID, HID);

        hipMemsetAsync(cnt, 0, 8 * sizeof(int), stream);
        rmsnorm_gate_kernel<<<S_LEN, 256, 0, stream>>>(h, ln2 + l * HID, gw + (size_t)l * NE * HID,
                                                       xh, cnt, idx, wt);

        cvt16_kernel<<<n8_w/256, 256, 0, stream>>>(w1 + (size_t)l*NE*FF*HID, s1, n8_w);
        cvt16_kernel<<<n8_w/256, 256, 0, stream>>>(w3 + (size_t)l*NE*FF*HID, s3, n8_w);
        moe_mlp1_h16<<<dim3(16, 16, 8), 256, 0, stream>>>(xh, s1, s3, cnt, idx, abh);

        cvt16_kernel<<<n8_w/256, 256, 0, stream>>>(w2 + (size_t)l*NE*HID*FF, s2, n8_w);
        moe_mlp2_h16<<<dim3(8, 16, 8), 256, 0, stream>>>(abh, s2, cnt, idx, wt, h);
    }
    rmsnorm_kernel<<<S_LEN, 256, 0, stream>>>(h, fln, (float*)d_out);
}

// Round 11
// 536.737 us; speedup vs baseline: 1.2738x; 1.1522x over previous
//
#include <hip/hip_runtime.h>
#include <hip/hip_bf16.h>
#include <math.h>

#define S_LEN 2048
#define HID   1024
#define NHEAD 16
#define KVH   4
#define HD    64
#define FF    1024
#define NE    8
#define NL    2

// ---- workspace layout (float offsets) ----
#define OFF_H    0
#define OFF_Q    (OFF_H + S_LEN*HID)
#define OFF_K    (OFF_Q + S_LEN*HID)
#define OFF_V    (OFF_K + S_LEN*KVH*HD)
#define OFF_COS  (OFF_V + S_LEN*KVH*HD)
#define OFF_SIN  (OFF_COS + S_LEN*32)
#define OFF_WT   (OFF_SIN + S_LEN*32)
#define OFF_INT  (OFF_WT + NE*S_LEN)
#define OFF_TOPE (OFF_INT + NE*S_LEN + 16)
#define OFF_TOPW (OFF_TOPE + S_LEN)
#define OFF_XH   (OFF_TOPW + 2*S_LEN)
#define OFF_AOH  (OFF_XH + S_LEN*HID/2)
#define OFF_ABH  (OFF_AOH + S_LEN*HID/2)
#define OFF_Q16  (OFF_ABH + NE*S_LEN*FF/2)
#define OFF_K16  (OFF_Q16 + S_LEN*HID/2)
#define OFF_VT16 (OFF_K16 + S_LEN*KVH*HD/2)
#define OFF_PO   (OFF_VT16 + S_LEN*KVH*HD/2)
#define OFF_PM   (OFF_PO + 80*NHEAD*64*64)
#define OFF_PL   (OFF_PM + 80*NHEAD*64)
#define OFF_WCVT (OFF_PL + 80*NHEAD*64)
// WCVT region (shorts): qkvo 2.5M + w1 8M + w3 8M + w2 8M = 26.5M shorts = 53MB

typedef __attribute__((ext_vector_type(8))) _Float16 f16x8;
typedef __attribute__((ext_vector_type(8))) short  s16x8;
typedef __attribute__((ext_vector_type(4))) float  f32x4;

__device__ __forceinline__ short f2h(float f) {
    union { _Float16 h; short s; } u;
    u.h = (_Float16)f;
    return u.s;
}

__device__ __forceinline__ s16x8 cvt8(float4 a, float4 b) {
    s16x8 w;
    w[0]=f2h(a.x); w[1]=f2h(a.y); w[2]=f2h(a.z); w[3]=f2h(a.w);
    w[4]=f2h(b.x); w[5]=f2h(b.y); w[6]=f2h(b.z); w[7]=f2h(b.w);
    return w;
}

// ---------------- fp32 -> fp16 convert ----------------
__global__ __launch_bounds__(256) void cvt16_kernel(const float* __restrict__ src,
                                                    short* __restrict__ dst, int n8) {
    int gid = blockIdx.x * 256 + threadIdx.x;
    if (gid >= n8) return;
    const float4* s = (const float4*)src + (size_t)gid * 2;
    *(s16x8*)(dst + (size_t)gid * 8) = cvt8(s[0], s[1]);
}

// ---------------- RoPE tables ----------------
__global__ void rope_tables_kernel(float* __restrict__ cosb, float* __restrict__ sinb) {
    int gid = blockIdx.x * 256 + threadIdx.x;
    int t = gid >> 5, i = gid & 31;
    float invf = powf(1.0e6f, -(float)i / 32.0f);
    float ang = (float)t * invf;
    cosb[gid] = cosf(ang);
    sinb[gid] = sinf(ang);
}

// ---------------- RMSNorm -> fp16 only ----------------
__global__ __launch_bounds__(256) void rmsnorm_h16_kernel(const float* __restrict__ x,
                                                          const float* __restrict__ w,
                                                          short* __restrict__ oh) {
    int row = blockIdx.x;
    const float4* xr = (const float4*)(x + (size_t)row * HID);
    float4 xv = xr[threadIdx.x];
    float ss = xv.x*xv.x + xv.y*xv.y + xv.z*xv.z + xv.w*xv.w;
    for (int off = 32; off; off >>= 1) ss += __shfl_xor(ss, off);
    __shared__ float sred[4];
    if ((threadIdx.x & 63) == 0) sred[threadIdx.x >> 6] = ss;
    __syncthreads();
    float tot = sred[0] + sred[1] + sred[2] + sred[3];
    float scale = rsqrtf(tot * (1.0f / (float)HID) + 1e-5f);
    float4 wv = ((const float4*)w)[threadIdx.x];
    float4 o;
    o.x = xv.x * scale * wv.x; o.y = xv.y * scale * wv.y;
    o.z = xv.z * scale * wv.z; o.w = xv.w * scale * wv.w;
    union { short s[4]; float2 f2; } hh;
    hh.s[0]=f2h(o.x); hh.s[1]=f2h(o.y); hh.s[2]=f2h(o.z); hh.s[3]=f2h(o.w);
    ((float2*)(oh + (size_t)row * HID))[threadIdx.x] = hh.f2;
}

// ---------------- RMSNorm + gate top-2 (NO atomics: writes per-token routing) ----------------
__global__ __launch_bounds__(256) void rmsnorm_gate_kernel(const float* __restrict__ x,
                                                           const float* __restrict__ w,
                                                           const float* __restrict__ gw,
                                                           short* __restrict__ oh,
                                                           int* __restrict__ tope,
                                                           float2* __restrict__ topw) {
    int row = blockIdx.x;
    const float4* xr = (const float4*)(x + (size_t)row * HID);
    float4 xv = xr[threadIdx.x];
    float ss = xv.x*xv.x + xv.y*xv.y + xv.z*xv.z + xv.w*xv.w;
    for (int off = 32; off; off >>= 1) ss += __shfl_xor(ss, off);
    __shared__ float sred[4];
    __shared__ float gred[4][NE];
    if ((threadIdx.x & 63) == 0) sred[threadIdx.x >> 6] = ss;
    __syncthreads();
    float tot = sred[0] + sred[1] + sred[2] + sred[3];
    float scale = rsqrtf(tot * (1.0f / (float)HID) + 1e-5f);
    float4 wv = ((const float4*)w)[threadIdx.x];
    float4 o;
    o.x = xv.x * scale * wv.x; o.y = xv.y * scale * wv.y;
    o.z = xv.z * scale * wv.z; o.w = xv.w * scale * wv.w;
    union { short s[4]; float2 f2; } hh;
    hh.s[0]=f2h(o.x); hh.s[1]=f2h(o.y); hh.s[2]=f2h(o.z); hh.s[3]=f2h(o.w);
    ((float2*)(oh + (size_t)row * HID))[threadIdx.x] = hh.f2;
    const float4* gr = (const float4*)gw;
    float acc[NE];
    #pragma unroll
    for (int e = 0; e < NE; ++e) {
        float4 g4 = gr[e * 256 + threadIdx.x];
        acc[e] = o.x*g4.x + o.y*g4.y + o.z*g4.z + o.w*g4.w;
    }
    #pragma unroll
    for (int e = 0; e < NE; ++e)
        for (int off = 32; off; off >>= 1) acc[e] += __shfl_xor(acc[e], off);
    if ((threadIdx.x & 63) == 0) {
        #pragma unroll
        for (int e = 0; e < NE; ++e) gred[threadIdx.x >> 6][e] = acc[e];
    }
    __syncthreads();
    if (threadIdx.x == 0) {
        float lg[NE];
        #pragma unroll
        for (int e = 0; e < NE; ++e)
            lg[e] = gred[0][e] + gred[1][e] + gred[2][e] + gred[3][e];
        float mx = lg[0];
        #pragma unroll
        for (int e = 1; e < NE; ++e) mx = fmaxf(mx, lg[e]);
        float p[NE];
        #pragma unroll
        for (int e = 0; e < NE; ++e) p[e] = __expf(lg[e] - mx);
        int i0 = 0;
        #pragma unroll
        for (int e = 1; e < NE; ++e) if (p[e] > p[i0]) i0 = e;
        int i1 = -1;
        #pragma unroll
        for (int e = 0; e < NE; ++e) if (e != i0 && (i1 < 0 || p[e] > p[i1])) i1 = e;
        float w0 = p[i0], w1 = p[i1];
        float inv = 1.0f / (w0 + w1);
        tope[row] = i0 | (i1 << 8);
        topw[row] = make_float2(w0 * inv, w1 * inv);
    }
}

// ---------------- build per-expert token lists (ballot prefix-scan, no atomics) ----------
// grid = NE blocks x 1024 threads; block e compacts tokens routed to expert e (token-sorted).
__global__ __launch_bounds__(1024) void route_build_kernel(const int* __restrict__ tope,
                                                           const float2* __restrict__ topw,
                                                           int* __restrict__ cnt,
                                                           int* __restrict__ idx,
                                                           float* __restrict__ wt) {
    const int e = blockIdx.x;
    const int lane = threadIdx.x & 63, wv = threadIdx.x >> 6;
    __shared__ int wtot[16];
    __shared__ int sbase;
    if (threadIdx.x == 0) sbase = 0;
    __syncthreads();
    for (int t0 = 0; t0 < S_LEN; t0 += 1024) {
        int t = t0 + threadIdx.x;
        int pk = tope[t];
        int e0 = pk & 0xff, e1 = (pk >> 8) & 0xff;
        bool sel = (e0 == e) || (e1 == e);
        unsigned long long mask = __ballot(sel);
        int prefix = __popcll(mask & ((1ULL << lane) - 1ULL));
        if (lane == 0) wtot[wv] = __popcll(mask);
        __syncthreads();
        if (sel) {
            int off = sbase;
            for (int i = 0; i < wv; ++i) off += wtot[i];
            float2 wpair = topw[t];
            float wsel = (e0 == e) ? wpair.x : wpair.y;
            int slot = off + prefix;
            idx[e * S_LEN + slot] = t;
            wt[e * S_LEN + slot] = wsel;
        }
        __syncthreads();
        if (threadIdx.x == 0) {
            int s = 0;
            #pragma unroll
            for (int i = 0; i < 16; ++i) s += wtot[i];
            sbase += s;
        }
    }
    __syncthreads();
    if (threadIdx.x == 0) cnt[e] = sbase;
}

// plain rmsnorm for final output (fp32)
__global__ __launch_bounds__(256) void rmsnorm_kernel(const float* __restrict__ x,
                                                      const float* __restrict__ w,
                                                      float* __restrict__ out) {
    int row = blockIdx.x;
    const float4* xr = (const float4*)(x + (size_t)row * HID);
    float4 xv = xr[threadIdx.x];
    float ss = xv.x*xv.x + xv.y*xv.y + xv.z*xv.z + xv.w*xv.w;
    for (int off = 32; off; off >>= 1) ss += __shfl_xor(ss, off);
    __shared__ float sred[4];
    if ((threadIdx.x & 63) == 0) sred[threadIdx.x >> 6] = ss;
    __syncthreads();
    float tot = sred[0] + sred[1] + sred[2] + sred[3];
    float scale = rsqrtf(tot * (1.0f / (float)HID) + 1e-5f);
    float4 wv = ((const float4*)w)[threadIdx.x];
    float4 o;
    o.x = xv.x * scale * wv.x; o.y = xv.y * scale * wv.y;
    o.z = xv.z * scale * wv.z; o.w = xv.w * scale * wv.w;
    ((float4*)(out + (size_t)row * HID))[threadIdx.x] = o;
}

// ---------------- RoPE apply + fp16 convert (q or k) ----------------
__global__ void rope_cvt_kernel(const float* __restrict__ p, const float* __restrict__ cosb,
                                const float* __restrict__ sinb, short* __restrict__ o16,
                                int nh, int total) {
    int gid = blockIdx.x * 256 + threadIdx.x;
    if (gid >= total) return;
    int per = nh * 32;
    int t = gid / per, r = gid % per;
    int hh = r >> 5, i = r & 31;
    float c = cosb[t*32 + i], s = sinb[t*32 + i];
    const float* base = p + (size_t)t * (nh * HD) + hh * HD + i;
    float a = base[0], b = base[32];
    short* ob = o16 + (size_t)t * (nh * HD) + hh * HD + i;
    ob[0]  = f2h(a * c - b * s);
    ob[32] = f2h(b * c + a * s);
}

// ---------------- V transpose + fp16: vt16[d][t] = fp16(vb[t][d]) ----------------
__global__ __launch_bounds__(256) void vtrans_kernel(const float* __restrict__ vb,
                                                     short* __restrict__ vt16) {
    __shared__ float tile[64][65];
    const int t0 = blockIdx.x * 64, d0 = blockIdx.y * 64;
    const int tr = threadIdx.x >> 2;
    const int dc = (threadIdx.x & 3) * 16;
    const float4* src = (const float4*)(vb + (size_t)(t0 + tr) * (KVH*HD) + d0 + dc);
    float4 v0 = src[0], v1 = src[1], v2 = src[2], v3 = src[3];
    tile[tr][dc+ 0]=v0.x; tile[tr][dc+ 1]=v0.y; tile[tr][dc+ 2]=v0.z; tile[tr][dc+ 3]=v0.w;
    tile[tr][dc+ 4]=v1.x; tile[tr][dc+ 5]=v1.y; tile[tr][dc+ 6]=v1.z; tile[tr][dc+ 7]=v1.w;
    tile[tr][dc+ 8]=v2.x; tile[tr][dc+ 9]=v2.y; tile[tr][dc+10]=v2.z; tile[tr][dc+11]=v2.w;
    tile[tr][dc+12]=v3.x; tile[tr][dc+13]=v3.y; tile[tr][dc+14]=v3.z; tile[tr][dc+15]=v3.w;
    __syncthreads();
    const int dr = threadIdx.x >> 2;
    const int tc = (threadIdx.x & 3) * 16;
    s16x8 w0, w1;
    #pragma unroll
    for (int i = 0; i < 8; ++i) {
        w0[i] = f2h(tile[tc + i][dr]);
        w1[i] = f2h(tile[tc + 8 + i][dr]);
    }
    short* dst = vt16 + (size_t)(d0 + dr) * S_LEN + t0 + tc;
    *(s16x8*)dst = w0;
    *(s16x8*)(dst + 8) = w1;
}

// ---------------- single-pass fp16 128x128 GEMM core ----------------
__device__ __forceinline__ void gemm128_core(
        const short* pA0, const short* pA1, const short* pB0, const short* pB1,
        int Kd, int tid, short* As, short* Bs, f32x4 (&acc)[4][4]) {
    const int lane = tid & 63, lo = lane & 15, hi = lane >> 4;
    const int wid = tid >> 6, wr = wid >> 1, wc = wid & 1;
    const int srow = tid >> 2, scol = (tid & 3) * 8;
    for (int k0 = 0; k0 < Kd; k0 += 32) {
        s16x8 a0 = *(const s16x8*)(pA0 + k0);
        s16x8 a1 = *(const s16x8*)(pA1 + k0);
        s16x8 b0 = *(const s16x8*)(pB0 + k0);
        s16x8 b1 = *(const s16x8*)(pB1 + k0);
        __syncthreads();
        *(s16x8*)&As[srow*40 + scol] = a0;
        *(s16x8*)&As[(64+srow)*40 + scol] = a1;
        *(s16x8*)&Bs[srow*40 + scol] = b0;
        *(s16x8*)&Bs[(64+srow)*40 + scol] = b1;
        __syncthreads();
        f16x8 aF[4], bF[4];
        #pragma unroll
        for (int m = 0; m < 4; ++m) aF[m] = *(const f16x8*)&As[(wr*64 + m*16 + lo)*40 + hi*8];
        #pragma unroll
        for (int n = 0; n < 4; ++n) bF[n] = *(const f16x8*)&Bs[(wc*64 + n*16 + lo)*40 + hi*8];
        #pragma unroll
        for (int m = 0; m < 4; ++m)
            #pragma unroll
            for (int n = 0; n < 4; ++n)
                acc[m][n] = __builtin_amdgcn_mfma_f32_16x16x32_f16(aF[m], bF[n], acc[m][n], 0, 0, 0);
    }
}

// ---------------- generic fp16 GEMM: C = A@B^T (+resid) ----------------
__global__ __launch_bounds__(256) void gemm_h16_kernel(const short* __restrict__ Ag,
        const short* __restrict__ Bg, float* __restrict__ C,
        const float* __restrict__ resid, int N, int Kd) {
    __shared__ __align__(16) short As[128*40], Bs[128*40];
    const int tid = threadIdx.x;
    const int lane = tid & 63, lo = lane & 15, hi = lane >> 4;
    const int wid = tid >> 6, wr = wid >> 1, wc = wid & 1;
    const int m0 = blockIdx.y * 128, n0 = blockIdx.x * 128;
    const int srow = tid >> 2, scol = (tid & 3) * 8;
    f32x4 acc[4][4];
    #pragma unroll
    for (int m = 0; m < 4; ++m)
        #pragma unroll
        for (int n = 0; n < 4; ++n) { acc[m][n][0]=0.f; acc[m][n][1]=0.f; acc[m][n][2]=0.f; acc[m][n][3]=0.f; }
    gemm128_core(Ag + (size_t)(m0+srow)*Kd + scol, Ag + (size_t)(m0+64+srow)*Kd + scol,
                 Bg + (size_t)(n0+srow)*Kd + scol, Bg + (size_t)(n0+64+srow)*Kd + scol,
                 Kd, tid, As, Bs, acc);
    #pragma unroll
    for (int m = 0; m < 4; ++m)
        #pragma unroll
        for (int n = 0; n < 4; ++n)
            #pragma unroll
            for (int r = 0; r < 4; ++r) {
                int row = m0 + wr*64 + m*16 + hi*4 + r;
                int col = n0 + wc*64 + n*16 + lo;
                float val = acc[m][n][r];
                if (resid) val += resid[(size_t)row * N + col];
                C[(size_t)row * N + col] = val;
            }
}

// ---------------- fused QKV GEMM (fp16) ----------------
__global__ __launch_bounds__(256) void qkv_h16_kernel(const short* __restrict__ Xh,
        const short* __restrict__ qw16, const short* __restrict__ kw16,
        const short* __restrict__ vw16,
        float* __restrict__ qo, float* __restrict__ ko, float* __restrict__ vo) {
    __shared__ __align__(16) short As[128*40], Bs[128*40];
    const int bx = blockIdx.x;
    const short* Bp; float* Cp; int Nc, n0;
    if (bx < 8)       { Bp = qw16; Cp = qo; Nc = 1024; n0 = bx * 128; }
    else if (bx < 10) { Bp = kw16; Cp = ko; Nc = 256;  n0 = (bx - 8) * 128; }
    else              { Bp = vw16; Cp = vo; Nc = 256;  n0 = (bx - 10) * 128; }
    const int tid = threadIdx.x;
    const int lane = tid & 63, lo = lane & 15, hi = lane >> 4;
    const int wid = tid >> 6, wr = wid >> 1, wc = wid & 1;
    const int m0 = blockIdx.y * 128;
    const int srow = tid >> 2, scol = (tid & 3) * 8;
    f32x4 acc[4][4];
    #pragma unroll
    for (int m = 0; m < 4; ++m)
        #pragma unroll
        for (int n = 0; n < 4; ++n) { acc[m][n][0]=0.f; acc[m][n][1]=0.f; acc[m][n][2]=0.f; acc[m][n][3]=0.f; }
    gemm128_core(Xh + (size_t)(m0+srow)*HID + scol, Xh + (size_t)(m0+64+srow)*HID + scol,
                 Bp + (size_t)(n0+srow)*HID + scol, Bp + (size_t)(n0+64+srow)*HID + scol,
                 HID, tid, As, Bs, acc);
    #pragma unroll
    for (int m = 0; m < 4; ++m)
        #pragma unroll
        for (int n = 0; n < 4; ++n)
            #pragma unroll
            for (int r = 0; r < 4; ++r) {
                int row = m0 + wr*64 + m*16 + hi*4 + r;
                int col = n0 + wc*64 + n*16 + lo;
                Cp[(size_t)row * Nc + col] = acc[m][n][r];
            }
}

// ---------------- split-K fp16 MFMA flash attention -> partials ----------------
__global__ __launch_bounds__(256) void attn_mfma_kernel(const short* __restrict__ q16,
                                                        const short* __restrict__ k16,
                                                        const short* __restrict__ vt16,
                                                        float* __restrict__ pO,
                                                        float* __restrict__ pm,
                                                        float* __restrict__ pl) {
    __shared__ __align__(16) short Ks[64][72];
    __shared__ __align__(16) short Vt[64][72];
    __shared__ __align__(16) short Ps[4][16][72];
    const int wid = threadIdx.x >> 6, lane = threadIdx.x & 63;
    const int lo = lane & 15, hi = lane >> 4;
    const int head = blockIdx.y;
    const int s = 79 - blockIdx.x;            // long chunks dispatched first
    int qi, c;
    if (s < 8)       { qi = s;                     c = 0; }
    else if (s < 24) { int t = s - 8;  qi = 8  + (t >> 1); c = t & 1; }
    else if (s < 48) { int t = s - 24; qi = 16 + t / 3;    c = t % 3; }
    else             { int t = s - 48; qi = 24 + (t >> 2); c = t & 3; }
    const int t_beg = c * 8;
    const int t_end = min(t_beg + 8, qi + 1);
    const int q0 = qi * 64;
    const int kvh = head >> 2;

    f16x8 qf[2];
    {
        const short* qr = q16 + (size_t)(q0 + wid*16 + lo) * HID + head*HD;
        qf[0] = *(const f16x8*)(qr + hi*8);
        qf[1] = *(const f16x8*)(qr + 32 + hi*8);
    }

    f32x4 acc[4];
    float m[4], l[4];
    #pragma unroll
    for (int r = 0; r < 4; ++r) {
        m[r] = -1e30f; l[r] = 0.f;
        acc[0][r] = 0.f; acc[1][r] = 0.f; acc[2][r] = 0.f; acc[3][r] = 0.f;
    }

    const int skey = threadIdx.x >> 2;        // K: token row; V: dim row
    const int sdg  = (threadIdx.x & 3) * 16;  // 16-short chunk

    s16x8 ka0, ka1, va0, va1;
    {
        const short* kr = k16 + (size_t)(t_beg*64 + skey)*(KVH*HD) + kvh*HD + sdg;
        ka0 = *(const s16x8*)kr; ka1 = *(const s16x8*)(kr + 8);
        const short* vr = vt16 + (size_t)(kvh*HD + skey)*S_LEN + t_beg*64 + sdg;
        va0 = *(const s16x8*)vr; va1 = *(const s16x8*)(vr + 8);
    }

    for (int t = t_beg; t < t_end; ++t) {
        __syncthreads();
        *(s16x8*)&Ks[skey][sdg]     = ka0;
        *(s16x8*)&Ks[skey][sdg + 8] = ka1;
        *(s16x8*)&Vt[skey][sdg]     = va0;
        *(s16x8*)&Vt[skey][sdg + 8] = va1;
        __syncthreads();
        if (t + 1 < t_end) {
            const short* kr = k16 + (size_t)((t+1)*64 + skey)*(KVH*HD) + kvh*HD + sdg;
            ka0 = *(const s16x8*)kr; ka1 = *(const s16x8*)(kr + 8);
            const short* vr = vt16 + (size_t)(kvh*HD + skey)*S_LEN + (t+1)*64 + sdg;
            va0 = *(const s16x8*)vr; va1 = *(const s16x8*)(vr + 8);
        }
        const int k0 = t * 64;
        f32x4 sc[4];
        #pragma unroll
        for (int f = 0; f < 4; ++f) {
            f32x4 sf; sf[0]=0.f; sf[1]=0.f; sf[2]=0.f; sf[3]=0.f;
            f16x8 bk0 = *(const f16x8*)&Ks[f*16 + lo][hi*8];
            sf = __builtin_amdgcn_mfma_f32_16x16x32_f16(qf[0], bk0, sf, 0, 0, 0);
            f16x8 bk1 = *(const f16x8*)&Ks[f*16 + lo][32 + hi*8];
            sf = __builtin_amdgcn_mfma_f32_16x16x32_f16(qf[1], bk1, sf, 0, 0, 0);
            sc[f] = sf;
        }
        #pragma unroll
        for (int f = 0; f < 4; ++f)
            #pragma unroll
            for (int r = 0; r < 4; ++r) sc[f][r] *= 0.125f;
        if (t == qi) {
            int qrow = q0 + wid*16 + hi*4;
            #pragma unroll
            for (int f = 0; f < 4; ++f)
                #pragma unroll
                for (int r = 0; r < 4; ++r)
                    if (k0 + f*16 + lo > qrow + r) sc[f][r] = -1e30f;
        }
        float scale_[4];
        #pragma unroll
        for (int r = 0; r < 4; ++r) {
            float x = fmaxf(fmaxf(sc[0][r], sc[1][r]), fmaxf(sc[2][r], sc[3][r]));
            x = fmaxf(x, __shfl_xor(x, 1));
            x = fmaxf(x, __shfl_xor(x, 2));
            x = fmaxf(x, __shfl_xor(x, 4));
            x = fmaxf(x, __shfl_xor(x, 8));
            float mn = fmaxf(m[r], x);
            scale_[r] = __expf(m[r] - mn);
            m[r] = mn;
            l[r] *= scale_[r];
            acc[0][r] *= scale_[r]; acc[1][r] *= scale_[r];
            acc[2][r] *= scale_[r]; acc[3][r] *= scale_[r];
        }
        float rs[4] = {0.f, 0.f, 0.f, 0.f};
        #pragma unroll
        for (int f = 0; f < 4; ++f)
            #pragma unroll
            for (int r = 0; r < 4; ++r) {
                float e = __expf(sc[f][r] - m[r]);
                rs[r] += e;
                Ps[wid][hi*4 + r][f*16 + lo] = f2h(e);
            }
        #pragma unroll
        for (int r = 0; r < 4; ++r) {
            float x = rs[r];
            x += __shfl_xor(x, 1); x += __shfl_xor(x, 2);
            x += __shfl_xor(x, 4); x += __shfl_xor(x, 8);
            l[r] += x;
        }
        asm volatile("s_waitcnt lgkmcnt(0)" ::: "memory");
        __builtin_amdgcn_sched_barrier(0);
        f16x8 pa0 = *(const f16x8*)&Ps[wid][lo][hi*8];
        f16x8 pa1 = *(const f16x8*)&Ps[wid][lo][32 + hi*8];
        #pragma unroll
        for (int f = 0; f < 4; ++f) {
            f32x4 o = acc[f];
            f16x8 v0 = *(const f16x8*)&Vt[f*16 + lo][hi*8];
            o = __builtin_amdgcn_mfma_f32_16x16x32_f16(pa0, v0, o, 0, 0, 0);
            f16x8 v1 = *(const f16x8*)&Vt[f*16 + lo][32 + hi*8];
            o = __builtin_amdgcn_mfma_f32_16x16x32_f16(pa1, v1, o, 0, 0, 0);
            acc[f] = o;
        }
    }
    const int pbase = head * 80 + s;
    float* po = pO + (size_t)pbase * 4096;
    #pragma unroll
    for (int r = 0; r < 4; ++r)
        #pragma unroll
        for (int f = 0; f < 4; ++f)
            po[(wid*16 + hi*4 + r) * 64 + f*16 + lo] = acc[f][r];
    if (lo == 0) {
        #pragma unroll
        for (int r = 0; r < 4; ++r) {
            pm[pbase*64 + wid*16 + hi*4 + r] = m[r];
            pl[pbase*64 + wid*16 + hi*4 + r] = l[r];
        }
    }
}

// ---------------- combine partials -> fp16 attention output ----------------
__global__ __launch_bounds__(256) void attn_combine_kernel(const float* __restrict__ pO,
        const float* __restrict__ pm, const float* __restrict__ pl,
        short* __restrict__ aoh) {
    const int qi = blockIdx.x, head = blockIdx.y;
    const int nch = qi / 8 + 1;
    int sbase;
    if (qi < 8)       sbase = qi;
    else if (qi < 16) sbase = 8 + (qi - 8) * 2;
    else if (qi < 24) sbase = 24 + (qi - 16) * 3;
    else              sbase = 48 + (qi - 24) * 4;
    const int row = threadIdx.x >> 2;
    const int d0 = (threadIdx.x & 3) * 16;
    float mv[4], lv[4];
    float mx = -1e30f;
    #pragma unroll
    for (int cd = 0; cd < 4; ++cd) {
        if (cd < nch) {
            int p = head * 80 + sbase + cd;
            mv[cd] = pm[p * 64 + row];
            lv[cd] = pl[p * 64 + row];
            mx = fmaxf(mx, mv[cd]);
        } else { mv[cd] = -1e30f; lv[cd] = 0.f; }
    }
    float w[4];
    float lsum = 0.f;
    #pragma unroll
    for (int cd = 0; cd < 4; ++cd) {
        w[cd] = (cd < nch) ? __expf(mv[cd] - mx) : 0.f;
        lsum += w[cd] * lv[cd];
    }
    float inv = 1.0f / lsum;
    float o[16] = {};
    #pragma unroll
    for (int cd = 0; cd < 4; ++cd) {
        if (cd < nch) {
            const float4* po = (const float4*)(pO + ((size_t)(head * 80 + sbase + cd)) * 4096 + row * 64 + d0);
            float wc = w[cd] * inv;
            #pragma unroll
            for (int j = 0; j < 4; ++j) {
                float4 vv = po[j];
                o[j*4+0] += wc * vv.x; o[j*4+1] += wc * vv.y;
                o[j*4+2] += wc * vv.z; o[j*4+3] += wc * vv.w;
            }
        }
    }
    size_t outb = (size_t)(qi * 64 + row) * HID + head * HD + d0;
    s16x8 w0, w1;
    #pragma unroll
    for (int i = 0; i < 8; ++i) { w0[i] = f2h(o[i]); w1[i] = f2h(o[8+i]); }
    *(s16x8*)(aoh + outb) = w0;
    *(s16x8*)(aoh + outb + 8) = w1;
}

// ---------------- MoE mlp1 (fp16): ab16 = fp16( silu(x@w1^T) * (x@w3^T) ) ----------------
__global__ __launch_bounds__(256) void moe_mlp1_h16(const short* __restrict__ Xh,
        const short* __restrict__ W1h, const short* __restrict__ W3h,
        const int* __restrict__ cnt, const int* __restrict__ idx,
        short* __restrict__ abh) {
    int e = blockIdx.z;
    int ne = cnt[e];
    int m0 = blockIdx.y * 128;
    if (m0 >= ne) return;
    int f0 = blockIdx.x * 64;
    __shared__ __align__(16) short As[128*40];
    __shared__ __align__(16) short Gs[64*40], Us[64*40];
    __shared__ int rows[128];
    const int tid = threadIdx.x;
    if (tid < 128) {
        int slot = m0 + tid;
        rows[tid] = (slot < ne) ? idx[e * S_LEN + slot] : 0;
    }
    __syncthreads();
    const int lane = tid & 63, lo = lane & 15, hi = lane >> 4;
    const int wid = tid >> 6, wr = wid >> 1, wc = wid & 1;
    const int srow = tid >> 2, scol = (tid & 3) * 8;
    const short* pX0 = Xh + (size_t)rows[srow] * HID + scol;
    const short* pX1 = Xh + (size_t)rows[64 + srow] * HID + scol;
    const short* p1 = W1h + ((size_t)e * FF + f0 + srow) * HID + scol;
    const short* p3 = W3h + ((size_t)e * FF + f0 + srow) * HID + scol;

    f32x4 ag[4][2], au[4][2];
    #pragma unroll
    for (int m = 0; m < 4; ++m)
        #pragma unroll
        for (int n = 0; n < 2; ++n) {
            ag[m][n][0]=0.f; ag[m][n][1]=0.f; ag[m][n][2]=0.f; ag[m][n][3]=0.f;
            au[m][n][0]=0.f; au[m][n][1]=0.f; au[m][n][2]=0.f; au[m][n][3]=0.f;
        }

    for (int k0 = 0; k0 < HID; k0 += 32) {
        s16x8 a0 = *(const s16x8*)(pX0 + k0);
        s16x8 a1 = *(const s16x8*)(pX1 + k0);
        s16x8 g0 = *(const s16x8*)(p1 + k0);
        s16x8 u0 = *(const s16x8*)(p3 + k0);
        __syncthreads();
        *(s16x8*)&As[srow*40 + scol] = a0;
        *(s16x8*)&As[(64+srow)*40 + scol] = a1;
        *(s16x8*)&Gs[srow*40 + scol] = g0;
        *(s16x8*)&Us[srow*40 + scol] = u0;
        __syncthreads();
        f16x8 aF[4], gF[2], uF[2];
        #pragma unroll
        for (int m = 0; m < 4; ++m) aF[m] = *(const f16x8*)&As[(wr*64 + m*16 + lo)*40 + hi*8];
        #pragma unroll
        for (int n = 0; n < 2; ++n) {
            gF[n] = *(const f16x8*)&Gs[(wc*32 + n*16 + lo)*40 + hi*8];
            uF[n] = *(const f16x8*)&Us[(wc*32 + n*16 + lo)*40 + hi*8];
        }
        #pragma unroll
        for (int m = 0; m < 4; ++m)
            #pragma unroll
            for (int n = 0; n < 2; ++n) {
                ag[m][n] = __builtin_amdgcn_mfma_f32_16x16x32_f16(aF[m], gF[n], ag[m][n], 0, 0, 0);
                au[m][n] = __builtin_amdgcn_mfma_f32_16x16x32_f16(aF[m], uF[n], au[m][n], 0, 0, 0);
            }
    }
    #pragma unroll
    for (int m = 0; m < 4; ++m)
        #pragma unroll
        for (int n = 0; n < 2; ++n)
            #pragma unroll
            for (int r = 0; r < 4; ++r) {
                int slot = m0 + wr*64 + m*16 + hi*4 + r;
                if (slot >= ne) continue;
                float g = ag[m][n][r], u = au[m][n][r];
                float a = g * (1.0f / (1.0f + __expf(-g))) * u;
                abh[((size_t)e * S_LEN + slot) * FF + f0 + wc*32 + n*16 + lo] = f2h(a);
            }
}

// ---------------- MoE mlp2 (fp16): h += wt * (a @ w2^T) ----------------
__global__ __launch_bounds__(256) void moe_mlp2_h16(const short* __restrict__ abh,
        const short* __restrict__ W2h,
        const int* __restrict__ cnt, const int* __restrict__ idx,
        const float* __restrict__ wt, float* __restrict__ hbuf) {
    int e = blockIdx.z;
    int ne = cnt[e];
    int m0 = blockIdx.y * 128;
    if (m0 >= ne) return;
    int n0 = blockIdx.x * 128;
    __shared__ __align__(16) short As[128*40], Bs[128*40];
    const int tid = threadIdx.x;
    const int lane = tid & 63, lo = lane & 15, hi = lane >> 4;
    const int wid = tid >> 6, wr = wid >> 1, wc = wid & 1;
    const int srow = tid >> 2, scol = (tid & 3) * 8;
    f32x4 acc[4][4];
    #pragma unroll
    for (int m = 0; m < 4; ++m)
        #pragma unroll
        for (int n = 0; n < 4; ++n) { acc[m][n][0]=0.f; acc[m][n][1]=0.f; acc[m][n][2]=0.f; acc[m][n][3]=0.f; }
    gemm128_core(abh + ((size_t)e*S_LEN + m0 + srow)*FF + scol,
                 abh + ((size_t)e*S_LEN + m0 + 64 + srow)*FF + scol,
                 W2h + ((size_t)e*HID + n0 + srow)*FF + scol,
                 W2h + ((size_t)e*HID + n0 + 64 + srow)*FF + scol,
                 FF, tid, As, Bs, acc);
    #pragma unroll
    for (int m = 0; m < 4; ++m) {
        #pragma unroll
        for (int r = 0; r < 4; ++r) {
            int slot = m0 + wr*64 + m*16 + hi*4 + r;
            if (slot >= ne) continue;
            int tok = idx[e * S_LEN + slot];
            float wv = wt[e * S_LEN + slot];
            #pragma unroll
            for (int n = 0; n < 4; ++n)
                atomicAdd(&hbuf[(size_t)tok * HID + n0 + wc*64 + n*16 + lo], acc[m][n][r] * wv);
        }
    }
}

extern "C" void kernel_launch(void* const* d_in, const int* in_sizes, int n_in,
                              void* d_out, int out_size, void* d_ws, size_t ws_size,
                              hipStream_t stream) {
    const float* emb = (const float*)d_in[0];
    const float* ln1 = (const float*)d_in[1];
    const float* ln2 = (const float*)d_in[2];
    const float* fln = (const float*)d_in[3];
    const float* qw  = (const float*)d_in[4];
    const float* kw  = (const float*)d_in[5];
    const float* vw  = (const float*)d_in[6];
    const float* ow  = (const float*)d_in[7];
    const float* gw  = (const float*)d_in[8];
    const float* w1  = (const float*)d_in[9];
    const float* w2  = (const float*)d_in[10];
    const float* w3  = (const float*)d_in[11];

    float* ws   = (float*)d_ws;
    float* h    = ws + OFF_H;
    float* q    = ws + OFF_Q;
    float* kb   = ws + OFF_K;
    float* vb   = ws + OFF_V;
    float* cosb = ws + OFF_COS;
    float* sinb = ws + OFF_SIN;
    float* wt   = ws + OFF_WT;
    int*   cnt  = (int*)(ws + OFF_INT);
    int*   idx  = cnt + 8;
    int*   tope = (int*)(ws + OFF_TOPE);
    float2* topw = (float2*)(ws + OFF_TOPW);
    short* xh   = (short*)(ws + OFF_XH);
    short* aoh  = (short*)(ws + OFF_AOH);
    short* abh  = (short*)(ws + OFF_ABH);
    short* q16  = (short*)(ws + OFF_Q16);
    short* k16  = (short*)(ws + OFF_K16);
    short* vt16 = (short*)(ws + OFF_VT16);
    float* pO   = ws + OFF_PO;
    float* pm   = ws + OFF_PM;
    float* pl   = ws + OFF_PL;
    short* WC   = (short*)(ws + OFF_WCVT);

    short* sq = WC;
    short* sk = sq + HID*HID;
    short* sv = sk + KVH*HD*HID;
    short* so = sv + KVH*HD*HID;
    short* s1 = so + HID*HID;
    short* s3 = s1 + (size_t)NE*FF*HID;
    short* s2 = s3 + (size_t)NE*FF*HID;

    hipMemcpyAsync(h, emb, (size_t)S_LEN * HID * sizeof(float), hipMemcpyDeviceToDevice, stream);
    rope_tables_kernel<<<S_LEN * 32 / 256, 256, 0, stream>>>(cosb, sinb);

    const int n8_qo = HID*HID/8, n8_kv = KVH*HD*HID/8, n8_w = NE*FF*HID/8;

    for (int l = 0; l < NL; ++l) {
        cvt16_kernel<<<n8_qo/256, 256, 0, stream>>>(qw + (size_t)l*HID*HID, sq, n8_qo);
        cvt16_kernel<<<n8_kv/256, 256, 0, stream>>>(kw + (size_t)l*KVH*HD*HID, sk, n8_kv);
        cvt16_kernel<<<n8_kv/256, 256, 0, stream>>>(vw + (size_t)l*KVH*HD*HID, sv, n8_kv);
        cvt16_kernel<<<n8_qo/256, 256, 0, stream>>>(ow + (size_t)l*HID*HID, so, n8_qo);

        rmsnorm_h16_kernel<<<S_LEN, 256, 0, stream>>>(h, ln1 + l * HID, xh);
        qkv_h16_kernel<<<dim3(12, 16), 256, 0, stream>>>(xh, sq, sk, sv, q, kb, vb);
        rope_cvt_kernel<<<(S_LEN * NHEAD * 32) / 256, 256, 0, stream>>>(q, cosb, sinb, q16, NHEAD, S_LEN * NHEAD * 32);
        rope_cvt_kernel<<<(S_LEN * KVH * 32) / 256, 256, 0, stream>>>(kb, cosb, sinb, k16, KVH, S_LEN * KVH * 32);
        vtrans_kernel<<<dim3(S_LEN/64, KVH*HD/64), 256, 0, stream>>>(vb, vt16);
        attn_mfma_kernel<<<dim3(80, NHEAD), 256, 0, stream>>>(q16, k16, vt16, pO, pm, pl);
        attn_combine_kernel<<<dim3(32, NHEAD), 256, 0, stream>>>(pO, pm, pl, aoh);
        gemm_h16_kernel<<<dim3(8, 16), 256, 0, stream>>>(aoh, so, h, h, HID, HID);

        rmsnorm_gate_kernel<<<S_LEN, 256, 0, stream>>>(h, ln2 + l * HID, gw + (size_t)l * NE * HID,
                                                       xh, tope, topw);
        route_build_kernel<<<NE, 1024, 0, stream>>>(tope, topw, cnt, idx, wt);

        cvt16_kernel<<<n8_w/256, 256, 0, stream>>>(w1 + (size_t)l*NE*FF*HID, s1, n8_w);
        cvt16_kernel<<<n8_w/256, 256, 0, stream>>>(w3 + (size_t)l*NE*FF*HID, s3, n8_w);
        moe_mlp1_h16<<<dim3(16, 16, 8), 256, 0, stream>>>(xh, s1, s3, cnt, idx, abh);

        cvt16_kernel<<<n8_w/256, 256, 0, stream>>>(w2 + (size_t)l*NE*HID*FF, s2, n8_w);
        moe_mlp2_h16<<<dim3(8, 16, 8), 256, 0, stream>>>(abh, s2, cnt, idx, wt, h);
    }
    rmsnorm_kernel<<<S_LEN, 256, 0, stream>>>(h, fln, (float*)d_out);
}

// Round 12
// 506.423 us; speedup vs baseline: 1.3501x; 1.0599x over previous
//
#include <hip/hip_runtime.h>
#include <hip/hip_bf16.h>
#include <math.h>

#define S_LEN 2048
#define HID   1024
#define NHEAD 16
#define KVH   4
#define HD    64
#define FF    1024
#define NE    8
#define NL    2

// ---- workspace layout (float offsets) ----
#define OFF_H    0
#define OFF_Q    (OFF_H + S_LEN*HID)
#define OFF_K    (OFF_Q + S_LEN*HID)
#define OFF_V    (OFF_K + S_LEN*KVH*HD)
#define OFF_COS  (OFF_V + S_LEN*KVH*HD)
#define OFF_SIN  (OFF_COS + S_LEN*32)
#define OFF_WT   (OFF_SIN + S_LEN*32)
#define OFF_INT  (OFF_WT + NE*S_LEN)
#define OFF_TOPE (OFF_INT + NE*S_LEN + 16)
#define OFF_TOPW (OFF_TOPE + S_LEN)
#define OFF_XH   (OFF_TOPW + 2*S_LEN)
#define OFF_AOH  (OFF_XH + S_LEN*HID/2)
#define OFF_ABH  (OFF_AOH + S_LEN*HID/2)
#define OFF_Q16  (OFF_ABH + NE*S_LEN*FF/2)
#define OFF_K16  (OFF_Q16 + S_LEN*HID/2)
#define OFF_VT16 (OFF_K16 + S_LEN*KVH*HD/2)
#define OFF_PO   (OFF_VT16 + S_LEN*KVH*HD/2)
#define OFF_PM   (OFF_PO + 80*NHEAD*64*64)
#define OFF_PL   (OFF_PM + 80*NHEAD*64)
#define OFF_WCVT (OFF_PL + 80*NHEAD*64)
// WCVT region (shorts): qkvo 2.5M + w1 8M + w3 8M + w2 8M = 26.5M shorts = 53MB

typedef __attribute__((ext_vector_type(8))) _Float16 f16x8;
typedef __attribute__((ext_vector_type(8))) short  s16x8;
typedef __attribute__((ext_vector_type(4))) float  f32x4;

__device__ __forceinline__ short f2h(float f) {
    union { _Float16 h; short s; } u;
    u.h = (_Float16)f;
    return u.s;
}

__device__ __forceinline__ s16x8 cvt8(float4 a, float4 b) {
    s16x8 w;
    w[0]=f2h(a.x); w[1]=f2h(a.y); w[2]=f2h(a.z); w[3]=f2h(a.w);
    w[4]=f2h(b.x); w[5]=f2h(b.y); w[6]=f2h(b.z); w[7]=f2h(b.w);
    return w;
}

// ---------------- fp32 -> fp16 convert ----------------
__global__ __launch_bounds__(256) void cvt16_kernel(const float* __restrict__ src,
                                                    short* __restrict__ dst, int n8) {
    int gid = blockIdx.x * 256 + threadIdx.x;
    if (gid >= n8) return;
    const float4* s = (const float4*)src + (size_t)gid * 2;
    *(s16x8*)(dst + (size_t)gid * 8) = cvt8(s[0], s[1]);
}

// ---------------- RoPE tables ----------------
__global__ void rope_tables_kernel(float* __restrict__ cosb, float* __restrict__ sinb) {
    int gid = blockIdx.x * 256 + threadIdx.x;
    int t = gid >> 5, i = gid & 31;
    float invf = powf(1.0e6f, -(float)i / 32.0f);
    float ang = (float)t * invf;
    cosb[gid] = cosf(ang);
    sinb[gid] = sinf(ang);
}

// ---------------- RMSNorm -> fp16 only ----------------
__global__ __launch_bounds__(256) void rmsnorm_h16_kernel(const float* __restrict__ x,
                                                          const float* __restrict__ w,
                                                          short* __restrict__ oh) {
    int row = blockIdx.x;
    const float4* xr = (const float4*)(x + (size_t)row * HID);
    float4 xv = xr[threadIdx.x];
    float ss = xv.x*xv.x + xv.y*xv.y + xv.z*xv.z + xv.w*xv.w;
    for (int off = 32; off; off >>= 1) ss += __shfl_xor(ss, off);
    __shared__ float sred[4];
    if ((threadIdx.x & 63) == 0) sred[threadIdx.x >> 6] = ss;
    __syncthreads();
    float tot = sred[0] + sred[1] + sred[2] + sred[3];
    float scale = rsqrtf(tot * (1.0f / (float)HID) + 1e-5f);
    float4 wv = ((const float4*)w)[threadIdx.x];
    float4 o;
    o.x = xv.x * scale * wv.x; o.y = xv.y * scale * wv.y;
    o.z = xv.z * scale * wv.z; o.w = xv.w * scale * wv.w;
    union { short s[4]; float2 f2; } hh;
    hh.s[0]=f2h(o.x); hh.s[1]=f2h(o.y); hh.s[2]=f2h(o.z); hh.s[3]=f2h(o.w);
    ((float2*)(oh + (size_t)row * HID))[threadIdx.x] = hh.f2;
}

// ---------------- RMSNorm + gate top-2 (NO atomics) ----------------
__global__ __launch_bounds__(256) void rmsnorm_gate_kernel(const float* __restrict__ x,
                                                           const float* __restrict__ w,
                                                           const float* __restrict__ gw,
                                                           short* __restrict__ oh,
                                                           int* __restrict__ tope,
                                                           float2* __restrict__ topw) {
    int row = blockIdx.x;
    const float4* xr = (const float4*)(x + (size_t)row * HID);
    float4 xv = xr[threadIdx.x];
    float ss = xv.x*xv.x + xv.y*xv.y + xv.z*xv.z + xv.w*xv.w;
    for (int off = 32; off; off >>= 1) ss += __shfl_xor(ss, off);
    __shared__ float sred[4];
    __shared__ float gred[4][NE];
    if ((threadIdx.x & 63) == 0) sred[threadIdx.x >> 6] = ss;
    __syncthreads();
    float tot = sred[0] + sred[1] + sred[2] + sred[3];
    float scale = rsqrtf(tot * (1.0f / (float)HID) + 1e-5f);
    float4 wv = ((const float4*)w)[threadIdx.x];
    float4 o;
    o.x = xv.x * scale * wv.x; o.y = xv.y * scale * wv.y;
    o.z = xv.z * scale * wv.z; o.w = xv.w * scale * wv.w;
    union { short s[4]; float2 f2; } hh;
    hh.s[0]=f2h(o.x); hh.s[1]=f2h(o.y); hh.s[2]=f2h(o.z); hh.s[3]=f2h(o.w);
    ((float2*)(oh + (size_t)row * HID))[threadIdx.x] = hh.f2;
    const float4* gr = (const float4*)gw;
    float acc[NE];
    #pragma unroll
    for (int e = 0; e < NE; ++e) {
        float4 g4 = gr[e * 256 + threadIdx.x];
        acc[e] = o.x*g4.x + o.y*g4.y + o.z*g4.z + o.w*g4.w;
    }
    #pragma unroll
    for (int e = 0; e < NE; ++e)
        for (int off = 32; off; off >>= 1) acc[e] += __shfl_xor(acc[e], off);
    if ((threadIdx.x & 63) == 0) {
        #pragma unroll
        for (int e = 0; e < NE; ++e) gred[threadIdx.x >> 6][e] = acc[e];
    }
    __syncthreads();
    if (threadIdx.x == 0) {
        float lg[NE];
        #pragma unroll
        for (int e = 0; e < NE; ++e)
            lg[e] = gred[0][e] + gred[1][e] + gred[2][e] + gred[3][e];
        float mx = lg[0];
        #pragma unroll
        for (int e = 1; e < NE; ++e) mx = fmaxf(mx, lg[e]);
        float p[NE];
        #pragma unroll
        for (int e = 0; e < NE; ++e) p[e] = __expf(lg[e] - mx);
        int i0 = 0;
        #pragma unroll
        for (int e = 1; e < NE; ++e) if (p[e] > p[i0]) i0 = e;
        int i1 = -1;
        #pragma unroll
        for (int e = 0; e < NE; ++e) if (e != i0 && (i1 < 0 || p[e] > p[i1])) i1 = e;
        float w0 = p[i0], w1 = p[i1];
        float inv = 1.0f / (w0 + w1);
        tope[row] = i0 | (i1 << 8);
        topw[row] = make_float2(w0 * inv, w1 * inv);
    }
}

// ---------------- build per-expert token lists (ballot prefix-scan, no atomics) ----------
__global__ __launch_bounds__(1024) void route_build_kernel(const int* __restrict__ tope,
                                                           const float2* __restrict__ topw,
                                                           int* __restrict__ cnt,
                                                           int* __restrict__ idx,
                                                           float* __restrict__ wt) {
    const int e = blockIdx.x;
    const int lane = threadIdx.x & 63, wv = threadIdx.x >> 6;
    __shared__ int wtot[16];
    __shared__ int sbase;
    if (threadIdx.x == 0) sbase = 0;
    __syncthreads();
    for (int t0 = 0; t0 < S_LEN; t0 += 1024) {
        int t = t0 + threadIdx.x;
        int pk = tope[t];
        int e0 = pk & 0xff, e1 = (pk >> 8) & 0xff;
        bool sel = (e0 == e) || (e1 == e);
        unsigned long long mask = __ballot(sel);
        int prefix = __popcll(mask & ((1ULL << lane) - 1ULL));
        if (lane == 0) wtot[wv] = __popcll(mask);
        __syncthreads();
        if (sel) {
            int off = sbase;
            for (int i = 0; i < wv; ++i) off += wtot[i];
            float2 wpair = topw[t];
            float wsel = (e0 == e) ? wpair.x : wpair.y;
            int slot = off + prefix;
            idx[e * S_LEN + slot] = t;
            wt[e * S_LEN + slot] = wsel;
        }
        __syncthreads();
        if (threadIdx.x == 0) {
            int s = 0;
            #pragma unroll
            for (int i = 0; i < 16; ++i) s += wtot[i];
            sbase += s;
        }
    }
    __syncthreads();
    if (threadIdx.x == 0) cnt[e] = sbase;
}

// plain rmsnorm for final output (fp32)
__global__ __launch_bounds__(256) void rmsnorm_kernel(const float* __restrict__ x,
                                                      const float* __restrict__ w,
                                                      float* __restrict__ out) {
    int row = blockIdx.x;
    const float4* xr = (const float4*)(x + (size_t)row * HID);
    float4 xv = xr[threadIdx.x];
    float ss = xv.x*xv.x + xv.y*xv.y + xv.z*xv.z + xv.w*xv.w;
    for (int off = 32; off; off >>= 1) ss += __shfl_xor(ss, off);
    __shared__ float sred[4];
    if ((threadIdx.x & 63) == 0) sred[threadIdx.x >> 6] = ss;
    __syncthreads();
    float tot = sred[0] + sred[1] + sred[2] + sred[3];
    float scale = rsqrtf(tot * (1.0f / (float)HID) + 1e-5f);
    float4 wv = ((const float4*)w)[threadIdx.x];
    float4 o;
    o.x = xv.x * scale * wv.x; o.y = xv.y * scale * wv.y;
    o.z = xv.z * scale * wv.z; o.w = xv.w * scale * wv.w;
    ((float4*)(out + (size_t)row * HID))[threadIdx.x] = o;
}

// ---------------- RoPE apply + fp16 convert (q or k) ----------------
__global__ void rope_cvt_kernel(const float* __restrict__ p, const float* __restrict__ cosb,
                                const float* __restrict__ sinb, short* __restrict__ o16,
                                int nh, int total) {
    int gid = blockIdx.x * 256 + threadIdx.x;
    if (gid >= total) return;
    int per = nh * 32;
    int t = gid / per, r = gid % per;
    int hh = r >> 5, i = r & 31;
    float c = cosb[t*32 + i], s = sinb[t*32 + i];
    const float* base = p + (size_t)t * (nh * HD) + hh * HD + i;
    float a = base[0], b = base[32];
    short* ob = o16 + (size_t)t * (nh * HD) + hh * HD + i;
    ob[0]  = f2h(a * c - b * s);
    ob[32] = f2h(b * c + a * s);
}

// ---------------- V transpose + fp16 ----------------
__global__ __launch_bounds__(256) void vtrans_kernel(const float* __restrict__ vb,
                                                     short* __restrict__ vt16) {
    __shared__ float tile[64][65];
    const int t0 = blockIdx.x * 64, d0 = blockIdx.y * 64;
    const int tr = threadIdx.x >> 2;
    const int dc = (threadIdx.x & 3) * 16;
    const float4* src = (const float4*)(vb + (size_t)(t0 + tr) * (KVH*HD) + d0 + dc);
    float4 v0 = src[0], v1 = src[1], v2 = src[2], v3 = src[3];
    tile[tr][dc+ 0]=v0.x; tile[tr][dc+ 1]=v0.y; tile[tr][dc+ 2]=v0.z; tile[tr][dc+ 3]=v0.w;
    tile[tr][dc+ 4]=v1.x; tile[tr][dc+ 5]=v1.y; tile[tr][dc+ 6]=v1.z; tile[tr][dc+ 7]=v1.w;
    tile[tr][dc+ 8]=v2.x; tile[tr][dc+ 9]=v2.y; tile[tr][dc+10]=v2.z; tile[tr][dc+11]=v2.w;
    tile[tr][dc+12]=v3.x; tile[tr][dc+13]=v3.y; tile[tr][dc+14]=v3.z; tile[tr][dc+15]=v3.w;
    __syncthreads();
    const int dr = threadIdx.x >> 2;
    const int tc = (threadIdx.x & 3) * 16;
    s16x8 w0, w1;
    #pragma unroll
    for (int i = 0; i < 8; ++i) {
        w0[i] = f2h(tile[tc + i][dr]);
        w1[i] = f2h(tile[tc + 8 + i][dr]);
    }
    short* dst = vt16 + (size_t)(d0 + dr) * S_LEN + t0 + tc;
    *(s16x8*)dst = w0;
    *(s16x8*)(dst + 8) = w1;
}

// ---------------- pipelined fp16 128x128 GEMM core (prefetch k+1 under compute) ----------
__device__ __forceinline__ void gemm128_core(
        const short* pA0, const short* pA1, const short* pB0, const short* pB1,
        int Kd, int tid, short* As, short* Bs, f32x4 (&acc)[4][4]) {
    const int lane = tid & 63, lo = lane & 15, hi = lane >> 4;
    const int wid = tid >> 6, wr = wid >> 1, wc = wid & 1;
    const int srow = tid >> 2, scol = (tid & 3) * 8;
    s16x8 a0 = *(const s16x8*)pA0;
    s16x8 a1 = *(const s16x8*)pA1;
    s16x8 b0 = *(const s16x8*)pB0;
    s16x8 b1 = *(const s16x8*)pB1;
    for (int k0 = 0; k0 < Kd; k0 += 32) {
        __syncthreads();
        *(s16x8*)&As[srow*40 + scol] = a0;
        *(s16x8*)&As[(64+srow)*40 + scol] = a1;
        *(s16x8*)&Bs[srow*40 + scol] = b0;
        *(s16x8*)&Bs[(64+srow)*40 + scol] = b1;
        __syncthreads();
        if (k0 + 32 < Kd) {   // issue next-tile loads; latency hides under MFMA
            a0 = *(const s16x8*)(pA0 + k0 + 32);
            a1 = *(const s16x8*)(pA1 + k0 + 32);
            b0 = *(const s16x8*)(pB0 + k0 + 32);
            b1 = *(const s16x8*)(pB1 + k0 + 32);
        }
        f16x8 aF[4], bF[4];
        #pragma unroll
        for (int m = 0; m < 4; ++m) aF[m] = *(const f16x8*)&As[(wr*64 + m*16 + lo)*40 + hi*8];
        #pragma unroll
        for (int n = 0; n < 4; ++n) bF[n] = *(const f16x8*)&Bs[(wc*64 + n*16 + lo)*40 + hi*8];
        #pragma unroll
        for (int m = 0; m < 4; ++m)
            #pragma unroll
            for (int n = 0; n < 4; ++n)
                acc[m][n] = __builtin_amdgcn_mfma_f32_16x16x32_f16(aF[m], bF[n], acc[m][n], 0, 0, 0);
    }
}

// ---------------- generic fp16 GEMM: C = A@B^T (+resid) ----------------
__global__ __launch_bounds__(256) void gemm_h16_kernel(const short* __restrict__ Ag,
        const short* __restrict__ Bg, float* __restrict__ C,
        const float* __restrict__ resid, int N, int Kd) {
    __shared__ __align__(16) short As[128*40], Bs[128*40];
    const int tid = threadIdx.x;
    const int lane = tid & 63, lo = lane & 15, hi = lane >> 4;
    const int wid = tid >> 6, wr = wid >> 1, wc = wid & 1;
    const int m0 = blockIdx.y * 128, n0 = blockIdx.x * 128;
    const int srow = tid >> 2, scol = (tid & 3) * 8;
    f32x4 acc[4][4];
    #pragma unroll
    for (int m = 0; m < 4; ++m)
        #pragma unroll
        for (int n = 0; n < 4; ++n) { acc[m][n][0]=0.f; acc[m][n][1]=0.f; acc[m][n][2]=0.f; acc[m][n][3]=0.f; }
    gemm128_core(Ag + (size_t)(m0+srow)*Kd + scol, Ag + (size_t)(m0+64+srow)*Kd + scol,
                 Bg + (size_t)(n0+srow)*Kd + scol, Bg + (size_t)(n0+64+srow)*Kd + scol,
                 Kd, tid, As, Bs, acc);
    #pragma unroll
    for (int m = 0; m < 4; ++m)
        #pragma unroll
        for (int n = 0; n < 4; ++n)
            #pragma unroll
            for (int r = 0; r < 4; ++r) {
                int row = m0 + wr*64 + m*16 + hi*4 + r;
                int col = n0 + wc*64 + n*16 + lo;
                float val = acc[m][n][r];
                if (resid) val += resid[(size_t)row * N + col];
                C[(size_t)row * N + col] = val;
            }
}

// ---------------- fused QKV GEMM (fp16) ----------------
__global__ __launch_bounds__(256) void qkv_h16_kernel(const short* __restrict__ Xh,
        const short* __restrict__ qw16, const short* __restrict__ kw16,
        const short* __restrict__ vw16,
        float* __restrict__ qo, float* __restrict__ ko, float* __restrict__ vo) {
    __shared__ __align__(16) short As[128*40], Bs[128*40];
    const int bx = blockIdx.x;
    const short* Bp; float* Cp; int Nc, n0;
    if (bx < 8)       { Bp = qw16; Cp = qo; Nc = 1024; n0 = bx * 128; }
    else if (bx < 10) { Bp = kw16; Cp = ko; Nc = 256;  n0 = (bx - 8) * 128; }
    else              { Bp = vw16; Cp = vo; Nc = 256;  n0 = (bx - 10) * 128; }
    const int tid = threadIdx.x;
    const int lane = tid & 63, lo = lane & 15, hi = lane >> 4;
    const int wid = tid >> 6, wr = wid >> 1, wc = wid & 1;
    const int m0 = blockIdx.y * 128;
    const int srow = tid >> 2, scol = (tid & 3) * 8;
    f32x4 acc[4][4];
    #pragma unroll
    for (int m = 0; m < 4; ++m)
        #pragma unroll
        for (int n = 0; n < 4; ++n) { acc[m][n][0]=0.f; acc[m][n][1]=0.f; acc[m][n][2]=0.f; acc[m][n][3]=0.f; }
    gemm128_core(Xh + (size_t)(m0+srow)*HID + scol, Xh + (size_t)(m0+64+srow)*HID + scol,
                 Bp + (size_t)(n0+srow)*HID + scol, Bp + (size_t)(n0+64+srow)*HID + scol,
                 HID, tid, As, Bs, acc);
    #pragma unroll
    for (int m = 0; m < 4; ++m)
        #pragma unroll
        for (int n = 0; n < 4; ++n)
            #pragma unroll
            for (int r = 0; r < 4; ++r) {
                int row = m0 + wr*64 + m*16 + hi*4 + r;
                int col = n0 + wc*64 + n*16 + lo;
                Cp[(size_t)row * Nc + col] = acc[m][n][r];
            }
}

// ---------------- split-K fp16 MFMA flash attention -> partials ----------------
__global__ __launch_bounds__(256) void attn_mfma_kernel(const short* __restrict__ q16,
                                                        const short* __restrict__ k16,
                                                        const short* __restrict__ vt16,
                                                        float* __restrict__ pO,
                                                        float* __restrict__ pm,
                                                        float* __restrict__ pl) {
    __shared__ __align__(16) short Ks[64][72];
    __shared__ __align__(16) short Vt[64][72];
    __shared__ __align__(16) short Ps[4][16][72];
    const int wid = threadIdx.x >> 6, lane = threadIdx.x & 63;
    const int lo = lane & 15, hi = lane >> 4;
    const int head = blockIdx.y;
    const int s = 79 - blockIdx.x;            // long chunks dispatched first
    int qi, c;
    if (s < 8)       { qi = s;                     c = 0; }
    else if (s < 24) { int t = s - 8;  qi = 8  + (t >> 1); c = t & 1; }
    else if (s < 48) { int t = s - 24; qi = 16 + t / 3;    c = t % 3; }
    else             { int t = s - 48; qi = 24 + (t >> 2); c = t & 3; }
    const int t_beg = c * 8;
    const int t_end = min(t_beg + 8, qi + 1);
    const int q0 = qi * 64;
    const int kvh = head >> 2;

    f16x8 qf[2];
    {
        const short* qr = q16 + (size_t)(q0 + wid*16 + lo) * HID + head*HD;
        qf[0] = *(const f16x8*)(qr + hi*8);
        qf[1] = *(const f16x8*)(qr + 32 + hi*8);
    }

    f32x4 acc[4];
    float m[4], l[4];
    #pragma unroll
    for (int r = 0; r < 4; ++r) {
        m[r] = -1e30f; l[r] = 0.f;
        acc[0][r] = 0.f; acc[1][r] = 0.f; acc[2][r] = 0.f; acc[3][r] = 0.f;
    }

    const int skey = threadIdx.x >> 2;
    const int sdg  = (threadIdx.x & 3) * 16;

    s16x8 ka0, ka1, va0, va1;
    {
        const short* kr = k16 + (size_t)(t_beg*64 + skey)*(KVH*HD) + kvh*HD + sdg;
        ka0 = *(const s16x8*)kr; ka1 = *(const s16x8*)(kr + 8);
        const short* vr = vt16 + (size_t)(kvh*HD + skey)*S_LEN + t_beg*64 + sdg;
        va0 = *(const s16x8*)vr; va1 = *(const s16x8*)(vr + 8);
    }

    for (int t = t_beg; t < t_end; ++t) {
        __syncthreads();
        *(s16x8*)&Ks[skey][sdg]     = ka0;
        *(s16x8*)&Ks[skey][sdg + 8] = ka1;
        *(s16x8*)&Vt[skey][sdg]     = va0;
        *(s16x8*)&Vt[skey][sdg + 8] = va1;
        __syncthreads();
        if (t + 1 < t_end) {
            const short* kr = k16 + (size_t)((t+1)*64 + skey)*(KVH*HD) + kvh*HD + sdg;
            ka0 = *(const s16x8*)kr; ka1 = *(const s16x8*)(kr + 8);
            const short* vr = vt16 + (size_t)(kvh*HD + skey)*S_LEN + (t+1)*64 + sdg;
            va0 = *(const s16x8*)vr; va1 = *(const s16x8*)(vr + 8);
        }
        const int k0 = t * 64;
        f32x4 sc[4];
        #pragma unroll
        for (int f = 0; f < 4; ++f) {
            f32x4 sf; sf[0]=0.f; sf[1]=0.f; sf[2]=0.f; sf[3]=0.f;
            f16x8 bk0 = *(const f16x8*)&Ks[f*16 + lo][hi*8];
            sf = __builtin_amdgcn_mfma_f32_16x16x32_f16(qf[0], bk0, sf, 0, 0, 0);
            f16x8 bk1 = *(const f16x8*)&Ks[f*16 + lo][32 + hi*8];
            sf = __builtin_amdgcn_mfma_f32_16x16x32_f16(qf[1], bk1, sf, 0, 0, 0);
            sc[f] = sf;
        }
        #pragma unroll
        for (int f = 0; f < 4; ++f)
            #pragma unroll
            for (int r = 0; r < 4; ++r) sc[f][r] *= 0.125f;
        if (t == qi) {
            int qrow = q0 + wid*16 + hi*4;
            #pragma unroll
            for (int f = 0; f < 4; ++f)
                #pragma unroll
                for (int r = 0; r < 4; ++r)
                    if (k0 + f*16 + lo > qrow + r) sc[f][r] = -1e30f;
        }
        float scale_[4];
        #pragma unroll
        for (int r = 0; r < 4; ++r) {
            float x = fmaxf(fmaxf(sc[0][r], sc[1][r]), fmaxf(sc[2][r], sc[3][r]));
            x = fmaxf(x, __shfl_xor(x, 1));
            x = fmaxf(x, __shfl_xor(x, 2));
            x = fmaxf(x, __shfl_xor(x, 4));
            x = fmaxf(x, __shfl_xor(x, 8));
            float mn = fmaxf(m[r], x);
            scale_[r] = __expf(m[r] - mn);
            m[r] = mn;
            l[r] *= scale_[r];
            acc[0][r] *= scale_[r]; acc[1][r] *= scale_[r];
            acc[2][r] *= scale_[r]; acc[3][r] *= scale_[r];
        }
        float rs[4] = {0.f, 0.f, 0.f, 0.f};
        #pragma unroll
        for (int f = 0; f < 4; ++f)
            #pragma unroll
            for (int r = 0; r < 4; ++r) {
                float e = __expf(sc[f][r] - m[r]);
                rs[r] += e;
                Ps[wid][hi*4 + r][f*16 + lo] = f2h(e);
            }
        #pragma unroll
        for (int r = 0; r < 4; ++r) {
            float x = rs[r];
            x += __shfl_xor(x, 1); x += __shfl_xor(x, 2);
            x += __shfl_xor(x, 4); x += __shfl_xor(x, 8);
            l[r] += x;
        }
        asm volatile("s_waitcnt lgkmcnt(0)" ::: "memory");
        __builtin_amdgcn_sched_barrier(0);
        f16x8 pa0 = *(const f16x8*)&Ps[wid][lo][hi*8];
        f16x8 pa1 = *(const f16x8*)&Ps[wid][lo][32 + hi*8];
        #pragma unroll
        for (int f = 0; f < 4; ++f) {
            f32x4 o = acc[f];
            f16x8 v0 = *(const f16x8*)&Vt[f*16 + lo][hi*8];
            o = __builtin_amdgcn_mfma_f32_16x16x32_f16(pa0, v0, o, 0, 0, 0);
            f16x8 v1 = *(const f16x8*)&Vt[f*16 + lo][32 + hi*8];
            o = __builtin_amdgcn_mfma_f32_16x16x32_f16(pa1, v1, o, 0, 0, 0);
            acc[f] = o;
        }
    }
    const int pbase = head * 80 + s;
    float* po = pO + (size_t)pbase * 4096;
    #pragma unroll
    for (int r = 0; r < 4; ++r)
        #pragma unroll
        for (int f = 0; f < 4; ++f)
            po[(wid*16 + hi*4 + r) * 64 + f*16 + lo] = acc[f][r];
    if (lo == 0) {
        #pragma unroll
        for (int r = 0; r < 4; ++r) {
            pm[pbase*64 + wid*16 + hi*4 + r] = m[r];
            pl[pbase*64 + wid*16 + hi*4 + r] = l[r];
        }
    }
}

// ---------------- combine partials -> fp16 attention output ----------------
__global__ __launch_bounds__(256) void attn_combine_kernel(const float* __restrict__ pO,
        const float* __restrict__ pm, const float* __restrict__ pl,
        short* __restrict__ aoh) {
    const int qi = blockIdx.x, head = blockIdx.y;
    const int nch = qi / 8 + 1;
    int sbase;
    if (qi < 8)       sbase = qi;
    else if (qi < 16) sbase = 8 + (qi - 8) * 2;
    else if (qi < 24) sbase = 24 + (qi - 16) * 3;
    else              sbase = 48 + (qi - 24) * 4;
    const int row = threadIdx.x >> 2;
    const int d0 = (threadIdx.x & 3) * 16;
    float mv[4], lv[4];
    float mx = -1e30f;
    #pragma unroll
    for (int cd = 0; cd < 4; ++cd) {
        if (cd < nch) {
            int p = head * 80 + sbase + cd;
            mv[cd] = pm[p * 64 + row];
            lv[cd] = pl[p * 64 + row];
            mx = fmaxf(mx, mv[cd]);
        } else { mv[cd] = -1e30f; lv[cd] = 0.f; }
    }
    float w[4];
    float lsum = 0.f;
    #pragma unroll
    for (int cd = 0; cd < 4; ++cd) {
        w[cd] = (cd < nch) ? __expf(mv[cd] - mx) : 0.f;
        lsum += w[cd] * lv[cd];
    }
    float inv = 1.0f / lsum;
    float o[16] = {};
    #pragma unroll
    for (int cd = 0; cd < 4; ++cd) {
        if (cd < nch) {
            const float4* po = (const float4*)(pO + ((size_t)(head * 80 + sbase + cd)) * 4096 + row * 64 + d0);
            float wc = w[cd] * inv;
            #pragma unroll
            for (int j = 0; j < 4; ++j) {
                float4 vv = po[j];
                o[j*4+0] += wc * vv.x; o[j*4+1] += wc * vv.y;
                o[j*4+2] += wc * vv.z; o[j*4+3] += wc * vv.w;
            }
        }
    }
    size_t outb = (size_t)(qi * 64 + row) * HID + head * HD + d0;
    s16x8 w0, w1;
    #pragma unroll
    for (int i = 0; i < 8; ++i) { w0[i] = f2h(o[i]); w1[i] = f2h(o[8+i]); }
    *(s16x8*)(aoh + outb) = w0;
    *(s16x8*)(aoh + outb + 8) = w1;
}

// ---------------- MoE mlp1 (fp16, pipelined) ----------------
__global__ __launch_bounds__(256) void moe_mlp1_h16(const short* __restrict__ Xh,
        const short* __restrict__ W1h, const short* __restrict__ W3h,
        const int* __restrict__ cnt, const int* __restrict__ idx,
        short* __restrict__ abh) {
    int e = blockIdx.z;
    int ne = cnt[e];
    int m0 = blockIdx.y * 128;
    if (m0 >= ne) return;
    int f0 = blockIdx.x * 64;
    __shared__ __align__(16) short As[128*40];
    __shared__ __align__(16) short Gs[64*40], Us[64*40];
    __shared__ int rows[128];
    const int tid = threadIdx.x;
    if (tid < 128) {
        int slot = m0 + tid;
        rows[tid] = (slot < ne) ? idx[e * S_LEN + slot] : 0;
    }
    __syncthreads();
    const int lane = tid & 63, lo = lane & 15, hi = lane >> 4;
    const int wid = tid >> 6, wr = wid >> 1, wc = wid & 1;
    const int srow = tid >> 2, scol = (tid & 3) * 8;
    const short* pX0 = Xh + (size_t)rows[srow] * HID + scol;
    const short* pX1 = Xh + (size_t)rows[64 + srow] * HID + scol;
    const short* p1 = W1h + ((size_t)e * FF + f0 + srow) * HID + scol;
    const short* p3 = W3h + ((size_t)e * FF + f0 + srow) * HID + scol;

    f32x4 ag[4][2], au[4][2];
    #pragma unroll
    for (int m = 0; m < 4; ++m)
        #pragma unroll
        for (int n = 0; n < 2; ++n) {
            ag[m][n][0]=0.f; ag[m][n][1]=0.f; ag[m][n][2]=0.f; ag[m][n][3]=0.f;
            au[m][n][0]=0.f; au[m][n][1]=0.f; au[m][n][2]=0.f; au[m][n][3]=0.f;
        }

    s16x8 a0 = *(const s16x8*)pX0;
    s16x8 a1 = *(const s16x8*)pX1;
    s16x8 g0 = *(const s16x8*)p1;
    s16x8 u0 = *(const s16x8*)p3;
    for (int k0 = 0; k0 < HID; k0 += 32) {
        __syncthreads();
        *(s16x8*)&As[srow*40 + scol] = a0;
        *(s16x8*)&As[(64+srow)*40 + scol] = a1;
        *(s16x8*)&Gs[srow*40 + scol] = g0;
        *(s16x8*)&Us[srow*40 + scol] = u0;
        __syncthreads();
        if (k0 + 32 < HID) {   // prefetch next tile under compute
            a0 = *(const s16x8*)(pX0 + k0 + 32);
            a1 = *(const s16x8*)(pX1 + k0 + 32);
            g0 = *(const s16x8*)(p1 + k0 + 32);
            u0 = *(const s16x8*)(p3 + k0 + 32);
        }
        f16x8 aF[4], gF[2], uF[2];
        #pragma unroll
        for (int m = 0; m < 4; ++m) aF[m] = *(const f16x8*)&As[(wr*64 + m*16 + lo)*40 + hi*8];
        #pragma unroll
        for (int n = 0; n < 2; ++n) {
            gF[n] = *(const f16x8*)&Gs[(wc*32 + n*16 + lo)*40 + hi*8];
            uF[n] = *(const f16x8*)&Us[(wc*32 + n*16 + lo)*40 + hi*8];
        }
        #pragma unroll
        for (int m = 0; m < 4; ++m)
            #pragma unroll
            for (int n = 0; n < 2; ++n) {
                ag[m][n] = __builtin_amdgcn_mfma_f32_16x16x32_f16(aF[m], gF[n], ag[m][n], 0, 0, 0);
                au[m][n] = __builtin_amdgcn_mfma_f32_16x16x32_f16(aF[m], uF[n], au[m][n], 0, 0, 0);
            }
    }
    #pragma unroll
    for (int m = 0; m < 4; ++m)
        #pragma unroll
        for (int n = 0; n < 2; ++n)
            #pragma unroll
            for (int r = 0; r < 4; ++r) {
                int slot = m0 + wr*64 + m*16 + hi*4 + r;
                if (slot >= ne) continue;
                float g = ag[m][n][r], u = au[m][n][r];
                float a = g * (1.0f / (1.0f + __expf(-g))) * u;
                abh[((size_t)e * S_LEN + slot) * FF + f0 + wc*32 + n*16 + lo] = f2h(a);
            }
}

// ---------------- MoE mlp2 (fp16, pipelined): h += wt * (a @ w2^T) ----------------
__global__ __launch_bounds__(256) void moe_mlp2_h16(const short* __restrict__ abh,
        const short* __restrict__ W2h,
        const int* __restrict__ cnt, const int* __restrict__ idx,
        const float* __restrict__ wt, float* __restrict__ hbuf) {
    int e = blockIdx.z;
    int ne = cnt[e];
    int m0 = blockIdx.y * 128;
    if (m0 >= ne) return;
    int n0 = blockIdx.x * 128;
    __shared__ __align__(16) short As[128*40], Bs[128*40];
    const int tid = threadIdx.x;
    const int lane = tid & 63, lo = lane & 15, hi = lane >> 4;
    const int wid = tid >> 6, wr = wid >> 1, wc = wid & 1;
    const int srow = tid >> 2, scol = (tid & 3) * 8;
    f32x4 acc[4][4];
    #pragma unroll
    for (int m = 0; m < 4; ++m)
        #pragma unroll
        for (int n = 0; n < 4; ++n) { acc[m][n][0]=0.f; acc[m][n][1]=0.f; acc[m][n][2]=0.f; acc[m][n][3]=0.f; }
    gemm128_core(abh + ((size_t)e*S_LEN + m0 + srow)*FF + scol,
                 abh + ((size_t)e*S_LEN + m0 + 64 + srow)*FF + scol,
                 W2h + ((size_t)e*HID + n0 + srow)*FF + scol,
                 W2h + ((size_t)e*HID + n0 + 64 + srow)*FF + scol,
                 FF, tid, As, Bs, acc);
    #pragma unroll
    for (int m = 0; m < 4; ++m) {
        #pragma unroll
        for (int r = 0; r < 4; ++r) {
            int slot = m0 + wr*64 + m*16 + hi*4 + r;
            if (slot >= ne) continue;
            int tok = idx[e * S_LEN + slot];
            float wv = wt[e * S_LEN + slot];
            #pragma unroll
            for (int n = 0; n < 4; ++n)
                atomicAdd(&hbuf[(size_t)tok * HID + n0 + wc*64 + n*16 + lo], acc[m][n][r] * wv);
        }
    }
}

extern "C" void kernel_launch(void* const* d_in, const int* in_sizes, int n_in,
                              void* d_out, int out_size, void* d_ws, size_t ws_size,
                              hipStream_t stream) {
    const float* emb = (const float*)d_in[0];
    const float* ln1 = (const float*)d_in[1];
    const float* ln2 = (const float*)d_in[2];
    const float* fln = (const float*)d_in[3];
    const float* qw  = (const float*)d_in[4];
    const float* kw  = (const float*)d_in[5];
    const float* vw  = (const float*)d_in[6];
    const float* ow  = (const float*)d_in[7];
    const float* gw  = (const float*)d_in[8];
    const float* w1  = (const float*)d_in[9];
    const float* w2  = (const float*)d_in[10];
    const float* w3  = (const float*)d_in[11];

    float* ws   = (float*)d_ws;
    float* h    = ws + OFF_H;
    float* q    = ws + OFF_Q;
    float* kb   = ws + OFF_K;
    float* vb   = ws + OFF_V;
    float* cosb = ws + OFF_COS;
    float* sinb = ws + OFF_SIN;
    float* wt   = ws + OFF_WT;
    int*   cnt  = (int*)(ws + OFF_INT);
    int*   idx  = cnt + 8;
    int*   tope = (int*)(ws + OFF_TOPE);
    float2* topw = (float2*)(ws + OFF_TOPW);
    short* xh   = (short*)(ws + OFF_XH);
    short* aoh  = (short*)(ws + OFF_AOH);
    short* abh  = (short*)(ws + OFF_ABH);
    short* q16  = (short*)(ws + OFF_Q16);
    short* k16  = (short*)(ws + OFF_K16);
    short* vt16 = (short*)(ws + OFF_VT16);
    float* pO   = ws + OFF_PO;
    float* pm   = ws + OFF_PM;
    float* pl   = ws + OFF_PL;
    short* WC   = (short*)(ws + OFF_WCVT);

    short* sq = WC;
    short* sk = sq + HID*HID;
    short* sv = sk + KVH*HD*HID;
    short* so = sv + KVH*HD*HID;
    short* s1 = so + HID*HID;
    short* s3 = s1 + (size_t)NE*FF*HID;
    short* s2 = s3 + (size_t)NE*FF*HID;

    hipMemcpyAsync(h, emb, (size_t)S_LEN * HID * sizeof(float), hipMemcpyDeviceToDevice, stream);
    rope_tables_kernel<<<S_LEN * 32 / 256, 256, 0, stream>>>(cosb, sinb);

    const int n8_qo = HID*HID/8, n8_kv = KVH*HD*HID/8, n8_w = NE*FF*HID/8;

    for (int l = 0; l < NL; ++l) {
        cvt16_kernel<<<n8_qo/256, 256, 0, stream>>>(qw + (size_t)l*HID*HID, sq, n8_qo);
        cvt16_kernel<<<n8_kv/256, 256, 0, stream>>>(kw + (size_t)l*KVH*HD*HID, sk, n8_kv);
        cvt16_kernel<<<n8_kv/256, 256, 0, stream>>>(vw + (size_t)l*KVH*HD*HID, sv, n8_kv);
        cvt16_kernel<<<n8_qo/256, 256, 0, stream>>>(ow + (size_t)l*HID*HID, so, n8_qo);

        rmsnorm_h16_kernel<<<S_LEN, 256, 0, stream>>>(h, ln1 + l * HID, xh);
        qkv_h16_kernel<<<dim3(12, 16), 256, 0, stream>>>(xh, sq, sk, sv, q, kb, vb);
        rope_cvt_kernel<<<(S_LEN * NHEAD * 32) / 256, 256, 0, stream>>>(q, cosb, sinb, q16, NHEAD, S_LEN * NHEAD * 32);
        rope_cvt_kernel<<<(S_LEN * KVH * 32) / 256, 256, 0, stream>>>(kb, cosb, sinb, k16, KVH, S_LEN * KVH * 32);
        vtrans_kernel<<<dim3(S_LEN/64, KVH*HD/64), 256, 0, stream>>>(vb, vt16);
        attn_mfma_kernel<<<dim3(80, NHEAD), 256, 0, stream>>>(q16, k16, vt16, pO, pm, pl);
        attn_combine_kernel<<<dim3(32, NHEAD), 256, 0, stream>>>(pO, pm, pl, aoh);
        gemm_h16_kernel<<<dim3(8, 16), 256, 0, stream>>>(aoh, so, h, h, HID, HID);

        rmsnorm_gate_kernel<<<S_LEN, 256, 0, stream>>>(h, ln2 + l * HID, gw + (size_t)l * NE * HID,
                                                       xh, tope, topw);
        route_build_kernel<<<NE, 1024, 0, stream>>>(tope, topw, cnt, idx, wt);

        cvt16_kernel<<<n8_w/256, 256, 0, stream>>>(w1 + (size_t)l*NE*FF*HID, s1, n8_w);
        cvt16_kernel<<<n8_w/256, 256, 0, stream>>>(w3 + (size_t)l*NE*FF*HID, s3, n8_w);
        moe_mlp1_h16<<<dim3(16, 16, 8), 256, 0, stream>>>(xh, s1, s3, cnt, idx, abh);

        cvt16_kernel<<<n8_w/256, 256, 0, stream>>>(w2 + (size_t)l*NE*HID*FF, s2, n8_w);
        moe_mlp2_h16<<<dim3(8, 16, 8), 256, 0, stream>>>(abh, s2, cnt, idx, wt, h);
    }
    rmsnorm_kernel<<<S_LEN, 256, 0, stream>>>(h, fln, (float*)d_out);
}

// Round 13
// 485.684 us; speedup vs baseline: 1.4077x; 1.0427x over previous
//
#include <hip/hip_runtime.h>
#include <hip/hip_bf16.h>
#include <math.h>

#define S_LEN 2048
#define HID   1024
#define NHEAD 16
#define KVH   4
#define HD    64
#define FF    1024
#define NE    8
#define NL    2

// ---- workspace layout (float offsets) ----
#define OFF_H    0
#define OFF_Q    (OFF_H + S_LEN*HID)
#define OFF_K    (OFF_Q + S_LEN*HID)
#define OFF_V    (OFF_K + S_LEN*KVH*HD)
#define OFF_COS  (OFF_V + S_LEN*KVH*HD)
#define OFF_SIN  (OFF_COS + S_LEN*32)
#define OFF_WT   (OFF_SIN + S_LEN*32)
#define OFF_INT  (OFF_WT + NE*S_LEN)
#define OFF_TOPE (OFF_INT + NE*S_LEN + 16)
#define OFF_TOPW (OFF_TOPE + S_LEN)
#define OFF_XH   (OFF_TOPW + 2*S_LEN)
#define OFF_AOH  (OFF_XH + S_LEN*HID/2)
#define OFF_ABH  (OFF_AOH + S_LEN*HID/2)
#define OFF_Q16  (OFF_ABH + NE*S_LEN*FF/2)
#define OFF_K16  (OFF_Q16 + S_LEN*HID/2)
#define OFF_VT16 (OFF_K16 + S_LEN*KVH*HD/2)
#define OFF_PO   (OFF_VT16 + S_LEN*KVH*HD/2)
#define OFF_PM   (OFF_PO + 80*NHEAD*64*64)
#define OFF_PL   (OFF_PM + 80*NHEAD*64)
#define OFF_WCVT (OFF_PL + 80*NHEAD*64)
// WCVT region (shorts): qkvo 2.5M + w1 8M + w3 8M + w2 8M = 26.5M shorts = 53MB

typedef __attribute__((ext_vector_type(8))) _Float16 f16x8;
typedef __attribute__((ext_vector_type(8))) short  s16x8;
typedef __attribute__((ext_vector_type(4))) float  f32x4;

__device__ __forceinline__ short f2h(float f) {
    union { _Float16 h; short s; } u;
    u.h = (_Float16)f;
    return u.s;
}

__device__ __forceinline__ s16x8 cvt8(float4 a, float4 b) {
    s16x8 w;
    w[0]=f2h(a.x); w[1]=f2h(a.y); w[2]=f2h(a.z); w[3]=f2h(a.w);
    w[4]=f2h(b.x); w[5]=f2h(b.y); w[6]=f2h(b.z); w[7]=f2h(b.w);
    return w;
}

// ---------------- fp32 -> fp16 convert ----------------
__global__ __launch_bounds__(256) void cvt16_kernel(const float* __restrict__ src,
                                                    short* __restrict__ dst, int n8) {
    int gid = blockIdx.x * 256 + threadIdx.x;
    if (gid >= n8) return;
    const float4* s = (const float4*)src + (size_t)gid * 2;
    *(s16x8*)(dst + (size_t)gid * 8) = cvt8(s[0], s[1]);
}

// ---------------- RoPE tables ----------------
__global__ void rope_tables_kernel(float* __restrict__ cosb, float* __restrict__ sinb) {
    int gid = blockIdx.x * 256 + threadIdx.x;
    int t = gid >> 5, i = gid & 31;
    float invf = powf(1.0e6f, -(float)i / 32.0f);
    float ang = (float)t * invf;
    cosb[gid] = cosf(ang);
    sinb[gid] = sinf(ang);
}

// ---------------- RMSNorm -> fp16 only ----------------
__global__ __launch_bounds__(256) void rmsnorm_h16_kernel(const float* __restrict__ x,
                                                          const float* __restrict__ w,
                                                          short* __restrict__ oh) {
    int row = blockIdx.x;
    const float4* xr = (const float4*)(x + (size_t)row * HID);
    float4 xv = xr[threadIdx.x];
    float ss = xv.x*xv.x + xv.y*xv.y + xv.z*xv.z + xv.w*xv.w;
    for (int off = 32; off; off >>= 1) ss += __shfl_xor(ss, off);
    __shared__ float sred[4];
    if ((threadIdx.x & 63) == 0) sred[threadIdx.x >> 6] = ss;
    __syncthreads();
    float tot = sred[0] + sred[1] + sred[2] + sred[3];
    float scale = rsqrtf(tot * (1.0f / (float)HID) + 1e-5f);
    float4 wv = ((const float4*)w)[threadIdx.x];
    float4 o;
    o.x = xv.x * scale * wv.x; o.y = xv.y * scale * wv.y;
    o.z = xv.z * scale * wv.z; o.w = xv.w * scale * wv.w;
    union { short s[4]; float2 f2; } hh;
    hh.s[0]=f2h(o.x); hh.s[1]=f2h(o.y); hh.s[2]=f2h(o.z); hh.s[3]=f2h(o.w);
    ((float2*)(oh + (size_t)row * HID))[threadIdx.x] = hh.f2;
}

// ---------------- RMSNorm + gate top-2 (NO atomics) ----------------
__global__ __launch_bounds__(256) void rmsnorm_gate_kernel(const float* __restrict__ x,
                                                           const float* __restrict__ w,
                                                           const float* __restrict__ gw,
                                                           short* __restrict__ oh,
                                                           int* __restrict__ tope,
                                                           float2* __restrict__ topw) {
    int row = blockIdx.x;
    const float4* xr = (const float4*)(x + (size_t)row * HID);
    float4 xv = xr[threadIdx.x];
    float ss = xv.x*xv.x + xv.y*xv.y + xv.z*xv.z + xv.w*xv.w;
    for (int off = 32; off; off >>= 1) ss += __shfl_xor(ss, off);
    __shared__ float sred[4];
    __shared__ float gred[4][NE];
    if ((threadIdx.x & 63) == 0) sred[threadIdx.x >> 6] = ss;
    __syncthreads();
    float tot = sred[0] + sred[1] + sred[2] + sred[3];
    float scale = rsqrtf(tot * (1.0f / (float)HID) + 1e-5f);
    float4 wv = ((const float4*)w)[threadIdx.x];
    float4 o;
    o.x = xv.x * scale * wv.x; o.y = xv.y * scale * wv.y;
    o.z = xv.z * scale * wv.z; o.w = xv.w * scale * wv.w;
    union { short s[4]; float2 f2; } hh;
    hh.s[0]=f2h(o.x); hh.s[1]=f2h(o.y); hh.s[2]=f2h(o.z); hh.s[3]=f2h(o.w);
    ((float2*)(oh + (size_t)row * HID))[threadIdx.x] = hh.f2;
    const float4* gr = (const float4*)gw;
    float acc[NE];
    #pragma unroll
    for (int e = 0; e < NE; ++e) {
        float4 g4 = gr[e * 256 + threadIdx.x];
        acc[e] = o.x*g4.x + o.y*g4.y + o.z*g4.z + o.w*g4.w;
    }
    #pragma unroll
    for (int e = 0; e < NE; ++e)
        for (int off = 32; off; off >>= 1) acc[e] += __shfl_xor(acc[e], off);
    if ((threadIdx.x & 63) == 0) {
        #pragma unroll
        for (int e = 0; e < NE; ++e) gred[threadIdx.x >> 6][e] = acc[e];
    }
    __syncthreads();
    if (threadIdx.x == 0) {
        float lg[NE];
        #pragma unroll
        for (int e = 0; e < NE; ++e)
            lg[e] = gred[0][e] + gred[1][e] + gred[2][e] + gred[3][e];
        float mx = lg[0];
        #pragma unroll
        for (int e = 1; e < NE; ++e) mx = fmaxf(mx, lg[e]);
        float p[NE];
        #pragma unroll
        for (int e = 0; e < NE; ++e) p[e] = __expf(lg[e] - mx);
        int i0 = 0;
        #pragma unroll
        for (int e = 1; e < NE; ++e) if (p[e] > p[i0]) i0 = e;
        int i1 = -1;
        #pragma unroll
        for (int e = 0; e < NE; ++e) if (e != i0 && (i1 < 0 || p[e] > p[i1])) i1 = e;
        float w0 = p[i0], w1 = p[i1];
        float inv = 1.0f / (w0 + w1);
        tope[row] = i0 | (i1 << 8);
        topw[row] = make_float2(w0 * inv, w1 * inv);
    }
}

// ---------------- build per-expert token lists (ballot prefix-scan, no atomics) ----------
__global__ __launch_bounds__(1024) void route_build_kernel(const int* __restrict__ tope,
                                                           const float2* __restrict__ topw,
                                                           int* __restrict__ cnt,
                                                           int* __restrict__ idx,
                                                           float* __restrict__ wt) {
    const int e = blockIdx.x;
    const int lane = threadIdx.x & 63, wv = threadIdx.x >> 6;
    __shared__ int wtot[16];
    __shared__ int sbase;
    if (threadIdx.x == 0) sbase = 0;
    __syncthreads();
    for (int t0 = 0; t0 < S_LEN; t0 += 1024) {
        int t = t0 + threadIdx.x;
        int pk = tope[t];
        int e0 = pk & 0xff, e1 = (pk >> 8) & 0xff;
        bool sel = (e0 == e) || (e1 == e);
        unsigned long long mask = __ballot(sel);
        int prefix = __popcll(mask & ((1ULL << lane) - 1ULL));
        if (lane == 0) wtot[wv] = __popcll(mask);
        __syncthreads();
        if (sel) {
            int off = sbase;
            for (int i = 0; i < wv; ++i) off += wtot[i];
            float2 wpair = topw[t];
            float wsel = (e0 == e) ? wpair.x : wpair.y;
            int slot = off + prefix;
            idx[e * S_LEN + slot] = t;
            wt[e * S_LEN + slot] = wsel;
        }
        __syncthreads();
        if (threadIdx.x == 0) {
            int s = 0;
            #pragma unroll
            for (int i = 0; i < 16; ++i) s += wtot[i];
            sbase += s;
        }
    }
    __syncthreads();
    if (threadIdx.x == 0) cnt[e] = sbase;
}

// plain rmsnorm for final output (fp32)
__global__ __launch_bounds__(256) void rmsnorm_kernel(const float* __restrict__ x,
                                                      const float* __restrict__ w,
                                                      float* __restrict__ out) {
    int row = blockIdx.x;
    const float4* xr = (const float4*)(x + (size_t)row * HID);
    float4 xv = xr[threadIdx.x];
    float ss = xv.x*xv.x + xv.y*xv.y + xv.z*xv.z + xv.w*xv.w;
    for (int off = 32; off; off >>= 1) ss += __shfl_xor(ss, off);
    __shared__ float sred[4];
    if ((threadIdx.x & 63) == 0) sred[threadIdx.x >> 6] = ss;
    __syncthreads();
    float tot = sred[0] + sred[1] + sred[2] + sred[3];
    float scale = rsqrtf(tot * (1.0f / (float)HID) + 1e-5f);
    float4 wv = ((const float4*)w)[threadIdx.x];
    float4 o;
    o.x = xv.x * scale * wv.x; o.y = xv.y * scale * wv.y;
    o.z = xv.z * scale * wv.z; o.w = xv.w * scale * wv.w;
    ((float4*)(out + (size_t)row * HID))[threadIdx.x] = o;
}

// ---------------- RoPE apply + fp16 convert (q or k) ----------------
__global__ void rope_cvt_kernel(const float* __restrict__ p, const float* __restrict__ cosb,
                                const float* __restrict__ sinb, short* __restrict__ o16,
                                int nh, int total) {
    int gid = blockIdx.x * 256 + threadIdx.x;
    if (gid >= total) return;
    int per = nh * 32;
    int t = gid / per, r = gid % per;
    int hh = r >> 5, i = r & 31;
    float c = cosb[t*32 + i], s = sinb[t*32 + i];
    const float* base = p + (size_t)t * (nh * HD) + hh * HD + i;
    float a = base[0], b = base[32];
    short* ob = o16 + (size_t)t * (nh * HD) + hh * HD + i;
    ob[0]  = f2h(a * c - b * s);
    ob[32] = f2h(b * c + a * s);
}

// ---------------- V transpose + fp16 ----------------
__global__ __launch_bounds__(256) void vtrans_kernel(const float* __restrict__ vb,
                                                     short* __restrict__ vt16) {
    __shared__ float tile[64][65];
    const int t0 = blockIdx.x * 64, d0 = blockIdx.y * 64;
    const int tr = threadIdx.x >> 2;
    const int dc = (threadIdx.x & 3) * 16;
    const float4* src = (const float4*)(vb + (size_t)(t0 + tr) * (KVH*HD) + d0 + dc);
    float4 v0 = src[0], v1 = src[1], v2 = src[2], v3 = src[3];
    tile[tr][dc+ 0]=v0.x; tile[tr][dc+ 1]=v0.y; tile[tr][dc+ 2]=v0.z; tile[tr][dc+ 3]=v0.w;
    tile[tr][dc+ 4]=v1.x; tile[tr][dc+ 5]=v1.y; tile[tr][dc+ 6]=v1.z; tile[tr][dc+ 7]=v1.w;
    tile[tr][dc+ 8]=v2.x; tile[tr][dc+ 9]=v2.y; tile[tr][dc+10]=v2.z; tile[tr][dc+11]=v2.w;
    tile[tr][dc+12]=v3.x; tile[tr][dc+13]=v3.y; tile[tr][dc+14]=v3.z; tile[tr][dc+15]=v3.w;
    __syncthreads();
    const int dr = threadIdx.x >> 2;
    const int tc = (threadIdx.x & 3) * 16;
    s16x8 w0, w1;
    #pragma unroll
    for (int i = 0; i < 8; ++i) {
        w0[i] = f2h(tile[tc + i][dr]);
        w1[i] = f2h(tile[tc + 8 + i][dr]);
    }
    short* dst = vt16 + (size_t)(d0 + dr) * S_LEN + t0 + tc;
    *(s16x8*)dst = w0;
    *(s16x8*)(dst + 8) = w1;
}

// ---------------- pipelined fp16 64x128 GEMM core (4 waves 2x2, each 32x64) ----------
__device__ __forceinline__ void gemm64_core(
        const short* pA0, const short* pB0, const short* pB1,
        int Kd, int tid, short* As, short* Bs, f32x4 (&acc)[2][4]) {
    const int lane = tid & 63, lo = lane & 15, hi = lane >> 4;
    const int wid = tid >> 6, wr = wid >> 1, wc = wid & 1;
    const int srow = tid >> 2, scol = (tid & 3) * 8;
    s16x8 a0 = *(const s16x8*)pA0;
    s16x8 b0 = *(const s16x8*)pB0;
    s16x8 b1 = *(const s16x8*)pB1;
    for (int k0 = 0; k0 < Kd; k0 += 32) {
        __syncthreads();
        *(s16x8*)&As[srow*40 + scol] = a0;
        *(s16x8*)&Bs[srow*40 + scol] = b0;
        *(s16x8*)&Bs[(64+srow)*40 + scol] = b1;
        __syncthreads();
        if (k0 + 32 < Kd) {   // prefetch next tile under compute
            a0 = *(const s16x8*)(pA0 + k0 + 32);
            b0 = *(const s16x8*)(pB0 + k0 + 32);
            b1 = *(const s16x8*)(pB1 + k0 + 32);
        }
        f16x8 aF[2], bF[4];
        #pragma unroll
        for (int m = 0; m < 2; ++m) aF[m] = *(const f16x8*)&As[(wr*32 + m*16 + lo)*40 + hi*8];
        #pragma unroll
        for (int n = 0; n < 4; ++n) bF[n] = *(const f16x8*)&Bs[(wc*64 + n*16 + lo)*40 + hi*8];
        #pragma unroll
        for (int m = 0; m < 2; ++m)
            #pragma unroll
            for (int n = 0; n < 4; ++n)
                acc[m][n] = __builtin_amdgcn_mfma_f32_16x16x32_f16(aF[m], bF[n], acc[m][n], 0, 0, 0);
    }
}

// ---------------- generic fp16 GEMM: C = A@B^T (+resid), 64-row tiles ----------------
__global__ __launch_bounds__(256) void gemm_h16_kernel(const short* __restrict__ Ag,
        const short* __restrict__ Bg, float* __restrict__ C,
        const float* __restrict__ resid, int N, int Kd) {
    __shared__ __align__(16) short As[64*40], Bs[128*40];
    const int tid = threadIdx.x;
    const int lane = tid & 63, lo = lane & 15, hi = lane >> 4;
    const int wid = tid >> 6, wr = wid >> 1, wc = wid & 1;
    const int m0 = blockIdx.y * 64, n0 = blockIdx.x * 128;
    const int srow = tid >> 2, scol = (tid & 3) * 8;
    f32x4 acc[2][4];
    #pragma unroll
    for (int m = 0; m < 2; ++m)
        #pragma unroll
        for (int n = 0; n < 4; ++n) { acc[m][n][0]=0.f; acc[m][n][1]=0.f; acc[m][n][2]=0.f; acc[m][n][3]=0.f; }
    gemm64_core(Ag + (size_t)(m0+srow)*Kd + scol,
                Bg + (size_t)(n0+srow)*Kd + scol, Bg + (size_t)(n0+64+srow)*Kd + scol,
                Kd, tid, As, Bs, acc);
    #pragma unroll
    for (int m = 0; m < 2; ++m)
        #pragma unroll
        for (int n = 0; n < 4; ++n)
            #pragma unroll
            for (int r = 0; r < 4; ++r) {
                int row = m0 + wr*32 + m*16 + hi*4 + r;
                int col = n0 + wc*64 + n*16 + lo;
                float val = acc[m][n][r];
                if (resid) val += resid[(size_t)row * N + col];
                C[(size_t)row * N + col] = val;
            }
}

// ---------------- fused QKV GEMM (fp16, 64-row tiles) ----------------
__global__ __launch_bounds__(256) void qkv_h16_kernel(const short* __restrict__ Xh,
        const short* __restrict__ qw16, const short* __restrict__ kw16,
        const short* __restrict__ vw16,
        float* __restrict__ qo, float* __restrict__ ko, float* __restrict__ vo) {
    __shared__ __align__(16) short As[64*40], Bs[128*40];
    const int bx = blockIdx.x;
    const short* Bp; float* Cp; int Nc, n0;
    if (bx < 8)       { Bp = qw16; Cp = qo; Nc = 1024; n0 = bx * 128; }
    else if (bx < 10) { Bp = kw16; Cp = ko; Nc = 256;  n0 = (bx - 8) * 128; }
    else              { Bp = vw16; Cp = vo; Nc = 256;  n0 = (bx - 10) * 128; }
    const int tid = threadIdx.x;
    const int lane = tid & 63, lo = lane & 15, hi = lane >> 4;
    const int wid = tid >> 6, wr = wid >> 1, wc = wid & 1;
    const int m0 = blockIdx.y * 64;
    const int srow = tid >> 2, scol = (tid & 3) * 8;
    f32x4 acc[2][4];
    #pragma unroll
    for (int m = 0; m < 2; ++m)
        #pragma unroll
        for (int n = 0; n < 4; ++n) { acc[m][n][0]=0.f; acc[m][n][1]=0.f; acc[m][n][2]=0.f; acc[m][n][3]=0.f; }
    gemm64_core(Xh + (size_t)(m0+srow)*HID + scol,
                Bp + (size_t)(n0+srow)*HID + scol, Bp + (size_t)(n0+64+srow)*HID + scol,
                HID, tid, As, Bs, acc);
    #pragma unroll
    for (int m = 0; m < 2; ++m)
        #pragma unroll
        for (int n = 0; n < 4; ++n)
            #pragma unroll
            for (int r = 0; r < 4; ++r) {
                int row = m0 + wr*32 + m*16 + hi*4 + r;
                int col = n0 + wc*64 + n*16 + lo;
                Cp[(size_t)row * Nc + col] = acc[m][n][r];
            }
}

// ---------------- split-K fp16 MFMA flash attention -> partials ----------------
__global__ __launch_bounds__(256) void attn_mfma_kernel(const short* __restrict__ q16,
                                                        const short* __restrict__ k16,
                                                        const short* __restrict__ vt16,
                                                        float* __restrict__ pO,
                                                        float* __restrict__ pm,
                                                        float* __restrict__ pl) {
    __shared__ __align__(16) short Ks[64][72];
    __shared__ __align__(16) short Vt[64][72];
    __shared__ __align__(16) short Ps[4][16][72];
    const int wid = threadIdx.x >> 6, lane = threadIdx.x & 63;
    const int lo = lane & 15, hi = lane >> 4;
    const int head = blockIdx.y;
    const int s = 79 - blockIdx.x;            // long chunks dispatched first
    int qi, c;
    if (s < 8)       { qi = s;                     c = 0; }
    else if (s < 24) { int t = s - 8;  qi = 8  + (t >> 1); c = t & 1; }
    else if (s < 48) { int t = s - 24; qi = 16 + t / 3;    c = t % 3; }
    else             { int t = s - 48; qi = 24 + (t >> 2); c = t & 3; }
    const int t_beg = c * 8;
    const int t_end = min(t_beg + 8, qi + 1);
    const int q0 = qi * 64;
    const int kvh = head >> 2;

    f16x8 qf[2];
    {
        const short* qr = q16 + (size_t)(q0 + wid*16 + lo) * HID + head*HD;
        qf[0] = *(const f16x8*)(qr + hi*8);
        qf[1] = *(const f16x8*)(qr + 32 + hi*8);
    }

    f32x4 acc[4];
    float m[4], l[4];
    #pragma unroll
    for (int r = 0; r < 4; ++r) {
        m[r] = -1e30f; l[r] = 0.f;
        acc[0][r] = 0.f; acc[1][r] = 0.f; acc[2][r] = 0.f; acc[3][r] = 0.f;
    }

    const int skey = threadIdx.x >> 2;
    const int sdg  = (threadIdx.x & 3) * 16;

    s16x8 ka0, ka1, va0, va1;
    {
        const short* kr = k16 + (size_t)(t_beg*64 + skey)*(KVH*HD) + kvh*HD + sdg;
        ka0 = *(const s16x8*)kr; ka1 = *(const s16x8*)(kr + 8);
        const short* vr = vt16 + (size_t)(kvh*HD + skey)*S_LEN + t_beg*64 + sdg;
        va0 = *(const s16x8*)vr; va1 = *(const s16x8*)(vr + 8);
    }

    for (int t = t_beg; t < t_end; ++t) {
        __syncthreads();
        *(s16x8*)&Ks[skey][sdg]     = ka0;
        *(s16x8*)&Ks[skey][sdg + 8] = ka1;
        *(s16x8*)&Vt[skey][sdg]     = va0;
        *(s16x8*)&Vt[skey][sdg + 8] = va1;
        __syncthreads();
        if (t + 1 < t_end) {
            const short* kr = k16 + (size_t)((t+1)*64 + skey)*(KVH*HD) + kvh*HD + sdg;
            ka0 = *(const s16x8*)kr; ka1 = *(const s16x8*)(kr + 8);
            const short* vr = vt16 + (size_t)(kvh*HD + skey)*S_LEN + (t+1)*64 + sdg;
            va0 = *(const s16x8*)vr; va1 = *(const s16x8*)(vr + 8);
        }
        const int k0 = t * 64;
        f32x4 sc[4];
        #pragma unroll
        for (int f = 0; f < 4; ++f) {
            f32x4 sf; sf[0]=0.f; sf[1]=0.f; sf[2]=0.f; sf[3]=0.f;
            f16x8 bk0 = *(const f16x8*)&Ks[f*16 + lo][hi*8];
            sf = __builtin_amdgcn_mfma_f32_16x16x32_f16(qf[0], bk0, sf, 0, 0, 0);
            f16x8 bk1 = *(const f16x8*)&Ks[f*16 + lo][32 + hi*8];
            sf = __builtin_amdgcn_mfma_f32_16x16x32_f16(qf[1], bk1, sf, 0, 0, 0);
            sc[f] = sf;
        }
        #pragma unroll
        for (int f = 0; f < 4; ++f)
            #pragma unroll
            for (int r = 0; r < 4; ++r) sc[f][r] *= 0.125f;
        if (t == qi) {
            int qrow = q0 + wid*16 + hi*4;
            #pragma unroll
            for (int f = 0; f < 4; ++f)
                #pragma unroll
                for (int r = 0; r < 4; ++r)
                    if (k0 + f*16 + lo > qrow + r) sc[f][r] = -1e30f;
        }
        float scale_[4];
        #pragma unroll
        for (int r = 0; r < 4; ++r) {
            float x = fmaxf(fmaxf(sc[0][r], sc[1][r]), fmaxf(sc[2][r], sc[3][r]));
            x = fmaxf(x, __shfl_xor(x, 1));
            x = fmaxf(x, __shfl_xor(x, 2));
            x = fmaxf(x, __shfl_xor(x, 4));
            x = fmaxf(x, __shfl_xor(x, 8));
            float mn = fmaxf(m[r], x);
            scale_[r] = __expf(m[r] - mn);
            m[r] = mn;
            l[r] *= scale_[r];
            acc[0][r] *= scale_[r]; acc[1][r] *= scale_[r];
            acc[2][r] *= scale_[r]; acc[3][r] *= scale_[r];
        }
        float rs[4] = {0.f, 0.f, 0.f, 0.f};
        #pragma unroll
        for (int f = 0; f < 4; ++f)
            #pragma unroll
            for (int r = 0; r < 4; ++r) {
                float e = __expf(sc[f][r] - m[r]);
                rs[r] += e;
                Ps[wid][hi*4 + r][f*16 + lo] = f2h(e);
            }
        #pragma unroll
        for (int r = 0; r < 4; ++r) {
            float x = rs[r];
            x += __shfl_xor(x, 1); x += __shfl_xor(x, 2);
            x += __shfl_xor(x, 4); x += __shfl_xor(x, 8);
            l[r] += x;
        }
        asm volatile("s_waitcnt lgkmcnt(0)" ::: "memory");
        __builtin_amdgcn_sched_barrier(0);
        f16x8 pa0 = *(const f16x8*)&Ps[wid][lo][hi*8];
        f16x8 pa1 = *(const f16x8*)&Ps[wid][lo][32 + hi*8];
        #pragma unroll
        for (int f = 0; f < 4; ++f) {
            f32x4 o = acc[f];
            f16x8 v0 = *(const f16x8*)&Vt[f*16 + lo][hi*8];
            o = __builtin_amdgcn_mfma_f32_16x16x32_f16(pa0, v0, o, 0, 0, 0);
            f16x8 v1 = *(const f16x8*)&Vt[f*16 + lo][32 + hi*8];
            o = __builtin_amdgcn_mfma_f32_16x16x32_f16(pa1, v1, o, 0, 0, 0);
            acc[f] = o;
        }
    }
    const int pbase = head * 80 + s;
    float* po = pO + (size_t)pbase * 4096;
    #pragma unroll
    for (int r = 0; r < 4; ++r)
        #pragma unroll
        for (int f = 0; f < 4; ++f)
            po[(wid*16 + hi*4 + r) * 64 + f*16 + lo] = acc[f][r];
    if (lo == 0) {
        #pragma unroll
        for (int r = 0; r < 4; ++r) {
            pm[pbase*64 + wid*16 + hi*4 + r] = m[r];
            pl[pbase*64 + wid*16 + hi*4 + r] = l[r];
        }
    }
}

// ---------------- combine partials -> fp16 attention output ----------------
__global__ __launch_bounds__(256) void attn_combine_kernel(const float* __restrict__ pO,
        const float* __restrict__ pm, const float* __restrict__ pl,
        short* __restrict__ aoh) {
    const int qi = blockIdx.x, head = blockIdx.y;
    const int nch = qi / 8 + 1;
    int sbase;
    if (qi < 8)       sbase = qi;
    else if (qi < 16) sbase = 8 + (qi - 8) * 2;
    else if (qi < 24) sbase = 24 + (qi - 16) * 3;
    else              sbase = 48 + (qi - 24) * 4;
    const int row = threadIdx.x >> 2;
    const int d0 = (threadIdx.x & 3) * 16;
    float mv[4], lv[4];
    float mx = -1e30f;
    #pragma unroll
    for (int cd = 0; cd < 4; ++cd) {
        if (cd < nch) {
            int p = head * 80 + sbase + cd;
            mv[cd] = pm[p * 64 + row];
            lv[cd] = pl[p * 64 + row];
            mx = fmaxf(mx, mv[cd]);
        } else { mv[cd] = -1e30f; lv[cd] = 0.f; }
    }
    float w[4];
    float lsum = 0.f;
    #pragma unroll
    for (int cd = 0; cd < 4; ++cd) {
        w[cd] = (cd < nch) ? __expf(mv[cd] - mx) : 0.f;
        lsum += w[cd] * lv[cd];
    }
    float inv = 1.0f / lsum;
    float o[16] = {};
    #pragma unroll
    for (int cd = 0; cd < 4; ++cd) {
        if (cd < nch) {
            const float4* po = (const float4*)(pO + ((size_t)(head * 80 + sbase + cd)) * 4096 + row * 64 + d0);
            float wc = w[cd] * inv;
            #pragma unroll
            for (int j = 0; j < 4; ++j) {
                float4 vv = po[j];
                o[j*4+0] += wc * vv.x; o[j*4+1] += wc * vv.y;
                o[j*4+2] += wc * vv.z; o[j*4+3] += wc * vv.w;
            }
        }
    }
    size_t outb = (size_t)(qi * 64 + row) * HID + head * HD + d0;
    s16x8 w0, w1;
    #pragma unroll
    for (int i = 0; i < 8; ++i) { w0[i] = f2h(o[i]); w1[i] = f2h(o[8+i]); }
    *(s16x8*)(aoh + outb) = w0;
    *(s16x8*)(aoh + outb + 8) = w1;
}

// ---------------- MoE mlp1 (fp16, 64-row tile, pipelined) ----------------
// tile 64 tokens x 64 F; 4 waves 2x2, each 32 rows x 32 f; dual (g,u) accumulators.
__global__ __launch_bounds__(256) void moe_mlp1_h16(const short* __restrict__ Xh,
        const short* __restrict__ W1h, const short* __restrict__ W3h,
        const int* __restrict__ cnt, const int* __restrict__ idx,
        short* __restrict__ abh) {
    int e = blockIdx.z;
    int ne = cnt[e];
    int m0 = blockIdx.y * 64;
    if (m0 >= ne) return;
    int f0 = blockIdx.x * 64;
    __shared__ __align__(16) short As[64*40];
    __shared__ __align__(16) short Gs[64*40], Us[64*40];
    __shared__ int rows[64];
    const int tid = threadIdx.x;
    if (tid < 64) {
        int slot = m0 + tid;
        rows[tid] = (slot < ne) ? idx[e * S_LEN + slot] : 0;
    }
    __syncthreads();
    const int lane = tid & 63, lo = lane & 15, hi = lane >> 4;
    const int wid = tid >> 6, wr = wid >> 1, wc = wid & 1;
    const int srow = tid >> 2, scol = (tid & 3) * 8;
    const short* pX0 = Xh + (size_t)rows[srow] * HID + scol;
    const short* p1 = W1h + ((size_t)e * FF + f0 + srow) * HID + scol;
    const short* p3 = W3h + ((size_t)e * FF + f0 + srow) * HID + scol;

    f32x4 ag[2][2], au[2][2];
    #pragma unroll
    for (int m = 0; m < 2; ++m)
        #pragma unroll
        for (int n = 0; n < 2; ++n) {
            ag[m][n][0]=0.f; ag[m][n][1]=0.f; ag[m][n][2]=0.f; ag[m][n][3]=0.f;
            au[m][n][0]=0.f; au[m][n][1]=0.f; au[m][n][2]=0.f; au[m][n][3]=0.f;
        }

    s16x8 a0 = *(const s16x8*)pX0;
    s16x8 g0 = *(const s16x8*)p1;
    s16x8 u0 = *(const s16x8*)p3;
    for (int k0 = 0; k0 < HID; k0 += 32) {
        __syncthreads();
        *(s16x8*)&As[srow*40 + scol] = a0;
        *(s16x8*)&Gs[srow*40 + scol] = g0;
        *(s16x8*)&Us[srow*40 + scol] = u0;
        __syncthreads();
        if (k0 + 32 < HID) {   // prefetch next tile under compute
            a0 = *(const s16x8*)(pX0 + k0 + 32);
            g0 = *(const s16x8*)(p1 + k0 + 32);
            u0 = *(const s16x8*)(p3 + k0 + 32);
        }
        f16x8 aF[2], gF[2], uF[2];
        #pragma unroll
        for (int m = 0; m < 2; ++m) aF[m] = *(const f16x8*)&As[(wr*32 + m*16 + lo)*40 + hi*8];
        #pragma unroll
        for (int n = 0; n < 2; ++n) {
            gF[n] = *(const f16x8*)&Gs[(wc*32 + n*16 + lo)*40 + hi*8];
            uF[n] = *(const f16x8*)&Us[(wc*32 + n*16 + lo)*40 + hi*8];
        }
        #pragma unroll
        for (int m = 0; m < 2; ++m)
            #pragma unroll
            for (int n = 0; n < 2; ++n) {
                ag[m][n] = __builtin_amdgcn_mfma_f32_16x16x32_f16(aF[m], gF[n], ag[m][n], 0, 0, 0);
                au[m][n] = __builtin_amdgcn_mfma_f32_16x16x32_f16(aF[m], uF[n], au[m][n], 0, 0, 0);
            }
    }
    #pragma unroll
    for (int m = 0; m < 2; ++m)
        #pragma unroll
        for (int n = 0; n < 2; ++n)
            #pragma unroll
            for (int r = 0; r < 4; ++r) {
                int slot = m0 + wr*32 + m*16 + hi*4 + r;
                if (slot >= ne) continue;
                float g = ag[m][n][r], u = au[m][n][r];
                float a = g * (1.0f / (1.0f + __expf(-g))) * u;
                abh[((size_t)e * S_LEN + slot) * FF + f0 + wc*32 + n*16 + lo] = f2h(a);
            }
}

// ---------------- MoE mlp2 (fp16, 64-row tile, pipelined): h += wt * (a @ w2^T) --------
__global__ __launch_bounds__(256) void moe_mlp2_h16(const short* __restrict__ abh,
        const short* __restrict__ W2h,
        const int* __restrict__ cnt, const int* __restrict__ idx,
        const float* __restrict__ wt, float* __restrict__ hbuf) {
    int e = blockIdx.z;
    int ne = cnt[e];
    int m0 = blockIdx.y * 64;
    if (m0 >= ne) return;
    int n0 = blockIdx.x * 128;
    __shared__ __align__(16) short As[64*40], Bs[128*40];
    const int tid = threadIdx.x;
    const int lane = tid & 63, lo = lane & 15, hi = lane >> 4;
    const int wid = tid >> 6, wr = wid >> 1, wc = wid & 1;
    const int srow = tid >> 2, scol = (tid & 3) * 8;
    f32x4 acc[2][4];
    #pragma unroll
    for (int m = 0; m < 2; ++m)
        #pragma unroll
        for (int n = 0; n < 4; ++n) { acc[m][n][0]=0.f; acc[m][n][1]=0.f; acc[m][n][2]=0.f; acc[m][n][3]=0.f; }
    gemm64_core(abh + ((size_t)e*S_LEN + m0 + srow)*FF + scol,
                W2h + ((size_t)e*HID + n0 + srow)*FF + scol,
                W2h + ((size_t)e*HID + n0 + 64 + srow)*FF + scol,
                FF, tid, As, Bs, acc);
    #pragma unroll
    for (int m = 0; m < 2; ++m) {
        #pragma unroll
        for (int r = 0; r < 4; ++r) {
            int slot = m0 + wr*32 + m*16 + hi*4 + r;
            if (slot >= ne) continue;
            int tok = idx[e * S_LEN + slot];
            float wv = wt[e * S_LEN + slot];
            #pragma unroll
            for (int n = 0; n < 4; ++n)
                atomicAdd(&hbuf[(size_t)tok * HID + n0 + wc*64 + n*16 + lo], acc[m][n][r] * wv);
        }
    }
}

extern "C" void kernel_launch(void* const* d_in, const int* in_sizes, int n_in,
                              void* d_out, int out_size, void* d_ws, size_t ws_size,
                              hipStream_t stream) {
    const float* emb = (const float*)d_in[0];
    const float* ln1 = (const float*)d_in[1];
    const float* ln2 = (const float*)d_in[2];
    const float* fln = (const float*)d_in[3];
    const float* qw  = (const float*)d_in[4];
    const float* kw  = (const float*)d_in[5];
    const float* vw  = (const float*)d_in[6];
    const float* ow  = (const float*)d_in[7];
    const float* gw  = (const float*)d_in[8];
    const float* w1  = (const float*)d_in[9];
    const float* w2  = (const float*)d_in[10];
    const float* w3  = (const float*)d_in[11];

    float* ws   = (float*)d_ws;
    float* h    = ws + OFF_H;
    float* q    = ws + OFF_Q;
    float* kb   = ws + OFF_K;
    float* vb   = ws + OFF_V;
    float* cosb = ws + OFF_COS;
    float* sinb = ws + OFF_SIN;
    float* wt   = ws + OFF_WT;
    int*   cnt  = (int*)(ws + OFF_INT);
    int*   idx  = cnt + 8;
    int*   tope = (int*)(ws + OFF_TOPE);
    float2* topw = (float2*)(ws + OFF_TOPW);
    short* xh   = (short*)(ws + OFF_XH);
    short* aoh  = (short*)(ws + OFF_AOH);
    short* abh  = (short*)(ws + OFF_ABH);
    short* q16  = (short*)(ws + OFF_Q16);
    short* k16  = (short*)(ws + OFF_K16);
    short* vt16 = (short*)(ws + OFF_VT16);
    float* pO   = ws + OFF_PO;
    float* pm   = ws + OFF_PM;
    float* pl   = ws + OFF_PL;
    short* WC   = (short*)(ws + OFF_WCVT);

    short* sq = WC;
    short* sk = sq + HID*HID;
    short* sv = sk + KVH*HD*HID;
    short* so = sv + KVH*HD*HID;
    short* s1 = so + HID*HID;
    short* s3 = s1 + (size_t)NE*FF*HID;
    short* s2 = s3 + (size_t)NE*FF*HID;

    hipMemcpyAsync(h, emb, (size_t)S_LEN * HID * sizeof(float), hipMemcpyDeviceToDevice, stream);
    rope_tables_kernel<<<S_LEN * 32 / 256, 256, 0, stream>>>(cosb, sinb);

    const int n8_qo = HID*HID/8, n8_kv = KVH*HD*HID/8, n8_w = NE*FF*HID/8;

    for (int l = 0; l < NL; ++l) {
        cvt16_kernel<<<n8_qo/256, 256, 0, stream>>>(qw + (size_t)l*HID*HID, sq, n8_qo);
        cvt16_kernel<<<n8_kv/256, 256, 0, stream>>>(kw + (size_t)l*KVH*HD*HID, sk, n8_kv);
        cvt16_kernel<<<n8_kv/256, 256, 0, stream>>>(vw + (size_t)l*KVH*HD*HID, sv, n8_kv);
        cvt16_kernel<<<n8_qo/256, 256, 0, stream>>>(ow + (size_t)l*HID*HID, so, n8_qo);

        rmsnorm_h16_kernel<<<S_LEN, 256, 0, stream>>>(h, ln1 + l * HID, xh);
        qkv_h16_kernel<<<dim3(12, 32), 256, 0, stream>>>(xh, sq, sk, sv, q, kb, vb);
        rope_cvt_kernel<<<(S_LEN * NHEAD * 32) / 256, 256, 0, stream>>>(q, cosb, sinb, q16, NHEAD, S_LEN * NHEAD * 32);
        rope_cvt_kernel<<<(S_LEN * KVH * 32) / 256, 256, 0, stream>>>(kb, cosb, sinb, k16, KVH, S_LEN * KVH * 32);
        vtrans_kernel<<<dim3(S_LEN/64, KVH*HD/64), 256, 0, stream>>>(vb, vt16);
        attn_mfma_kernel<<<dim3(80, NHEAD), 256, 0, stream>>>(q16, k16, vt16, pO, pm, pl);
        attn_combine_kernel<<<dim3(32, NHEAD), 256, 0, stream>>>(pO, pm, pl, aoh);
        gemm_h16_kernel<<<dim3(8, 32), 256, 0, stream>>>(aoh, so, h, h, HID, HID);

        rmsnorm_gate_kernel<<<S_LEN, 256, 0, stream>>>(h, ln2 + l * HID, gw + (size_t)l * NE * HID,
                                                       xh, tope, topw);
        route_build_kernel<<<NE, 1024, 0, stream>>>(tope, topw, cnt, idx, wt);

        cvt16_kernel<<<n8_w/256, 256, 0, stream>>>(w1 + (size_t)l*NE*FF*HID, s1, n8_w);
        cvt16_kernel<<<n8_w/256, 256, 0, stream>>>(w3 + (size_t)l*NE*FF*HID, s3, n8_w);
        moe_mlp1_h16<<<dim3(16, 32, 8), 256, 0, stream>>>(xh, s1, s3, cnt, idx, abh);

        cvt16_kernel<<<n8_w/256, 256, 0, stream>>>(w2 + (size_t)l*NE*HID*FF, s2, n8_w);
        moe_mlp2_h16<<<dim3(8, 32, 8), 256, 0, stream>>>(abh, s2, cnt, idx, wt, h);
    }
    rmsnorm_kernel<<<S_LEN, 256, 0, stream>>>(h, fln, (float*)d_out);
}